// Round 3
// baseline (263.474 us; speedup 1.0000x reference)
//
#include <hip/hip_runtime.h>
#include <hip/hip_bf16.h>

#define CIN 384
#define PQ 1024
#define PKV 256
#define HEADS 6
#define DH 64
#define INNER 384
#define ATTN_SCALE 0.125f

typedef __hip_bfloat16 bf16;
typedef unsigned short ushort;
typedef __bf16 bf16x8 __attribute__((ext_vector_type(8)));
typedef float floatx4 __attribute__((ext_vector_type(4)));

__device__ __forceinline__ float b2f(bf16 v) { return __bfloat162float(v); }
__device__ __forceinline__ bf16 f2b(float v) { return __float2bfloat16(v); }
__device__ __forceinline__ ushort f2bu(float v) { bf16 h = __float2bfloat16(v); return *(ushort*)&h; }
__device__ __forceinline__ float ldf(const void* p, size_t i, int isbf) {
    return isbf ? __bfloat162float(((const bf16*)p)[i]) : ((const float*)p)[i];
}
// async global->LDS DMA, 16B per lane; LDS dest = uniform base + lane*16
__device__ __forceinline__ void dma16(const bf16* g, bf16* l) {
    __builtin_amdgcn_global_load_lds(
        (const __attribute__((address_space(1))) unsigned int*)g,
        (__attribute__((address_space(3))) unsigned int*)l, 16, 0, 0);
}
// uniform scalar dtype probe (replaces detect_kernel dispatch)
__device__ __forceinline__ int probe_isbf(const void* x) {
    const unsigned* u = (const unsigned*)x;
    int cnt = 0;
    for (int i = 0; i < 64; i++) {
        unsigned e = (u[i] >> 7) & 0xFFu;
        cnt += (e >= 100u && e <= 140u) ? 1 : 0;
    }
    return cnt >= 48 ? 1 : 0;
}
__device__ __forceinline__ unsigned cvtpk(float lo, float hi) {
    unsigned r;
    asm("v_cvt_pk_bf16_f32 %0, %1, %2" : "=v"(r) : "v"(lo), "v"(hi));
    return r;
}
// half-wave swap: lo = [a(lanes0-31) | b(lanes0-31)], hi = [a(32-63) | b(32-63)]
__device__ __forceinline__ void halfswap(unsigned a, unsigned b, unsigned& lo, unsigned& hi) {
#if __has_builtin(__builtin_amdgcn_permlane32_swap)
    auto r = __builtin_amdgcn_permlane32_swap(a, b, false, false);
    lo = r[0]; hi = r[1];
#else
    unsigned ax = (unsigned)__shfl_xor((int)a, 32, 64);
    unsigned bx = (unsigned)__shfl_xor((int)b, 32, 64);
    bool lower = (threadIdx.x & 32) == 0;
    lo = lower ? a : bx;
    hi = lower ? ax : b;
#endif
}

// ---------------- weight convert: 3 segments -> contiguous bf16 ------------------
__global__ void wconv_kernel(const void* __restrict__ w0, const void* __restrict__ w1,
                             const void* __restrict__ w2, bf16* __restrict__ dst,
                             const void* __restrict__ xprobe) {
    int isbf = probe_isbf(xprobe);
    const int n0 = INNER * CIN, n1 = 2 * INNER * CIN, n2 = INNER * CIN;
    int i = blockIdx.x * 256 + threadIdx.x;
    int total = n0 + n1 + n2;
    for (; i < total; i += gridDim.x * 256) {
        float v;
        if (i < n0) v = ldf(w0, i, isbf);
        else if (i < n0 + n1) v = ldf(w1, i - n0, isbf);
        else v = ldf(w2, i - n0 - n1, isbf);
        dst[i] = f2b(v);
    }
}

// ---------------- depthwise 3x3 + BN -> Y^T [b][p][c] ----------------------------
template <int STRIDE, int HO, int WO>
__global__ __launch_bounds__(256) void dw_bn_kernel(
        const void* __restrict__ x, const void* __restrict__ wdw,
        const void* __restrict__ gamma, const void* __restrict__ beta,
        const void* __restrict__ mean, const void* __restrict__ var,
        bf16* __restrict__ yt) {
    constexpr int IN_ROWS = (8 - 1) * STRIDE + 3;       // 10 or 17
    constexpr int RL = 37;                              // slab stride 370%32=18 -> 2-way
    constexpr int PT = 8 * WO;
    constexpr unsigned XSZ = 32u * IN_ROWS * RL * 4;
    constexpr unsigned OSZ = (unsigned)PT * 40 * 2;
    __shared__ __align__(16) char smem[XSZ > OSZ ? XSZ : OSZ];
    float (*xin)[IN_ROWS][RL] = (float (*)[IN_ROWS][RL])smem;  // [cc][i][1+w]
    ushort (*outt)[40] = (ushort (*)[40])smem;                 // [g*WO+wo][cc]

    int isbf = probe_isbf(x);
    int rg = blockIdx.x;
    int c0 = blockIdx.y * 32;
    int b  = blockIdx.z;
    int tid = threadIdx.x;
    int ri0 = rg * 8 * STRIDE - 1;

    for (int e = tid; e < 32 * IN_ROWS; e += 256) {
        int i = e % IN_ROWS, cc = e / IN_ROWS;
        xin[cc][i][0] = 0.f;
        xin[cc][i][33] = 0.f;
    }

    const int NCHUNK = 32 * IN_ROWS * 4;
    for (int ch = tid; ch < NCHUNK; ch += 256) {
        int wc = ch & 3;
        int t  = ch >> 2;
        int i  = t % IN_ROWS;
        int cc = t / IN_ROWS;
        int row = ri0 + i;
        float f[8];
        if (row >= 0 && row < 32) {
            size_t goff = ((size_t)(b * CIN + c0 + cc) * 32 + row) * 32 + wc * 8;
            if (isbf) {
                uint4 v = *(const uint4*)((const bf16*)x + goff);
                const ushort* u = (const ushort*)&v;
#pragma unroll
                for (int j = 0; j < 8; j++) f[j] = __uint_as_float((unsigned)u[j] << 16);
            } else {
                float4 v0 = *(const float4*)((const float*)x + goff);
                float4 v1 = *(const float4*)((const float*)x + goff + 4);
                f[0] = v0.x; f[1] = v0.y; f[2] = v0.z; f[3] = v0.w;
                f[4] = v1.x; f[5] = v1.y; f[6] = v1.z; f[7] = v1.w;
            }
        } else {
#pragma unroll
            for (int j = 0; j < 8; j++) f[j] = 0.f;
        }
        float* dst = &xin[cc][i][1 + wc * 8];
#pragma unroll
        for (int j = 0; j < 8; j++) dst[j] = f[j];
    }

    int cc = tid & 31;
    int g  = tid >> 5;
    int c  = c0 + cc;
    float w9[9];
#pragma unroll
    for (int k = 0; k < 9; k++) w9[k] = ldf(wdw, c * 9 + k, isbf);
    float inv  = ldf(gamma, c, isbf) * rsqrtf(ldf(var, c, isbf) + 1e-5f);
    float bias = ldf(beta, c, isbf) - ldf(mean, c, isbf) * inv;
    __syncthreads();

    const float* xr0 = xin[cc][g * STRIDE + 0];
    const float* xr1 = xin[cc][g * STRIDE + 1];
    const float* xr2 = xin[cc][g * STRIDE + 2];
    float o[WO];
    if (STRIDE == 1) {
        float a0 = xr0[0], a1 = xr0[1];
        float b0 = xr1[0], b1 = xr1[1];
        float q0 = xr2[0], q1 = xr2[1];
#pragma unroll
        for (int wo = 0; wo < WO; wo++) {
            float a2 = xr0[wo + 2], b2 = xr1[wo + 2], q2 = xr2[wo + 2];
            float acc = w9[0] * a0 + w9[1] * a1 + w9[2] * a2
                      + w9[3] * b0 + w9[4] * b1 + w9[5] * b2
                      + w9[6] * q0 + w9[7] * q1 + w9[8] * q2;
            o[wo] = acc * inv + bias;
            a0 = a1; a1 = a2; b0 = b1; b1 = b2; q0 = q1; q1 = q2;
        }
    } else {
        float a0 = xr0[0], b0 = xr1[0], q0 = xr2[0];
#pragma unroll
        for (int wo = 0; wo < WO; wo++) {
            float a1 = xr0[2 * wo + 1], a2 = xr0[2 * wo + 2];
            float b1 = xr1[2 * wo + 1], b2 = xr1[2 * wo + 2];
            float q1 = xr2[2 * wo + 1], q2 = xr2[2 * wo + 2];
            float acc = w9[0] * a0 + w9[1] * a1 + w9[2] * a2
                      + w9[3] * b0 + w9[4] * b1 + w9[5] * b2
                      + w9[6] * q0 + w9[7] * q1 + w9[8] * q2;
            o[wo] = acc * inv + bias;
            a0 = a2; b0 = b2; q0 = q2;
        }
    }
    __syncthreads();

#pragma unroll
    for (int wo = 0; wo < WO; wo++) outt[g * WO + wo][cc] = f2bu(o[wo]);
    __syncthreads();

    const size_t pbase = (size_t)b * (HO * WO) + (size_t)rg * 8 * WO;
    for (int chk = tid; chk < PT * 4; chk += 256) {
        int k = chk & 3, p = chk >> 2;
        uint4 v = *(const uint4*)&outt[p][k * 8];
        *(uint4*)(yt + (pbase + p) * CIN + c0 + k * 8) = v;
    }
}

// ---------------- MFMA pointwise GEMM, BK=64 (half the barriers vs BK=32) --------
// C^T[p][o] = sum_c Yt[b][p][c] * W[o][c]. 128x128 tile.
// LDS rows 128B (8x16B granules), slot = g ^ (row&7) -> ~2-way on ds_read_b128.
template <int P, int MODE>
__global__ __launch_bounds__(256, 2) void mfma_pw(
        const bf16* __restrict__ wt, const bf16* __restrict__ yt,
        const void* __restrict__ bias, void* __restrict__ out0,
        bf16* __restrict__ out1, int O, const void* __restrict__ xprobe) {
    __shared__ __align__(16) bf16 As[2][8192];  // 128 rows x 64 k
    __shared__ __align__(16) bf16 Bs[2][8192];
    int tid = threadIdx.x;
    int wave = tid >> 6, lane = tid & 63;
    int l15 = lane & 15, quad = lane >> 4;
    int wm = wave & 1, wn = wave >> 1;
    int b = blockIdx.z;
    int p0 = blockIdx.x * 128;
    int o0 = blockIdx.y * 128;

    const bf16* asrc = yt + ((size_t)b * P + p0) * CIN;
    const bf16* bsrc = wt + (size_t)o0 * CIN;

    int srow = lane >> 3;  // 0..7 rows per issue
    int sc   = lane & 7;   // granule slot
    auto stage = [&](int step, int buf) {
#pragma unroll
        for (int it = 0; it < 4; it++) {
            int row = wave * 32 + it * 8 + srow;
            int g = sc ^ (row & 7);
            size_t goff = (size_t)row * CIN + step * 64 + g * 8;
            dma16(asrc + goff, &As[buf][(wave * 4 + it) * 512]);
            dma16(bsrc + goff, &Bs[buf][(wave * 4 + it) * 512]);
        }
    };

    floatx4 acc[4][4];
#pragma unroll
    for (int pt = 0; pt < 4; pt++)
#pragma unroll
        for (int ot = 0; ot < 4; ot++) acc[pt][ot] = (floatx4){0.f, 0.f, 0.f, 0.f};

    stage(0, 0);
    __syncthreads();
    for (int s = 0; s < CIN / 64; s++) {
        int buf = s & 1;
        if (s < CIN / 64 - 1) stage(s + 1, buf ^ 1);
#pragma unroll
        for (int ks = 0; ks < 2; ks++) {
            bf16x8 af[4], bw[4];
#pragma unroll
            for (int pt = 0; pt < 4; pt++) {
                int row = wm * 64 + pt * 16 + l15;
                af[pt] = *(const bf16x8*)&As[buf][row * 64 + (((ks * 4 + quad) ^ (row & 7))) * 8];
            }
#pragma unroll
            for (int ot = 0; ot < 4; ot++) {
                int row = wn * 64 + ot * 16 + l15;
                bw[ot] = *(const bf16x8*)&Bs[buf][row * 64 + (((ks * 4 + quad) ^ (row & 7))) * 8];
            }
#pragma unroll
            for (int pt = 0; pt < 4; pt++)
#pragma unroll
                for (int ot = 0; ot < 4; ot++)
                    acc[pt][ot] = __builtin_amdgcn_mfma_f32_16x16x32_bf16(af[pt], bw[ot], acc[pt][ot], 0, 0, 0);
        }
        __syncthreads();
    }

    int pw0 = p0 + wm * 64, ow0 = o0 + wn * 64;
    if (MODE == 2) {
        int isbf = probe_isbf(xprobe);
#pragma unroll
        for (int ot = 0; ot < 4; ot++) {
            int o = ow0 + ot * 16 + l15;
            float bv = ldf(bias, o, isbf);
#pragma unroll
            for (int pt = 0; pt < 4; pt++) {
                int p = pw0 + pt * 16 + quad * 4;
                size_t idx = ((size_t)b * O + o) * P + p;
                if (!isbf) {
                    float4 v4 = {acc[pt][ot][0] + bv, acc[pt][ot][1] + bv,
                                 acc[pt][ot][2] + bv, acc[pt][ot][3] + bv};
                    *(float4*)((float*)out0 + idx) = v4;
                } else {
                    ushort4 u4 = {f2bu(acc[pt][ot][0] + bv), f2bu(acc[pt][ot][1] + bv),
                                  f2bu(acc[pt][ot][2] + bv), f2bu(acc[pt][ot][3] + bv)};
                    *(ushort4*)((bf16*)out0 + idx) = u4;
                }
            }
        }
    } else if (MODE == 0) {
#pragma unroll
        for (int ot = 0; ot < 4; ot++) {
            int o = ow0 + ot * 16 + l15;
            int h = o >> 6, d = o & 63;
            bf16* base = (bf16*)out0 + ((size_t)(b * HEADS + h) * P) * 64 + d;
#pragma unroll
            for (int pt = 0; pt < 4; pt++)
#pragma unroll
                for (int r = 0; r < 4; r++)
                    base[(size_t)(pw0 + pt * 16 + quad * 4 + r) * 64] = f2b(acc[pt][ot][r]);
        }
    } else {  // MODE 1: K | V fused
#pragma unroll
        for (int ot = 0; ot < 4; ot++) {
            int o = ow0 + ot * 16 + l15;
            if (o < INNER) {
                int h = o >> 6, d = o & 63;
                bf16* base = (bf16*)out0 + ((size_t)(b * HEADS + h) * P) * 64 + d;
#pragma unroll
                for (int pt = 0; pt < 4; pt++)
#pragma unroll
                    for (int r = 0; r < 4; r++)
                        base[(size_t)(pw0 + pt * 16 + quad * 4 + r) * 64] = f2b(acc[pt][ot][r]);
            } else {
                int ch = o - INNER;
                bf16* base = out1 + ((size_t)b * INNER + ch) * PKV;
#pragma unroll
                for (int pt = 0; pt < 4; pt++)
#pragma unroll
                    for (int r = 0; r < 4; r++)
                        base[pw0 + pt * 16 + quad * 4 + r] = f2b(acc[pt][ot][r]);
            }
        }
    }
}

// ---------------- fused MFMA attention v3 ----------------------------------------
// K direct from global (L2-hot, XCD-pinned); V staged in LDS (32KB); LDS total
// 42KB -> 3 blocks/CU (12 waves). Swapped S^T = mfma(K,Q) keeps P in registers;
// cvt_pk_bf16 + permlane32_swap + xor16-shfl reshapes P into true 16x16x32
// A-frags, so PV uses wide MFMAs + conflict-free b128 V reads. One barrier per
// block (V-DMA drain), placed after tile-0 QK^T+softmax to hide staging latency.
__global__ __launch_bounds__(256, 3) void attn_kernel(
        const bf16* __restrict__ qalt, const bf16* __restrict__ kalt,
        const bf16* __restrict__ valt, bf16* __restrict__ ao) {
    __shared__ __align__(16) bf16 Vl[16384];        // 32 KB
    __shared__ __align__(16) ushort Ot[4][16][80];  // 10 KB, per-wave scratch
    int tid = threadIdx.x;
    int wave = tid >> 6, lane = tid & 63;
    int l15 = lane & 15, quad = lane >> 4;
    int blk = blockIdx.x;
    int swz = (blk & 7) * 192 + (blk >> 3);  // 1536 = 8*192, bijective
    int seg = swz & 7;                        // 8 segments of 128 Q rows
    int bh  = swz >> 3;                       // 8 consecutive segs share (b,h) & XCD
    int b = bh / HEADS, h = bh % HEADS;

    const bf16* qbase = qalt + (size_t)(b * HEADS + h) * PQ * DH;
    const bf16* kbase = kalt + (size_t)(b * HEADS + h) * PKV * DH;
    const bf16* vbase = valt + ((size_t)b * INNER + h * DH) * PKV;

    // stage V: rows 512B = 32 granules, LDS slot cs2 holds global granule cs2^(row&15)
    {
        int d = lane >> 5, cs2 = lane & 31;
#pragma unroll
        for (int it = 0; it < 8; it++) {
            int dr = (wave * 8 + it) * 2 + d;
            int g = cs2 ^ (dr & 15);
            dma16(vbase + (size_t)dr * 256 + g * 8, &Vl[(wave * 8 + it) * 512]);
        }
    }

    int p0 = seg * 128 + wave * 16;  // tile t adds t*64
    const bf16* qrow = qbase + (size_t)(p0 + l15) * DH + quad * 8;
    const bf16* krow = kbase + (size_t)l15 * DH + quad * 8;
    bf16x8 qc0 = *(const bf16x8*)qrow;
    bf16x8 qc1 = *(const bf16x8*)(qrow + 32);

    const float C = ATTN_SCALE * 1.44269504f;  // fold scale into exp2

#pragma unroll
    for (int t = 0; t < 2; t++) {
        // S^T = K Q^T : lane holds S[q=l15][k = jt*16 + quad*4 + r], K from global
        floatx4 s[16];
#pragma unroll
        for (int jt = 0; jt < 16; jt++) s[jt] = (floatx4){0.f, 0.f, 0.f, 0.f};
#pragma unroll
        for (int jt = 0; jt < 16; jt++) {
            bf16x8 k0 = *(const bf16x8*)(krow + jt * 16 * DH);
            bf16x8 k1 = *(const bf16x8*)(krow + jt * 16 * DH + 32);
            s[jt] = __builtin_amdgcn_mfma_f32_16x16x32_bf16(k0, qc0, s[jt], 0, 0, 0);
            s[jt] = __builtin_amdgcn_mfma_f32_16x16x32_bf16(k1, qc1, s[jt], 0, 0, 0);
        }

        // prefetch next tile's Q under softmax
        bf16x8 qn0 = qc0, qn1 = qc1;
        if (t == 0) {
            qn0 = *(const bf16x8*)(qrow + 64 * DH);
            qn1 = *(const bf16x8*)(qrow + 64 * DH + 32);
        }

        // softmax: row q=l15 spread over quads -> 2 shuffles per reduce
        float mx = s[0][0];
#pragma unroll
        for (int jt = 0; jt < 16; jt++)
#pragma unroll
            for (int r = 0; r < 4; r++) mx = fmaxf(mx, s[jt][r]);
        mx = fmaxf(mx, __shfl_xor(mx, 16, 64));
        mx = fmaxf(mx, __shfl_xor(mx, 32, 64));
        float mc = mx * C;
        float sm = 0.f;
#pragma unroll
        for (int jt = 0; jt < 16; jt++)
#pragma unroll
            for (int r = 0; r < 4; r++) {
                float e = exp2f(s[jt][r] * C - mc);
                s[jt][r] = e;
                sm += e;
            }
        sm += __shfl_xor(sm, 16, 64);
        sm += __shfl_xor(sm, 32, 64);
        float pinv = 1.f / sm;

        if (t == 0) __syncthreads();  // V staging drain, hidden under QK^T+softmax

        // PV: reshape P (S^T regs) -> 16x16x32 A-frags via pack + half-swap + xor16
        floatx4 oacc[4];
#pragma unroll
        for (int nt = 0; nt < 4; nt++) oacc[nt] = (floatx4){0.f, 0.f, 0.f, 0.f};
#pragma unroll
        for (int kk = 0; kk < 8; kk++) {
            floatx4 se = s[2 * kk], so = s[2 * kk + 1];
            unsigned E0 = cvtpk(se[0] * pinv, se[1] * pinv);
            unsigned E1 = cvtpk(se[2] * pinv, se[3] * pinv);
            unsigned D0 = cvtpk(so[0] * pinv, so[1] * pinv);
            unsigned D1 = cvtpk(so[2] * pinv, so[3] * pinv);
            unsigned lo0, hi0, lo1, hi1;
            halfswap(E0, D0, lo0, hi0);
            halfswap(E1, D1, lo1, hi1);
            unsigned sel0 = (quad & 1) ? hi0 : lo0;
            unsigned sel1 = (quad & 1) ? hi1 : lo1;
            unsigned x0 = (unsigned)__shfl_xor((int)sel0, 16, 64);
            unsigned x1 = (unsigned)__shfl_xor((int)sel1, 16, 64);
            union { unsigned u[4]; bf16x8 v; } pf;
            pf.u[0] = (quad & 1) ? x0 : sel0;
            pf.u[1] = (quad & 1) ? x1 : sel1;
            pf.u[2] = (quad & 1) ? sel0 : x0;
            pf.u[3] = (quad & 1) ? sel1 : x1;
#pragma unroll
            for (int nt = 0; nt < 4; nt++) {
                int d = nt * 16 + l15;
                bf16x8 bv = *(const bf16x8*)&Vl[d * 256 + ((kk * 4 + quad) ^ (d & 15)) * 8];
                oacc[nt] = __builtin_amdgcn_mfma_f32_16x16x32_bf16(pf.v, bv, oacc[nt], 0, 0, 0);
            }
        }

        // C-layout -> per-wave LDS slice -> coalesced [p][c] store
#pragma unroll
        for (int nt = 0; nt < 4; nt++)
#pragma unroll
            for (int r = 0; r < 4; r++)
                Ot[wave][quad * 4 + r][nt * 16 + l15] = f2bu(oacc[nt][r]);
        int row = lane >> 2, d0 = (lane & 3) * 16;
        uint4 ld0 = *(const uint4*)&Ot[wave][row][d0];
        uint4 ld1 = *(const uint4*)&Ot[wave][row][d0 + 8];
        bf16* dst = ao + ((size_t)b * PQ + p0 + t * 64 + row) * INNER + h * DH + d0;
        *(uint4*)dst = ld0;
        *(uint4*)(dst + 8) = ld1;

        qc0 = qn0; qc1 = qn1;
    }
}

extern "C" void kernel_launch(void* const* d_in, const int* in_sizes, int n_in,
                              void* d_out, int out_size, void* d_ws, size_t ws_size,
                              hipStream_t stream) {
    const void* x        = d_in[0];
    const void* q_dw     = d_in[1];
    const void* q_gamma  = d_in[2];
    const void* q_beta   = d_in[3];
    const void* q_mean   = d_in[4];
    const void* q_var    = d_in[5];
    const void* q_pw     = d_in[6];
    const void* kv_dw    = d_in[7];
    const void* kv_gamma = d_in[8];
    const void* kv_beta  = d_in[9];
    const void* kv_mean  = d_in[10];
    const void* kv_var   = d_in[11];
    const void* kv_pw    = d_in[12];
    const void* out_w    = d_in[13];
    const void* out_b    = d_in[14];

    bf16* pool = (bf16*)((char*)d_ws + 256);
    bf16* yqt  = pool;                              // [32,1024,384] Y^T Q-path; reused as aob
    bf16* ykvt = yqt  + (size_t)32 * 1024 * 384;    // [32,256,384]  Y^T KV-path
    bf16* qalt = ykvt + (size_t)32 * 256 * 384;     // [32,6,1024,64]
    bf16* kalt = qalt + (size_t)32 * 6 * 1024 * 64; // [32,6,256,64]
    bf16* valt = kalt + (size_t)32 * 6 * 256 * 64;  // [32,384,256]
    bf16* wbf  = valt + (size_t)32 * 384 * 256;     // q_pw | kv_pw | out_w bf16
    bf16* qpw_bf = wbf;
    bf16* kvpw_bf = wbf + (size_t)INNER * CIN;
    bf16* outw_bf = kvpw_bf + (size_t)2 * INNER * CIN;
    bf16* aob  = yqt;  // alias: yqt dead after Q pointwise; attn writes [b][p][c]

    wconv_kernel<<<576, 256, 0, stream>>>(q_pw, kv_pw, out_w, wbf, x);
    dw_bn_kernel<1, 32, 32><<<dim3(4, 12, 32), 256, 0, stream>>>(x, q_dw, q_gamma, q_beta, q_mean, q_var, yqt);
    dw_bn_kernel<2, 16, 16><<<dim3(2, 12, 32), 256, 0, stream>>>(x, kv_dw, kv_gamma, kv_beta, kv_mean, kv_var, ykvt);
    mfma_pw<1024, 0><<<dim3(8, 3, 32), 256, 0, stream>>>(qpw_bf, yqt, nullptr, qalt, nullptr, INNER, x);
    mfma_pw<256, 1><<<dim3(2, 6, 32), 256, 0, stream>>>(kvpw_bf, ykvt, nullptr, kalt, valt, 2 * INNER, x);
    attn_kernel<<<1536, 256, 0, stream>>>(qalt, kalt, valt, aob);
    mfma_pw<1024, 2><<<dim3(8, 3, 32), 256, 0, stream>>>(outw_bf, aob, out_b, d_out, nullptr, CIN, x);
}

// Round 6
// 241.905 us; speedup vs baseline: 1.0892x; 1.0892x over previous
//
#include <hip/hip_runtime.h>
#include <hip/hip_bf16.h>

#define CIN 384
#define PQ 1024
#define PKV 256
#define HEADS 6
#define DH 64
#define INNER 384
#define ATTN_SCALE 0.125f

typedef __hip_bfloat16 bf16;
typedef unsigned short ushort;
typedef __bf16 bf16x8 __attribute__((ext_vector_type(8)));
typedef float floatx4 __attribute__((ext_vector_type(4)));

__device__ __forceinline__ float b2f(bf16 v) { return __bfloat162float(v); }
__device__ __forceinline__ bf16 f2b(float v) { return __float2bfloat16(v); }
__device__ __forceinline__ ushort f2bu(float v) { bf16 h = __float2bfloat16(v); return *(ushort*)&h; }
__device__ __forceinline__ float ldf(const void* p, size_t i, int isbf) {
    return isbf ? __bfloat162float(((const bf16*)p)[i]) : ((const float*)p)[i];
}
// async global->LDS DMA, 16B per lane; LDS dest = uniform base + lane*16
__device__ __forceinline__ void dma16(const bf16* g, bf16* l) {
    __builtin_amdgcn_global_load_lds(
        (const __attribute__((address_space(1))) unsigned int*)g,
        (__attribute__((address_space(3))) unsigned int*)l, 16, 0, 0);
}
// uniform scalar dtype probe
__device__ __forceinline__ int probe_isbf(const void* x) {
    const unsigned* u = (const unsigned*)x;
    int cnt = 0;
    for (int i = 0; i < 64; i++) {
        unsigned e = (u[i] >> 7) & 0xFFu;
        cnt += (e >= 100u && e <= 140u) ? 1 : 0;
    }
    return cnt >= 48 ? 1 : 0;
}
__device__ __forceinline__ unsigned cvtpk(float lo, float hi) {
    unsigned r;
    asm("v_cvt_pk_bf16_f32 %0, %1, %2" : "=v"(r) : "v"(lo), "v"(hi));
    return r;
}
// half-wave swap: lo = [a(lanes0-31) | b(lanes0-31)], hi = [a(32-63) | b(32-63)]
__device__ __forceinline__ void halfswap(unsigned a, unsigned b, unsigned& lo, unsigned& hi) {
#if __has_builtin(__builtin_amdgcn_permlane32_swap)
    auto r = __builtin_amdgcn_permlane32_swap(a, b, false, false);
    lo = r[0]; hi = r[1];
#else
    unsigned ax = (unsigned)__shfl_xor((int)a, 32, 64);
    unsigned bx = (unsigned)__shfl_xor((int)b, 32, 64);
    bool lower = (threadIdx.x & 32) == 0;
    lo = lower ? a : bx;
    hi = lower ? ax : b;
#endif
}

// ---------------- weight convert: 3 segments -> contiguous bf16 ------------------
__global__ void wconv_kernel(const void* __restrict__ w0, const void* __restrict__ w1,
                             const void* __restrict__ w2, bf16* __restrict__ dst,
                             const void* __restrict__ xprobe) {
    int isbf = probe_isbf(xprobe);
    const int n0 = INNER * CIN, n1 = 2 * INNER * CIN, n2 = INNER * CIN;
    int i = blockIdx.x * 256 + threadIdx.x;
    int total = n0 + n1 + n2;
    for (; i < total; i += gridDim.x * 256) {
        float v;
        if (i < n0) v = ldf(w0, i, isbf);
        else if (i < n0 + n1) v = ldf(w1, i - n0, isbf);
        else v = ldf(w2, i - n0 - n1, isbf);
        dst[i] = f2b(v);
    }
}

// ---------------- depthwise 3x3 + BN -> Y^T [b][p][c] ----------------------------
template <int STRIDE, int HO, int WO>
__global__ __launch_bounds__(256) void dw_bn_kernel(
        const void* __restrict__ x, const void* __restrict__ wdw,
        const void* __restrict__ gamma, const void* __restrict__ beta,
        const void* __restrict__ mean, const void* __restrict__ var,
        bf16* __restrict__ yt) {
    constexpr int IN_ROWS = (8 - 1) * STRIDE + 3;       // 10 or 17
    constexpr int RL = 37;                              // slab stride 370%32=18 -> 2-way
    constexpr int PT = 8 * WO;
    constexpr unsigned XSZ = 32u * IN_ROWS * RL * 4;
    constexpr unsigned OSZ = (unsigned)PT * 40 * 2;
    __shared__ __align__(16) char smem[XSZ > OSZ ? XSZ : OSZ];
    float (*xin)[IN_ROWS][RL] = (float (*)[IN_ROWS][RL])smem;  // [cc][i][1+w]
    ushort (*outt)[40] = (ushort (*)[40])smem;                 // [g*WO+wo][cc]

    int isbf = probe_isbf(x);
    int rg = blockIdx.x;
    int c0 = blockIdx.y * 32;
    int b  = blockIdx.z;
    int tid = threadIdx.x;
    int ri0 = rg * 8 * STRIDE - 1;

    for (int e = tid; e < 32 * IN_ROWS; e += 256) {
        int i = e % IN_ROWS, cc = e / IN_ROWS;
        xin[cc][i][0] = 0.f;
        xin[cc][i][33] = 0.f;
    }

    const int NCHUNK = 32 * IN_ROWS * 4;
    for (int ch = tid; ch < NCHUNK; ch += 256) {
        int wc = ch & 3;
        int t  = ch >> 2;
        int i  = t % IN_ROWS;
        int cc = t / IN_ROWS;
        int row = ri0 + i;
        float f[8];
        if (row >= 0 && row < 32) {
            size_t goff = ((size_t)(b * CIN + c0 + cc) * 32 + row) * 32 + wc * 8;
            if (isbf) {
                uint4 v = *(const uint4*)((const bf16*)x + goff);
                const ushort* u = (const ushort*)&v;
#pragma unroll
                for (int j = 0; j < 8; j++) f[j] = __uint_as_float((unsigned)u[j] << 16);
            } else {
                float4 v0 = *(const float4*)((const float*)x + goff);
                float4 v1 = *(const float4*)((const float*)x + goff + 4);
                f[0] = v0.x; f[1] = v0.y; f[2] = v0.z; f[3] = v0.w;
                f[4] = v1.x; f[5] = v1.y; f[6] = v1.z; f[7] = v1.w;
            }
        } else {
#pragma unroll
            for (int j = 0; j < 8; j++) f[j] = 0.f;
        }
        float* dst = &xin[cc][i][1 + wc * 8];
#pragma unroll
        for (int j = 0; j < 8; j++) dst[j] = f[j];
    }

    int cc = tid & 31;
    int g  = tid >> 5;
    int c  = c0 + cc;
    float w9[9];
#pragma unroll
    for (int k = 0; k < 9; k++) w9[k] = ldf(wdw, c * 9 + k, isbf);
    float inv  = ldf(gamma, c, isbf) * rsqrtf(ldf(var, c, isbf) + 1e-5f);
    float bias = ldf(beta, c, isbf) - ldf(mean, c, isbf) * inv;
    __syncthreads();

    const float* xr0 = xin[cc][g * STRIDE + 0];
    const float* xr1 = xin[cc][g * STRIDE + 1];
    const float* xr2 = xin[cc][g * STRIDE + 2];
    float o[WO];
    if (STRIDE == 1) {
        float a0 = xr0[0], a1 = xr0[1];
        float b0 = xr1[0], b1 = xr1[1];
        float q0 = xr2[0], q1 = xr2[1];
#pragma unroll
        for (int wo = 0; wo < WO; wo++) {
            float a2 = xr0[wo + 2], b2 = xr1[wo + 2], q2 = xr2[wo + 2];
            float acc = w9[0] * a0 + w9[1] * a1 + w9[2] * a2
                      + w9[3] * b0 + w9[4] * b1 + w9[5] * b2
                      + w9[6] * q0 + w9[7] * q1 + w9[8] * q2;
            o[wo] = acc * inv + bias;
            a0 = a1; a1 = a2; b0 = b1; b1 = b2; q0 = q1; q1 = q2;
        }
    } else {
        float a0 = xr0[0], b0 = xr1[0], q0 = xr2[0];
#pragma unroll
        for (int wo = 0; wo < WO; wo++) {
            float a1 = xr0[2 * wo + 1], a2 = xr0[2 * wo + 2];
            float b1 = xr1[2 * wo + 1], b2 = xr1[2 * wo + 2];
            float q1 = xr2[2 * wo + 1], q2 = xr2[2 * wo + 2];
            float acc = w9[0] * a0 + w9[1] * a1 + w9[2] * a2
                      + w9[3] * b0 + w9[4] * b1 + w9[5] * b2
                      + w9[6] * q0 + w9[7] * q1 + w9[8] * q2;
            o[wo] = acc * inv + bias;
            a0 = a2; b0 = b2; q0 = q2;
        }
    }
    __syncthreads();

#pragma unroll
    for (int wo = 0; wo < WO; wo++) outt[g * WO + wo][cc] = f2bu(o[wo]);
    __syncthreads();

    const size_t pbase = (size_t)b * (HO * WO) + (size_t)rg * 8 * WO;
    for (int chk = tid; chk < PT * 4; chk += 256) {
        int k = chk & 3, p = chk >> 2;
        uint4 v = *(const uint4*)&outt[p][k * 8];
        *(uint4*)(yt + (pbase + p) * CIN + c0 + k * 8) = v;
    }
}

// ---------------- MFMA pointwise GEMM, BK=32, double-buffered --------------------
// C^T[p][o] = sum_c Yt[b][p][c] * W[o][c]. 128x128 tile.
// LDS rows 64B (4x16B chunks), chunk slot = c ^ (row&3) -> <=4-way on ds_read_b128.
template <int P, int MODE>
__global__ __launch_bounds__(256, 2) void mfma_pw(
        const bf16* __restrict__ wt, const bf16* __restrict__ yt,
        const void* __restrict__ bias, void* __restrict__ out0,
        bf16* __restrict__ out1, int O, const void* __restrict__ xprobe) {
    __shared__ __align__(16) bf16 As[2][4096];  // 128 rows x 32 k
    __shared__ __align__(16) bf16 Bs[2][4096];
    int tid = threadIdx.x;
    int wave = tid >> 6, lane = tid & 63;
    int l15 = lane & 15, quad = lane >> 4;
    int wm = wave & 1, wn = wave >> 1;
    int b = blockIdx.z;
    int p0 = blockIdx.x * 128;
    int o0 = blockIdx.y * 128;

    const bf16* asrc = yt + ((size_t)b * P + p0) * CIN;
    const bf16* bsrc = wt + (size_t)o0 * CIN;

    int srow = (lane >> 2);
    int sc   = lane & 3;
    auto stage = [&](int step, int buf) {
#pragma unroll
        for (int it = 0; it < 2; it++) {
            int row = wave * 32 + it * 16 + srow;
            int g = sc ^ (row & 3);
            size_t goff = (size_t)row * CIN + step * 32 + g * 8;
            dma16(asrc + goff, &As[buf][(wave * 2 + it) * 512]);
            dma16(bsrc + goff, &Bs[buf][(wave * 2 + it) * 512]);
        }
    };

    floatx4 acc[4][4];
#pragma unroll
    for (int pt = 0; pt < 4; pt++)
#pragma unroll
        for (int ot = 0; ot < 4; ot++) acc[pt][ot] = (floatx4){0.f, 0.f, 0.f, 0.f};

    stage(0, 0);
    __syncthreads();
    for (int s = 0; s < CIN / 32; s++) {
        int buf = s & 1;
        if (s < CIN / 32 - 1) stage(s + 1, buf ^ 1);
        bf16x8 af[4], bw[4];
        int slot = (quad ^ (l15 & 3)) * 8;
#pragma unroll
        for (int pt = 0; pt < 4; pt++)
            af[pt] = *(const bf16x8*)&As[buf][(wm * 64 + pt * 16 + l15) * 32 + slot];
#pragma unroll
        for (int ot = 0; ot < 4; ot++)
            bw[ot] = *(const bf16x8*)&Bs[buf][(wn * 64 + ot * 16 + l15) * 32 + slot];
#pragma unroll
        for (int pt = 0; pt < 4; pt++)
#pragma unroll
            for (int ot = 0; ot < 4; ot++)
                acc[pt][ot] = __builtin_amdgcn_mfma_f32_16x16x32_bf16(af[pt], bw[ot], acc[pt][ot], 0, 0, 0);
        __syncthreads();
    }

    int pw0 = p0 + wm * 64, ow0 = o0 + wn * 64;
    if (MODE == 2) {
        int isbf = probe_isbf(xprobe);
#pragma unroll
        for (int ot = 0; ot < 4; ot++) {
            int o = ow0 + ot * 16 + l15;
            float bv = ldf(bias, o, isbf);
#pragma unroll
            for (int pt = 0; pt < 4; pt++) {
                int p = pw0 + pt * 16 + quad * 4;
                size_t idx = ((size_t)b * O + o) * P + p;
                if (!isbf) {
                    float4 v4 = {acc[pt][ot][0] + bv, acc[pt][ot][1] + bv,
                                 acc[pt][ot][2] + bv, acc[pt][ot][3] + bv};
                    *(float4*)((float*)out0 + idx) = v4;
                } else {
                    ushort4 u4 = {f2bu(acc[pt][ot][0] + bv), f2bu(acc[pt][ot][1] + bv),
                                  f2bu(acc[pt][ot][2] + bv), f2bu(acc[pt][ot][3] + bv)};
                    *(ushort4*)((bf16*)out0 + idx) = u4;
                }
            }
        }
    } else if (MODE == 0) {
#pragma unroll
        for (int ot = 0; ot < 4; ot++) {
            int o = ow0 + ot * 16 + l15;
            int h = o >> 6, d = o & 63;
            bf16* base = (bf16*)out0 + ((size_t)(b * HEADS + h) * P) * 64 + d;
#pragma unroll
            for (int pt = 0; pt < 4; pt++)
#pragma unroll
                for (int r = 0; r < 4; r++)
                    base[(size_t)(pw0 + pt * 16 + quad * 4 + r) * 64] = f2b(acc[pt][ot][r]);
        }
    } else {  // MODE 1: K | V fused
#pragma unroll
        for (int ot = 0; ot < 4; ot++) {
            int o = ow0 + ot * 16 + l15;
            if (o < INNER) {
                int h = o >> 6, d = o & 63;
                bf16* base = (bf16*)out0 + ((size_t)(b * HEADS + h) * P) * 64 + d;
#pragma unroll
                for (int pt = 0; pt < 4; pt++)
#pragma unroll
                    for (int r = 0; r < 4; r++)
                        base[(size_t)(pw0 + pt * 16 + quad * 4 + r) * 64] = f2b(acc[pt][ot][r]);
            } else {
                int ch = o - INNER;
                bf16* base = out1 + ((size_t)b * INNER + ch) * PKV;
#pragma unroll
                for (int pt = 0; pt < 4; pt++)
#pragma unroll
                    for (int r = 0; r < 4; r++)
                        base[pw0 + pt * 16 + quad * 4 + r] = f2b(acc[pt][ot][r]);
            }
        }
    }
}

// ---------------- fused MFMA attention v5: round-2 shell + round-3 PV ------------
// K+V staged ONCE in LDS per block (74KB, 2 blocks/CU); 4-tile barrier-free loop.
// Swapped S^T = mfma(K,Q) keeps P in registers; round-3's PROVEN reshape
// (cvt_pk + permlane32_swap + xor16, sel = qodd ? hi : lo) builds 16x16x32
// A-frags; PV = mfma(P, V) wide MFMAs with conflict-free b128 V reads; output
// through per-wave Ot slice (round-2's proven coalesced store).
__global__ __launch_bounds__(256, 2) void attn_kernel(
        const bf16* __restrict__ qalt, const bf16* __restrict__ kalt,
        const bf16* __restrict__ valt, bf16* __restrict__ ao) {
    __shared__ __align__(16) bf16 Kl[16384];        // 32 KB, persistent
    __shared__ __align__(16) bf16 Vl[16384];        // 32 KB, persistent
    __shared__ __align__(16) ushort Ot[4][16][80];  // 10 KB, per-wave scratch
    int tid = threadIdx.x;
    int wave = tid >> 6, lane = tid & 63;
    int l15 = lane & 15, quad = lane >> 4;
    int blk = blockIdx.x;
    int swz = (blk & 7) * 96 + (blk >> 3);   // 768 = 8*96, bijective
    int seg = swz & 3;                        // 4 segments of 256 Q rows
    int bh  = swz >> 2;                       // 4 consecutive segs share (b,h) & XCD
    int b = bh / HEADS, h = bh % HEADS;

    const bf16* qbase = qalt + (size_t)(b * HEADS + h) * PQ * DH;
    const bf16* kbase = kalt + (size_t)(b * HEADS + h) * PKV * DH;
    const bf16* vbase = valt + ((size_t)b * INNER + h * DH) * PKV;

    // stage K: rows 128B, granule slot = cs ^ (row&7)
    {
        int j = lane >> 3, cs = lane & 7;
#pragma unroll
        for (int it = 0; it < 8; it++) {
            int jr = (wave * 8 + it) * 8 + j;
            int g = cs ^ (jr & 7);
            dma16(kbase + (size_t)jr * 64 + g * 8, &Kl[(wave * 8 + it) * 512]);
        }
        // stage V: rows 512B, granule slot = cs2 ^ (row&15)
        int d = lane >> 5, cs2 = lane & 31;
#pragma unroll
        for (int it = 0; it < 8; it++) {
            int dr = (wave * 8 + it) * 2 + d;
            int g = cs2 ^ (dr & 15);
            dma16(vbase + (size_t)dr * 256 + g * 8, &Vl[(wave * 8 + it) * 512]);
        }
    }

    int p0 = seg * 256 + wave * 16;  // tile t adds t*64
    const bf16* qrow = qbase + (size_t)(p0 + l15) * DH + quad * 8;
    bf16x8 qc0 = *(const bf16x8*)qrow;          // overlaps the K/V DMA
    bf16x8 qc1 = *(const bf16x8*)(qrow + 32);
    __syncthreads();  // drains DMA (vmcnt) + cross-wave staging visibility

    const float C = ATTN_SCALE * 1.44269504f;   // fold scale into exp2

#pragma unroll
    for (int t = 0; t < 4; t++) {
        // prefetch next tile's Q under this tile's compute
        bf16x8 qn0 = qc0, qn1 = qc1;
        if (t < 3) {
            const bf16* qr = qrow + (size_t)(t + 1) * 64 * DH;
            qn0 = *(const bf16x8*)qr;
            qn1 = *(const bf16x8*)(qr + 32);
        }

        // S^T = K Q^T : lane holds S[q=l15][k = jt*16 + quad*4 + r]
        floatx4 s[16];
#pragma unroll
        for (int jt = 0; jt < 16; jt++) s[jt] = (floatx4){0.f, 0.f, 0.f, 0.f};
#pragma unroll
        for (int jt = 0; jt < 16; jt++) {
            int j = jt * 16 + l15;
            bf16x8 k0 = *(const bf16x8*)&Kl[j * 64 + (quad ^ (j & 7)) * 8];
            bf16x8 k1 = *(const bf16x8*)&Kl[j * 64 + ((4 + quad) ^ (j & 7)) * 8];
            s[jt] = __builtin_amdgcn_mfma_f32_16x16x32_bf16(k0, qc0, s[jt], 0, 0, 0);
            s[jt] = __builtin_amdgcn_mfma_f32_16x16x32_bf16(k1, qc1, s[jt], 0, 0, 0);
        }

        // softmax: row q=l15 spread over quads -> 2 shuffles per reduce
        float mx = s[0][0];
#pragma unroll
        for (int jt = 0; jt < 16; jt++)
#pragma unroll
            for (int r = 0; r < 4; r++) mx = fmaxf(mx, s[jt][r]);
        mx = fmaxf(mx, __shfl_xor(mx, 16, 64));
        mx = fmaxf(mx, __shfl_xor(mx, 32, 64));
        float mc = mx * C;
        float sm = 0.f;
#pragma unroll
        for (int jt = 0; jt < 16; jt++)
#pragma unroll
            for (int r = 0; r < 4; r++) {
                float e = exp2f(s[jt][r] * C - mc);
                s[jt][r] = e;
                sm += e;
            }
        sm += __shfl_xor(sm, 16, 64);
        sm += __shfl_xor(sm, 32, 64);
        float pinv = 1.f / sm;

        // PV: round-3's PROVEN reshape P (S^T regs) -> 16x16x32 A-frags
        floatx4 oacc[4];
#pragma unroll
        for (int nt = 0; nt < 4; nt++) oacc[nt] = (floatx4){0.f, 0.f, 0.f, 0.f};
#pragma unroll
        for (int kk = 0; kk < 8; kk++) {
            floatx4 se = s[2 * kk], so = s[2 * kk + 1];
            unsigned E0 = cvtpk(se[0] * pinv, se[1] * pinv);
            unsigned E1 = cvtpk(se[2] * pinv, se[3] * pinv);
            unsigned D0 = cvtpk(so[0] * pinv, so[1] * pinv);
            unsigned D1 = cvtpk(so[2] * pinv, so[3] * pinv);
            unsigned lo0, hi0, lo1, hi1;
            halfswap(E0, D0, lo0, hi0);
            halfswap(E1, D1, lo1, hi1);
            unsigned sel0 = (quad & 1) ? hi0 : lo0;
            unsigned sel1 = (quad & 1) ? hi1 : lo1;
            unsigned x0 = (unsigned)__shfl_xor((int)sel0, 16, 64);
            unsigned x1 = (unsigned)__shfl_xor((int)sel1, 16, 64);
            union { unsigned u[4]; bf16x8 v; } pf;
            pf.u[0] = (quad & 1) ? x0 : sel0;
            pf.u[1] = (quad & 1) ? x1 : sel1;
            pf.u[2] = (quad & 1) ? sel0 : x0;
            pf.u[3] = (quad & 1) ? sel1 : x1;
#pragma unroll
            for (int nt = 0; nt < 4; nt++) {
                int d = nt * 16 + l15;
                bf16x8 bv = *(const bf16x8*)&Vl[d * 256 + ((kk * 4 + quad) ^ (d & 15)) * 8];
                oacc[nt] = __builtin_amdgcn_mfma_f32_16x16x32_bf16(pf.v, bv, oacc[nt], 0, 0, 0);
            }
        }

        // C-layout -> per-wave LDS slice -> coalesced [p][c] store (round-2 proven)
#pragma unroll
        for (int nt = 0; nt < 4; nt++)
#pragma unroll
            for (int r = 0; r < 4; r++)
                Ot[wave][quad * 4 + r][nt * 16 + l15] = f2bu(oacc[nt][r]);
        int row = lane >> 2, d0 = (lane & 3) * 16;
        uint4 ld0 = *(const uint4*)&Ot[wave][row][d0];
        uint4 ld1 = *(const uint4*)&Ot[wave][row][d0 + 8];
        bf16* dst = ao + ((size_t)b * PQ + p0 + t * 64 + row) * INNER + h * DH + d0;
        *(uint4*)dst = ld0;
        *(uint4*)(dst + 8) = ld1;

        qc0 = qn0; qc1 = qn1;
    }
}

extern "C" void kernel_launch(void* const* d_in, const int* in_sizes, int n_in,
                              void* d_out, int out_size, void* d_ws, size_t ws_size,
                              hipStream_t stream) {
    const void* x        = d_in[0];
    const void* q_dw     = d_in[1];
    const void* q_gamma  = d_in[2];
    const void* q_beta   = d_in[3];
    const void* q_mean   = d_in[4];
    const void* q_var    = d_in[5];
    const void* q_pw     = d_in[6];
    const void* kv_dw    = d_in[7];
    const void* kv_gamma = d_in[8];
    const void* kv_beta  = d_in[9];
    const void* kv_mean  = d_in[10];
    const void* kv_var   = d_in[11];
    const void* kv_pw    = d_in[12];
    const void* out_w    = d_in[13];
    const void* out_b    = d_in[14];

    bf16* pool = (bf16*)((char*)d_ws + 256);
    bf16* yqt  = pool;                              // [32,1024,384] Y^T Q-path; reused as aob
    bf16* ykvt = yqt  + (size_t)32 * 1024 * 384;    // [32,256,384]  Y^T KV-path
    bf16* qalt = ykvt + (size_t)32 * 256 * 384;     // [32,6,1024,64]
    bf16* kalt = qalt + (size_t)32 * 6 * 1024 * 64; // [32,6,256,64]
    bf16* valt = kalt + (size_t)32 * 6 * 256 * 64;  // [32,384,256]
    bf16* wbf  = valt + (size_t)32 * 384 * 256;     // q_pw | kv_pw | out_w bf16
    bf16* qpw_bf = wbf;
    bf16* kvpw_bf = wbf + (size_t)INNER * CIN;
    bf16* outw_bf = kvpw_bf + (size_t)2 * INNER * CIN;
    bf16* aob  = yqt;  // alias: yqt dead after Q pointwise; attn writes [b][p][c]

    wconv_kernel<<<576, 256, 0, stream>>>(q_pw, kv_pw, out_w, wbf, x);
    dw_bn_kernel<1, 32, 32><<<dim3(4, 12, 32), 256, 0, stream>>>(x, q_dw, q_gamma, q_beta, q_mean, q_var, yqt);
    dw_bn_kernel<2, 16, 16><<<dim3(2, 12, 32), 256, 0, stream>>>(x, kv_dw, kv_gamma, kv_beta, kv_mean, kv_var, ykvt);
    mfma_pw<1024, 0><<<dim3(8, 3, 32), 256, 0, stream>>>(qpw_bf, yqt, nullptr, qalt, nullptr, INNER, x);
    mfma_pw<256, 1><<<dim3(2, 6, 32), 256, 0, stream>>>(kvpw_bf, ykvt, nullptr, kalt, valt, 2 * INNER, x);
    attn_kernel<<<768, 256, 0, stream>>>(qalt, kalt, valt, aob);
    mfma_pw<1024, 2><<<dim3(8, 3, 32), 256, 0, stream>>>(outw_bf, aob, out_b, d_out, nullptr, CIN, x);
}

// Round 7
// 240.173 us; speedup vs baseline: 1.0970x; 1.0072x over previous
//
#include <hip/hip_runtime.h>
#include <hip/hip_bf16.h>

#define CIN 384
#define PQ 1024
#define PKV 256
#define HEADS 6
#define DH 64
#define INNER 384
#define ATTN_SCALE 0.125f

typedef __hip_bfloat16 bf16;
typedef unsigned short ushort;
typedef __bf16 bf16x8 __attribute__((ext_vector_type(8)));
typedef float floatx4 __attribute__((ext_vector_type(4)));

__device__ __forceinline__ float b2f(bf16 v) { return __bfloat162float(v); }
__device__ __forceinline__ bf16 f2b(float v) { return __float2bfloat16(v); }
__device__ __forceinline__ ushort f2bu(float v) { bf16 h = __float2bfloat16(v); return *(ushort*)&h; }
__device__ __forceinline__ float ldf(const void* p, size_t i, int isbf) {
    return isbf ? __bfloat162float(((const bf16*)p)[i]) : ((const float*)p)[i];
}
// async global->LDS DMA, 16B per lane; LDS dest = uniform base + lane*16
__device__ __forceinline__ void dma16(const bf16* g, bf16* l) {
    __builtin_amdgcn_global_load_lds(
        (const __attribute__((address_space(1))) unsigned int*)g,
        (__attribute__((address_space(3))) unsigned int*)l, 16, 0, 0);
}
// uniform scalar dtype probe
__device__ __forceinline__ int probe_isbf(const void* x) {
    const unsigned* u = (const unsigned*)x;
    int cnt = 0;
    for (int i = 0; i < 64; i++) {
        unsigned e = (u[i] >> 7) & 0xFFu;
        cnt += (e >= 100u && e <= 140u) ? 1 : 0;
    }
    return cnt >= 48 ? 1 : 0;
}
__device__ __forceinline__ unsigned cvtpk(float lo, float hi) {
    unsigned r;
    asm("v_cvt_pk_bf16_f32 %0, %1, %2" : "=v"(r) : "v"(lo), "v"(hi));
    return r;
}
// half-wave swap: lo = [a(lanes0-31) | b(lanes0-31)], hi = [a(32-63) | b(32-63)]
__device__ __forceinline__ void halfswap(unsigned a, unsigned b, unsigned& lo, unsigned& hi) {
#if __has_builtin(__builtin_amdgcn_permlane32_swap)
    auto r = __builtin_amdgcn_permlane32_swap(a, b, false, false);
    lo = r[0]; hi = r[1];
#else
    unsigned ax = (unsigned)__shfl_xor((int)a, 32, 64);
    unsigned bx = (unsigned)__shfl_xor((int)b, 32, 64);
    bool lower = (threadIdx.x & 32) == 0;
    lo = lower ? a : bx;
    hi = lower ? ax : b;
#endif
}

// ---------------- weight convert: 3 segments -> contiguous bf16 ------------------
__global__ void wconv_kernel(const void* __restrict__ w0, const void* __restrict__ w1,
                             const void* __restrict__ w2, bf16* __restrict__ dst,
                             const void* __restrict__ xprobe) {
    int isbf = probe_isbf(xprobe);
    const int n0 = INNER * CIN, n1 = 2 * INNER * CIN, n2 = INNER * CIN;
    int i = blockIdx.x * 256 + threadIdx.x;
    int total = n0 + n1 + n2;
    for (; i < total; i += gridDim.x * 256) {
        float v;
        if (i < n0) v = ldf(w0, i, isbf);
        else if (i < n0 + n1) v = ldf(w1, i - n0, isbf);
        else v = ldf(w2, i - n0 - n1, isbf);
        dst[i] = f2b(v);
    }
}

// ---------------- depthwise 3x3 + BN -> Y^T [b][p][c] ----------------------------
template <int STRIDE, int HO, int WO>
__global__ __launch_bounds__(256) void dw_bn_kernel(
        const void* __restrict__ x, const void* __restrict__ wdw,
        const void* __restrict__ gamma, const void* __restrict__ beta,
        const void* __restrict__ mean, const void* __restrict__ var,
        bf16* __restrict__ yt) {
    constexpr int IN_ROWS = (8 - 1) * STRIDE + 3;       // 10 or 17
    constexpr int RL = 37;                              // slab stride 370%32=18 -> 2-way
    constexpr int PT = 8 * WO;
    constexpr unsigned XSZ = 32u * IN_ROWS * RL * 4;
    constexpr unsigned OSZ = (unsigned)PT * 40 * 2;
    __shared__ __align__(16) char smem[XSZ > OSZ ? XSZ : OSZ];
    float (*xin)[IN_ROWS][RL] = (float (*)[IN_ROWS][RL])smem;  // [cc][i][1+w]
    ushort (*outt)[40] = (ushort (*)[40])smem;                 // [g*WO+wo][cc]

    int isbf = probe_isbf(x);
    int rg = blockIdx.x;
    int c0 = blockIdx.y * 32;
    int b  = blockIdx.z;
    int tid = threadIdx.x;
    int ri0 = rg * 8 * STRIDE - 1;

    for (int e = tid; e < 32 * IN_ROWS; e += 256) {
        int i = e % IN_ROWS, cc = e / IN_ROWS;
        xin[cc][i][0] = 0.f;
        xin[cc][i][33] = 0.f;
    }

    const int NCHUNK = 32 * IN_ROWS * 4;
    for (int ch = tid; ch < NCHUNK; ch += 256) {
        int wc = ch & 3;
        int t  = ch >> 2;
        int i  = t % IN_ROWS;
        int cc = t / IN_ROWS;
        int row = ri0 + i;
        float f[8];
        if (row >= 0 && row < 32) {
            size_t goff = ((size_t)(b * CIN + c0 + cc) * 32 + row) * 32 + wc * 8;
            if (isbf) {
                uint4 v = *(const uint4*)((const bf16*)x + goff);
                const ushort* u = (const ushort*)&v;
#pragma unroll
                for (int j = 0; j < 8; j++) f[j] = __uint_as_float((unsigned)u[j] << 16);
            } else {
                float4 v0 = *(const float4*)((const float*)x + goff);
                float4 v1 = *(const float4*)((const float*)x + goff + 4);
                f[0] = v0.x; f[1] = v0.y; f[2] = v0.z; f[3] = v0.w;
                f[4] = v1.x; f[5] = v1.y; f[6] = v1.z; f[7] = v1.w;
            }
        } else {
#pragma unroll
            for (int j = 0; j < 8; j++) f[j] = 0.f;
        }
        float* dst = &xin[cc][i][1 + wc * 8];
#pragma unroll
        for (int j = 0; j < 8; j++) dst[j] = f[j];
    }

    int cc = tid & 31;
    int g  = tid >> 5;
    int c  = c0 + cc;
    float w9[9];
#pragma unroll
    for (int k = 0; k < 9; k++) w9[k] = ldf(wdw, c * 9 + k, isbf);
    float inv  = ldf(gamma, c, isbf) * rsqrtf(ldf(var, c, isbf) + 1e-5f);
    float bias = ldf(beta, c, isbf) - ldf(mean, c, isbf) * inv;
    __syncthreads();

    const float* xr0 = xin[cc][g * STRIDE + 0];
    const float* xr1 = xin[cc][g * STRIDE + 1];
    const float* xr2 = xin[cc][g * STRIDE + 2];
    float o[WO];
    if (STRIDE == 1) {
        float a0 = xr0[0], a1 = xr0[1];
        float b0 = xr1[0], b1 = xr1[1];
        float q0 = xr2[0], q1 = xr2[1];
#pragma unroll
        for (int wo = 0; wo < WO; wo++) {
            float a2 = xr0[wo + 2], b2 = xr1[wo + 2], q2 = xr2[wo + 2];
            float acc = w9[0] * a0 + w9[1] * a1 + w9[2] * a2
                      + w9[3] * b0 + w9[4] * b1 + w9[5] * b2
                      + w9[6] * q0 + w9[7] * q1 + w9[8] * q2;
            o[wo] = acc * inv + bias;
            a0 = a1; a1 = a2; b0 = b1; b1 = b2; q0 = q1; q1 = q2;
        }
    } else {
        float a0 = xr0[0], b0 = xr1[0], q0 = xr2[0];
#pragma unroll
        for (int wo = 0; wo < WO; wo++) {
            float a1 = xr0[2 * wo + 1], a2 = xr0[2 * wo + 2];
            float b1 = xr1[2 * wo + 1], b2 = xr1[2 * wo + 2];
            float q1 = xr2[2 * wo + 1], q2 = xr2[2 * wo + 2];
            float acc = w9[0] * a0 + w9[1] * a1 + w9[2] * a2
                      + w9[3] * b0 + w9[4] * b1 + w9[5] * b2
                      + w9[6] * q0 + w9[7] * q1 + w9[8] * q2;
            o[wo] = acc * inv + bias;
            a0 = a2; b0 = b2; q0 = q2;
        }
    }
    __syncthreads();

#pragma unroll
    for (int wo = 0; wo < WO; wo++) outt[g * WO + wo][cc] = f2bu(o[wo]);
    __syncthreads();

    const size_t pbase = (size_t)b * (HO * WO) + (size_t)rg * 8 * WO;
    for (int chk = tid; chk < PT * 4; chk += 256) {
        int k = chk & 3, p = chk >> 2;
        uint4 v = *(const uint4*)&outt[p][k * 8];
        *(uint4*)(yt + (pbase + p) * CIN + c0 + k * 8) = v;
    }
}

// ---------------- merged QKV pointwise GEMM (modes 0+1), 3 blocks/CU -------------
// blocks 0..767: Q path (P=1024, yqt x qpw -> qalt). blocks 768..1151: KV path
// (P=256, ykvt x kvpw -> kalt | valt). Same 128x128 BK=32 double-buffered body;
// unified epilogue (o<INNER -> [b,h,p,d] store; else valt [b,c,p]).
__global__ __launch_bounds__(256, 3) void mfma_pw_qkv(
        const bf16* __restrict__ qpw, const bf16* __restrict__ yqt,
        bf16* __restrict__ qalt,
        const bf16* __restrict__ kvpw, const bf16* __restrict__ ykvt,
        bf16* __restrict__ kalt, bf16* __restrict__ valt) {
    __shared__ __align__(16) bf16 As[2][4096];  // 128 rows x 32 k
    __shared__ __align__(16) bf16 Bs[2][4096];
    int tid = threadIdx.x;
    int wave = tid >> 6, lane = tid & 63;
    int l15 = lane & 15, quad = lane >> 4;
    int wm = wave & 1, wn = wave >> 1;

    int bid = blockIdx.x;
    int P, b, p0, o0;
    const bf16 *asrc0, *bsrc0;
    bf16* outq;
    if (bid < 768) {                 // mode 0: Q path, grid (8,3,32) flattened
        int m = bid;
        int p0t = m & 7; m >>= 3;
        int o0t = m % 3; b = m / 3;
        P = 1024; p0 = p0t * 128; o0 = o0t * 128;
        asrc0 = yqt; bsrc0 = qpw; outq = qalt;
    } else {                          // mode 1: KV path, grid (2,6,32) flattened
        int m = bid - 768;
        int p0t = m & 1; m >>= 1;
        int o0t = m % 6; b = m / 6;
        P = 256; p0 = p0t * 128; o0 = o0t * 128;
        asrc0 = ykvt; bsrc0 = kvpw; outq = kalt;
    }

    const bf16* asrc = asrc0 + ((size_t)b * P + p0) * CIN;
    const bf16* bsrc = bsrc0 + (size_t)o0 * CIN;

    int srow = (lane >> 2);
    int sc   = lane & 3;
    auto stage = [&](int step, int buf) {
#pragma unroll
        for (int it = 0; it < 2; it++) {
            int row = wave * 32 + it * 16 + srow;
            int g = sc ^ (row & 3);
            size_t goff = (size_t)row * CIN + step * 32 + g * 8;
            dma16(asrc + goff, &As[buf][(wave * 2 + it) * 512]);
            dma16(bsrc + goff, &Bs[buf][(wave * 2 + it) * 512]);
        }
    };

    floatx4 acc[4][4];
#pragma unroll
    for (int pt = 0; pt < 4; pt++)
#pragma unroll
        for (int ot = 0; ot < 4; ot++) acc[pt][ot] = (floatx4){0.f, 0.f, 0.f, 0.f};

    stage(0, 0);
    __syncthreads();
    for (int s = 0; s < CIN / 32; s++) {
        int buf = s & 1;
        if (s < CIN / 32 - 1) stage(s + 1, buf ^ 1);
        bf16x8 af[4], bw[4];
        int slot = (quad ^ (l15 & 3)) * 8;
#pragma unroll
        for (int pt = 0; pt < 4; pt++)
            af[pt] = *(const bf16x8*)&As[buf][(wm * 64 + pt * 16 + l15) * 32 + slot];
#pragma unroll
        for (int ot = 0; ot < 4; ot++)
            bw[ot] = *(const bf16x8*)&Bs[buf][(wn * 64 + ot * 16 + l15) * 32 + slot];
#pragma unroll
        for (int pt = 0; pt < 4; pt++)
#pragma unroll
            for (int ot = 0; ot < 4; ot++)
                acc[pt][ot] = __builtin_amdgcn_mfma_f32_16x16x32_bf16(af[pt], bw[ot], acc[pt][ot], 0, 0, 0);
        __syncthreads();
    }

    int pw0 = p0 + wm * 64, ow0 = o0 + wn * 64;
#pragma unroll
    for (int ot = 0; ot < 4; ot++) {
        int o = ow0 + ot * 16 + l15;
        if (o < INNER) {
            int h = o >> 6, d = o & 63;
            bf16* base = outq + ((size_t)(b * HEADS + h) * P) * 64 + d;
#pragma unroll
            for (int pt = 0; pt < 4; pt++)
#pragma unroll
                for (int r = 0; r < 4; r++)
                    base[(size_t)(pw0 + pt * 16 + quad * 4 + r) * 64] = f2b(acc[pt][ot][r]);
        } else {
            int ch = o - INNER;
            bf16* base = valt + ((size_t)b * INNER + ch) * PKV;
#pragma unroll
            for (int pt = 0; pt < 4; pt++)
#pragma unroll
                for (int r = 0; r < 4; r++)
                    base[pw0 + pt * 16 + quad * 4 + r] = f2b(acc[pt][ot][r]);
        }
    }
}

// ---------------- out-projection GEMM (mode 2), 3 blocks/CU ----------------------
__global__ __launch_bounds__(256, 3) void mfma_pw_out(
        const bf16* __restrict__ wt, const bf16* __restrict__ yt,
        const void* __restrict__ bias, void* __restrict__ out0,
        const void* __restrict__ xprobe) {
    __shared__ __align__(16) bf16 As[2][4096];
    __shared__ __align__(16) bf16 Bs[2][4096];
    const int P = PQ, O = CIN;
    int tid = threadIdx.x;
    int wave = tid >> 6, lane = tid & 63;
    int l15 = lane & 15, quad = lane >> 4;
    int wm = wave & 1, wn = wave >> 1;
    int b = blockIdx.z;
    int p0 = blockIdx.x * 128;
    int o0 = blockIdx.y * 128;

    const bf16* asrc = yt + ((size_t)b * P + p0) * CIN;
    const bf16* bsrc = wt + (size_t)o0 * CIN;

    int srow = (lane >> 2);
    int sc   = lane & 3;
    auto stage = [&](int step, int buf) {
#pragma unroll
        for (int it = 0; it < 2; it++) {
            int row = wave * 32 + it * 16 + srow;
            int g = sc ^ (row & 3);
            size_t goff = (size_t)row * CIN + step * 32 + g * 8;
            dma16(asrc + goff, &As[buf][(wave * 2 + it) * 512]);
            dma16(bsrc + goff, &Bs[buf][(wave * 2 + it) * 512]);
        }
    };

    floatx4 acc[4][4];
#pragma unroll
    for (int pt = 0; pt < 4; pt++)
#pragma unroll
        for (int ot = 0; ot < 4; ot++) acc[pt][ot] = (floatx4){0.f, 0.f, 0.f, 0.f};

    stage(0, 0);
    __syncthreads();
    for (int s = 0; s < CIN / 32; s++) {
        int buf = s & 1;
        if (s < CIN / 32 - 1) stage(s + 1, buf ^ 1);
        bf16x8 af[4], bw[4];
        int slot = (quad ^ (l15 & 3)) * 8;
#pragma unroll
        for (int pt = 0; pt < 4; pt++)
            af[pt] = *(const bf16x8*)&As[buf][(wm * 64 + pt * 16 + l15) * 32 + slot];
#pragma unroll
        for (int ot = 0; ot < 4; ot++)
            bw[ot] = *(const bf16x8*)&Bs[buf][(wn * 64 + ot * 16 + l15) * 32 + slot];
#pragma unroll
        for (int pt = 0; pt < 4; pt++)
#pragma unroll
            for (int ot = 0; ot < 4; ot++)
                acc[pt][ot] = __builtin_amdgcn_mfma_f32_16x16x32_bf16(af[pt], bw[ot], acc[pt][ot], 0, 0, 0);
        __syncthreads();
    }

    int pw0 = p0 + wm * 64, ow0 = o0 + wn * 64;
    int isbf = probe_isbf(xprobe);
#pragma unroll
    for (int ot = 0; ot < 4; ot++) {
        int o = ow0 + ot * 16 + l15;
        float bv = ldf(bias, o, isbf);
#pragma unroll
        for (int pt = 0; pt < 4; pt++) {
            int p = pw0 + pt * 16 + quad * 4;
            size_t idx = ((size_t)b * O + o) * P + p;
            if (!isbf) {
                float4 v4 = {acc[pt][ot][0] + bv, acc[pt][ot][1] + bv,
                             acc[pt][ot][2] + bv, acc[pt][ot][3] + bv};
                *(float4*)((float*)out0 + idx) = v4;
            } else {
                ushort4 u4 = {f2bu(acc[pt][ot][0] + bv), f2bu(acc[pt][ot][1] + bv),
                              f2bu(acc[pt][ot][2] + bv), f2bu(acc[pt][ot][3] + bv)};
                *(ushort4*)((bf16*)out0 + idx) = u4;
            }
        }
    }
}

// ---------------- fused MFMA attention v5 + setprio ------------------------------
// K+V staged ONCE in LDS per block (74KB, 2 blocks/CU); 4-tile barrier-free loop.
// Swapped S^T = mfma(K,Q) keeps P in registers; proven reshape (cvt_pk +
// permlane32_swap + xor16) builds 16x16x32 A-frags; PV wide MFMAs; Ot store.
__global__ __launch_bounds__(256, 2) void attn_kernel(
        const bf16* __restrict__ qalt, const bf16* __restrict__ kalt,
        const bf16* __restrict__ valt, bf16* __restrict__ ao) {
    __shared__ __align__(16) bf16 Kl[16384];        // 32 KB, persistent
    __shared__ __align__(16) bf16 Vl[16384];        // 32 KB, persistent
    __shared__ __align__(16) ushort Ot[4][16][80];  // 10 KB, per-wave scratch
    int tid = threadIdx.x;
    int wave = tid >> 6, lane = tid & 63;
    int l15 = lane & 15, quad = lane >> 4;
    int blk = blockIdx.x;
    int swz = (blk & 7) * 96 + (blk >> 3);   // 768 = 8*96, bijective
    int seg = swz & 3;                        // 4 segments of 256 Q rows
    int bh  = swz >> 2;                       // 4 consecutive segs share (b,h) & XCD
    int b = bh / HEADS, h = bh % HEADS;

    const bf16* qbase = qalt + (size_t)(b * HEADS + h) * PQ * DH;
    const bf16* kbase = kalt + (size_t)(b * HEADS + h) * PKV * DH;
    const bf16* vbase = valt + ((size_t)b * INNER + h * DH) * PKV;

    // stage K: rows 128B, granule slot = cs ^ (row&7)
    {
        int j = lane >> 3, cs = lane & 7;
#pragma unroll
        for (int it = 0; it < 8; it++) {
            int jr = (wave * 8 + it) * 8 + j;
            int g = cs ^ (jr & 7);
            dma16(kbase + (size_t)jr * 64 + g * 8, &Kl[(wave * 8 + it) * 512]);
        }
        // stage V: rows 512B, granule slot = cs2 ^ (row&15)
        int d = lane >> 5, cs2 = lane & 31;
#pragma unroll
        for (int it = 0; it < 8; it++) {
            int dr = (wave * 8 + it) * 2 + d;
            int g = cs2 ^ (dr & 15);
            dma16(vbase + (size_t)dr * 256 + g * 8, &Vl[(wave * 8 + it) * 512]);
        }
    }

    int p0 = seg * 256 + wave * 16;  // tile t adds t*64
    const bf16* qrow = qbase + (size_t)(p0 + l15) * DH + quad * 8;
    bf16x8 qc0 = *(const bf16x8*)qrow;          // overlaps the K/V DMA
    bf16x8 qc1 = *(const bf16x8*)(qrow + 32);
    __syncthreads();  // drains DMA (vmcnt) + cross-wave staging visibility

    const float C = ATTN_SCALE * 1.44269504f;   // fold scale into exp2

#pragma unroll
    for (int t = 0; t < 4; t++) {
        // prefetch next tile's Q under this tile's compute
        bf16x8 qn0 = qc0, qn1 = qc1;
        if (t < 3) {
            const bf16* qr = qrow + (size_t)(t + 1) * 64 * DH;
            qn0 = *(const bf16x8*)qr;
            qn1 = *(const bf16x8*)(qr + 32);
        }

        // S^T = K Q^T : lane holds S[q=l15][k = jt*16 + quad*4 + r]
        floatx4 s[16];
#pragma unroll
        for (int jt = 0; jt < 16; jt++) s[jt] = (floatx4){0.f, 0.f, 0.f, 0.f};
        __builtin_amdgcn_s_setprio(1);
#pragma unroll
        for (int jt = 0; jt < 16; jt++) {
            int j = jt * 16 + l15;
            bf16x8 k0 = *(const bf16x8*)&Kl[j * 64 + (quad ^ (j & 7)) * 8];
            bf16x8 k1 = *(const bf16x8*)&Kl[j * 64 + ((4 + quad) ^ (j & 7)) * 8];
            s[jt] = __builtin_amdgcn_mfma_f32_16x16x32_bf16(k0, qc0, s[jt], 0, 0, 0);
            s[jt] = __builtin_amdgcn_mfma_f32_16x16x32_bf16(k1, qc1, s[jt], 0, 0, 0);
        }
        __builtin_amdgcn_s_setprio(0);

        // softmax: row q=l15 spread over quads -> 2 shuffles per reduce
        float mx = s[0][0];
#pragma unroll
        for (int jt = 0; jt < 16; jt++)
#pragma unroll
            for (int r = 0; r < 4; r++) mx = fmaxf(mx, s[jt][r]);
        mx = fmaxf(mx, __shfl_xor(mx, 16, 64));
        mx = fmaxf(mx, __shfl_xor(mx, 32, 64));
        float mc = mx * C;
        float sm = 0.f;
#pragma unroll
        for (int jt = 0; jt < 16; jt++)
#pragma unroll
            for (int r = 0; r < 4; r++) {
                float e = exp2f(s[jt][r] * C - mc);
                s[jt][r] = e;
                sm += e;
            }
        sm += __shfl_xor(sm, 16, 64);
        sm += __shfl_xor(sm, 32, 64);
        float pinv = 1.f / sm;

        // PV: proven reshape P (S^T regs) -> 16x16x32 A-frags
        floatx4 oacc[4];
#pragma unroll
        for (int nt = 0; nt < 4; nt++) oacc[nt] = (floatx4){0.f, 0.f, 0.f, 0.f};
        __builtin_amdgcn_s_setprio(1);
#pragma unroll
        for (int kk = 0; kk < 8; kk++) {
            floatx4 se = s[2 * kk], so = s[2 * kk + 1];
            unsigned E0 = cvtpk(se[0] * pinv, se[1] * pinv);
            unsigned E1 = cvtpk(se[2] * pinv, se[3] * pinv);
            unsigned D0 = cvtpk(so[0] * pinv, so[1] * pinv);
            unsigned D1 = cvtpk(so[2] * pinv, so[3] * pinv);
            unsigned lo0, hi0, lo1, hi1;
            halfswap(E0, D0, lo0, hi0);
            halfswap(E1, D1, lo1, hi1);
            unsigned sel0 = (quad & 1) ? hi0 : lo0;
            unsigned sel1 = (quad & 1) ? hi1 : lo1;
            unsigned x0 = (unsigned)__shfl_xor((int)sel0, 16, 64);
            unsigned x1 = (unsigned)__shfl_xor((int)sel1, 16, 64);
            union { unsigned u[4]; bf16x8 v; } pf;
            pf.u[0] = (quad & 1) ? x0 : sel0;
            pf.u[1] = (quad & 1) ? x1 : sel1;
            pf.u[2] = (quad & 1) ? sel0 : x0;
            pf.u[3] = (quad & 1) ? sel1 : x1;
#pragma unroll
            for (int nt = 0; nt < 4; nt++) {
                int d = nt * 16 + l15;
                bf16x8 bv = *(const bf16x8*)&Vl[d * 256 + ((kk * 4 + quad) ^ (d & 15)) * 8];
                oacc[nt] = __builtin_amdgcn_mfma_f32_16x16x32_bf16(pf.v, bv, oacc[nt], 0, 0, 0);
            }
        }
        __builtin_amdgcn_s_setprio(0);

        // C-layout -> per-wave LDS slice -> coalesced [p][c] store
#pragma unroll
        for (int nt = 0; nt < 4; nt++)
#pragma unroll
            for (int r = 0; r < 4; r++)
                Ot[wave][quad * 4 + r][nt * 16 + l15] = f2bu(oacc[nt][r]);
        int row = lane >> 2, d0 = (lane & 3) * 16;
        uint4 ld0 = *(const uint4*)&Ot[wave][row][d0];
        uint4 ld1 = *(const uint4*)&Ot[wave][row][d0 + 8];
        bf16* dst = ao + ((size_t)b * PQ + p0 + t * 64 + row) * INNER + h * DH + d0;
        *(uint4*)dst = ld0;
        *(uint4*)(dst + 8) = ld1;

        qc0 = qn0; qc1 = qn1;
    }
}

extern "C" void kernel_launch(void* const* d_in, const int* in_sizes, int n_in,
                              void* d_out, int out_size, void* d_ws, size_t ws_size,
                              hipStream_t stream) {
    const void* x        = d_in[0];
    const void* q_dw     = d_in[1];
    const void* q_gamma  = d_in[2];
    const void* q_beta   = d_in[3];
    const void* q_mean   = d_in[4];
    const void* q_var    = d_in[5];
    const void* q_pw     = d_in[6];
    const void* kv_dw    = d_in[7];
    const void* kv_gamma = d_in[8];
    const void* kv_beta  = d_in[9];
    const void* kv_mean  = d_in[10];
    const void* kv_var   = d_in[11];
    const void* kv_pw    = d_in[12];
    const void* out_w    = d_in[13];
    const void* out_b    = d_in[14];

    bf16* pool = (bf16*)((char*)d_ws + 256);
    bf16* yqt  = pool;                              // [32,1024,384] Y^T Q-path; reused as aob
    bf16* ykvt = yqt  + (size_t)32 * 1024 * 384;    // [32,256,384]  Y^T KV-path
    bf16* qalt = ykvt + (size_t)32 * 256 * 384;     // [32,6,1024,64]
    bf16* kalt = qalt + (size_t)32 * 6 * 1024 * 64; // [32,6,256,64]
    bf16* valt = kalt + (size_t)32 * 6 * 256 * 64;  // [32,384,256]
    bf16* wbf  = valt + (size_t)32 * 384 * 256;     // q_pw | kv_pw | out_w bf16
    bf16* qpw_bf = wbf;
    bf16* kvpw_bf = wbf + (size_t)INNER * CIN;
    bf16* outw_bf = kvpw_bf + (size_t)2 * INNER * CIN;
    bf16* aob  = yqt;  // alias: yqt dead after Q pointwise; attn writes [b][p][c]

    wconv_kernel<<<576, 256, 0, stream>>>(q_pw, kv_pw, out_w, wbf, x);
    dw_bn_kernel<1, 32, 32><<<dim3(4, 12, 32), 256, 0, stream>>>(x, q_dw, q_gamma, q_beta, q_mean, q_var, yqt);
    dw_bn_kernel<2, 16, 16><<<dim3(2, 12, 32), 256, 0, stream>>>(x, kv_dw, kv_gamma, kv_beta, kv_mean, kv_var, ykvt);
    mfma_pw_qkv<<<1152, 256, 0, stream>>>(qpw_bf, yqt, qalt, kvpw_bf, ykvt, kalt, valt);
    attn_kernel<<<768, 256, 0, stream>>>(qalt, kalt, valt, aob);
    mfma_pw_out<<<dim3(8, 3, 32), 256, 0, stream>>>(outw_bf, aob, out_b, d_out, x);
}

// Round 8
// 236.847 us; speedup vs baseline: 1.1124x; 1.0140x over previous
//
#include <hip/hip_runtime.h>
#include <hip/hip_bf16.h>

#define CIN 384
#define PQ 1024
#define PKV 256
#define HEADS 6
#define DH 64
#define INNER 384
#define ATTN_SCALE 0.125f

typedef __hip_bfloat16 bf16;
typedef unsigned short ushort;
typedef __bf16 bf16x8 __attribute__((ext_vector_type(8)));
typedef float floatx4 __attribute__((ext_vector_type(4)));

__device__ __forceinline__ float b2f(bf16 v) { return __bfloat162float(v); }
__device__ __forceinline__ bf16 f2b(float v) { return __float2bfloat16(v); }
__device__ __forceinline__ ushort f2bu(float v) { bf16 h = __float2bfloat16(v); return *(ushort*)&h; }
__device__ __forceinline__ float ldf(const void* p, size_t i, int isbf) {
    return isbf ? __bfloat162float(((const bf16*)p)[i]) : ((const float*)p)[i];
}
// async global->LDS DMA, 16B per lane; LDS dest = uniform base + lane*16
__device__ __forceinline__ void dma16(const bf16* g, bf16* l) {
    __builtin_amdgcn_global_load_lds(
        (const __attribute__((address_space(1))) unsigned int*)g,
        (__attribute__((address_space(3))) unsigned int*)l, 16, 0, 0);
}
// uniform scalar dtype probe
__device__ __forceinline__ int probe_isbf(const void* x) {
    const unsigned* u = (const unsigned*)x;
    int cnt = 0;
    for (int i = 0; i < 64; i++) {
        unsigned e = (u[i] >> 7) & 0xFFu;
        cnt += (e >= 100u && e <= 140u) ? 1 : 0;
    }
    return cnt >= 48 ? 1 : 0;
}
__device__ __forceinline__ unsigned cvtpk(float lo, float hi) {
    unsigned r;
    asm("v_cvt_pk_bf16_f32 %0, %1, %2" : "=v"(r) : "v"(lo), "v"(hi));
    return r;
}
// half-wave swap: lo = [a(lanes0-31) | b(lanes0-31)], hi = [a(32-63) | b(32-63)]
__device__ __forceinline__ void halfswap(unsigned a, unsigned b, unsigned& lo, unsigned& hi) {
#if __has_builtin(__builtin_amdgcn_permlane32_swap)
    auto r = __builtin_amdgcn_permlane32_swap(a, b, false, false);
    lo = r[0]; hi = r[1];
#else
    unsigned ax = (unsigned)__shfl_xor((int)a, 32, 64);
    unsigned bx = (unsigned)__shfl_xor((int)b, 32, 64);
    bool lower = (threadIdx.x & 32) == 0;
    lo = lower ? a : bx;
    hi = lower ? ax : b;
#endif
}

// ---------------- depthwise 3x3 + BN -> Y^T [b][p][c]; wconv fused (y==12) ------
template <int STRIDE, int HO, int WO>
__global__ __launch_bounds__(256) void dw_bn_kernel(
        const void* __restrict__ x, const void* __restrict__ wdw,
        const void* __restrict__ gamma, const void* __restrict__ beta,
        const void* __restrict__ mean, const void* __restrict__ var,
        bf16* __restrict__ yt,
        const void* __restrict__ w0, const void* __restrict__ w1,
        const void* __restrict__ w2, bf16* __restrict__ wdst) {
    constexpr int IN_ROWS = (8 - 1) * STRIDE + 3;       // 10 or 17
    constexpr int RL = 37;                              // slab stride 370%32=18 -> 2-way
    constexpr int PT = 8 * WO;
    constexpr unsigned XSZ = 32u * IN_ROWS * RL * 4;
    constexpr unsigned OSZ = (unsigned)PT * 40 * 2;
    __shared__ __align__(16) char smem[XSZ > OSZ ? XSZ : OSZ];
    float (*xin)[IN_ROWS][RL] = (float (*)[IN_ROWS][RL])smem;  // [cc][i][1+w]
    ushort (*outt)[40] = (ushort (*)[40])smem;                 // [g*WO+wo][cc]

    int isbf = probe_isbf(x);
    int rg = blockIdx.x;
    int c0 = blockIdx.y * 32;
    int b  = blockIdx.z;
    int tid = threadIdx.x;

    if (c0 >= CIN) {  // fused weight-convert blocks (blockIdx.y == 12, stride-1 only)
        const int n0 = INNER * CIN, n1 = 2 * INNER * CIN, n2 = INNER * CIN;
        const int total = n0 + n1 + n2;
        for (int i = (b * 4 + rg) * 256 + tid; i < total; i += 32768) {
            float v;
            if (i < n0) v = ldf(w0, i, isbf);
            else if (i < n0 + n1) v = ldf(w1, i - n0, isbf);
            else v = ldf(w2, i - n0 - n1, isbf);
            wdst[i] = f2b(v);
        }
        return;
    }

    int ri0 = rg * 8 * STRIDE - 1;

    for (int e = tid; e < 32 * IN_ROWS; e += 256) {
        int i = e % IN_ROWS, cc = e / IN_ROWS;
        xin[cc][i][0] = 0.f;
        xin[cc][i][33] = 0.f;
    }

    const int NCHUNK = 32 * IN_ROWS * 4;
    for (int ch = tid; ch < NCHUNK; ch += 256) {
        int wc = ch & 3;
        int t  = ch >> 2;
        int i  = t % IN_ROWS;
        int cc = t / IN_ROWS;
        int row = ri0 + i;
        float f[8];
        if (row >= 0 && row < 32) {
            size_t goff = ((size_t)(b * CIN + c0 + cc) * 32 + row) * 32 + wc * 8;
            if (isbf) {
                uint4 v = *(const uint4*)((const bf16*)x + goff);
                const ushort* u = (const ushort*)&v;
#pragma unroll
                for (int j = 0; j < 8; j++) f[j] = __uint_as_float((unsigned)u[j] << 16);
            } else {
                float4 v0 = *(const float4*)((const float*)x + goff);
                float4 v1 = *(const float4*)((const float*)x + goff + 4);
                f[0] = v0.x; f[1] = v0.y; f[2] = v0.z; f[3] = v0.w;
                f[4] = v1.x; f[5] = v1.y; f[6] = v1.z; f[7] = v1.w;
            }
        } else {
#pragma unroll
            for (int j = 0; j < 8; j++) f[j] = 0.f;
        }
        float* dst = &xin[cc][i][1 + wc * 8];
#pragma unroll
        for (int j = 0; j < 8; j++) dst[j] = f[j];
    }

    int cc = tid & 31;
    int g  = tid >> 5;
    int c  = c0 + cc;
    float w9[9];
#pragma unroll
    for (int k = 0; k < 9; k++) w9[k] = ldf(wdw, c * 9 + k, isbf);
    float inv  = ldf(gamma, c, isbf) * rsqrtf(ldf(var, c, isbf) + 1e-5f);
    float bias = ldf(beta, c, isbf) - ldf(mean, c, isbf) * inv;
    __syncthreads();

    const float* xr0 = xin[cc][g * STRIDE + 0];
    const float* xr1 = xin[cc][g * STRIDE + 1];
    const float* xr2 = xin[cc][g * STRIDE + 2];
    float o[WO];
    if (STRIDE == 1) {
        float a0 = xr0[0], a1 = xr0[1];
        float b0 = xr1[0], b1 = xr1[1];
        float q0 = xr2[0], q1 = xr2[1];
#pragma unroll
        for (int wo = 0; wo < WO; wo++) {
            float a2 = xr0[wo + 2], b2 = xr1[wo + 2], q2 = xr2[wo + 2];
            float acc = w9[0] * a0 + w9[1] * a1 + w9[2] * a2
                      + w9[3] * b0 + w9[4] * b1 + w9[5] * b2
                      + w9[6] * q0 + w9[7] * q1 + w9[8] * q2;
            o[wo] = acc * inv + bias;
            a0 = a1; a1 = a2; b0 = b1; b1 = b2; q0 = q1; q1 = q2;
        }
    } else {
        float a0 = xr0[0], b0 = xr1[0], q0 = xr2[0];
#pragma unroll
        for (int wo = 0; wo < WO; wo++) {
            float a1 = xr0[2 * wo + 1], a2 = xr0[2 * wo + 2];
            float b1 = xr1[2 * wo + 1], b2 = xr1[2 * wo + 2];
            float q1 = xr2[2 * wo + 1], q2 = xr2[2 * wo + 2];
            float acc = w9[0] * a0 + w9[1] * a1 + w9[2] * a2
                      + w9[3] * b0 + w9[4] * b1 + w9[5] * b2
                      + w9[6] * q0 + w9[7] * q1 + w9[8] * q2;
            o[wo] = acc * inv + bias;
            a0 = a2; b0 = b2; q0 = q2;
        }
    }
    __syncthreads();

#pragma unroll
    for (int wo = 0; wo < WO; wo++) outt[g * WO + wo][cc] = f2bu(o[wo]);
    __syncthreads();

    const size_t pbase = (size_t)b * (HO * WO) + (size_t)rg * 8 * WO;
    for (int chk = tid; chk < PT * 4; chk += 256) {
        int k = chk & 3, p = chk >> 2;
        uint4 v = *(const uint4*)&outt[p][k * 8];
        *(uint4*)(yt + (pbase + p) * CIN + c0 + k * 8) = v;
    }
}

// ---------------- merged QKV pointwise GEMM (modes 0+1), 3 blocks/CU -------------
__global__ __launch_bounds__(256, 3) void mfma_pw_qkv(
        const bf16* __restrict__ qpw, const bf16* __restrict__ yqt,
        bf16* __restrict__ qalt,
        const bf16* __restrict__ kvpw, const bf16* __restrict__ ykvt,
        bf16* __restrict__ kalt, bf16* __restrict__ valt) {
    __shared__ __align__(16) bf16 As[2][4096];  // 128 rows x 32 k
    __shared__ __align__(16) bf16 Bs[2][4096];
    int tid = threadIdx.x;
    int wave = tid >> 6, lane = tid & 63;
    int l15 = lane & 15, quad = lane >> 4;
    int wm = wave & 1, wn = wave >> 1;

    int bid = blockIdx.x;
    int P, b, p0, o0;
    const bf16 *asrc0, *bsrc0;
    bf16* outq;
    if (bid < 768) {                 // mode 0: Q path, grid (8,3,32) flattened
        int m = bid;
        int p0t = m & 7; m >>= 3;
        int o0t = m % 3; b = m / 3;
        P = 1024; p0 = p0t * 128; o0 = o0t * 128;
        asrc0 = yqt; bsrc0 = qpw; outq = qalt;
    } else {                          // mode 1: KV path, grid (2,6,32) flattened
        int m = bid - 768;
        int p0t = m & 1; m >>= 1;
        int o0t = m % 6; b = m / 6;
        P = 256; p0 = p0t * 128; o0 = o0t * 128;
        asrc0 = ykvt; bsrc0 = kvpw; outq = kalt;
    }

    const bf16* asrc = asrc0 + ((size_t)b * P + p0) * CIN;
    const bf16* bsrc = bsrc0 + (size_t)o0 * CIN;

    int srow = (lane >> 2);
    int sc   = lane & 3;
    auto stage = [&](int step, int buf) {
#pragma unroll
        for (int it = 0; it < 2; it++) {
            int row = wave * 32 + it * 16 + srow;
            int g = sc ^ (row & 3);
            size_t goff = (size_t)row * CIN + step * 32 + g * 8;
            dma16(asrc + goff, &As[buf][(wave * 2 + it) * 512]);
            dma16(bsrc + goff, &Bs[buf][(wave * 2 + it) * 512]);
        }
    };

    floatx4 acc[4][4];
#pragma unroll
    for (int pt = 0; pt < 4; pt++)
#pragma unroll
        for (int ot = 0; ot < 4; ot++) acc[pt][ot] = (floatx4){0.f, 0.f, 0.f, 0.f};

    stage(0, 0);
    __syncthreads();
    for (int s = 0; s < CIN / 32; s++) {
        int buf = s & 1;
        if (s < CIN / 32 - 1) stage(s + 1, buf ^ 1);
        bf16x8 af[4], bw[4];
        int slot = (quad ^ (l15 & 3)) * 8;
#pragma unroll
        for (int pt = 0; pt < 4; pt++)
            af[pt] = *(const bf16x8*)&As[buf][(wm * 64 + pt * 16 + l15) * 32 + slot];
#pragma unroll
        for (int ot = 0; ot < 4; ot++)
            bw[ot] = *(const bf16x8*)&Bs[buf][(wn * 64 + ot * 16 + l15) * 32 + slot];
#pragma unroll
        for (int pt = 0; pt < 4; pt++)
#pragma unroll
            for (int ot = 0; ot < 4; ot++)
                acc[pt][ot] = __builtin_amdgcn_mfma_f32_16x16x32_bf16(af[pt], bw[ot], acc[pt][ot], 0, 0, 0);
        __syncthreads();
    }

    int pw0 = p0 + wm * 64, ow0 = o0 + wn * 64;
#pragma unroll
    for (int ot = 0; ot < 4; ot++) {
        int o = ow0 + ot * 16 + l15;
        if (o < INNER) {
            int h = o >> 6, d = o & 63;
            bf16* base = outq + ((size_t)(b * HEADS + h) * P) * 64 + d;
#pragma unroll
            for (int pt = 0; pt < 4; pt++)
#pragma unroll
                for (int r = 0; r < 4; r++)
                    base[(size_t)(pw0 + pt * 16 + quad * 4 + r) * 64] = f2b(acc[pt][ot][r]);
        } else {
            int ch = o - INNER;
            bf16* base = valt + ((size_t)b * INNER + ch) * PKV;
#pragma unroll
            for (int pt = 0; pt < 4; pt++)
#pragma unroll
                for (int r = 0; r < 4; r++)
                    base[pw0 + pt * 16 + quad * 4 + r] = f2b(acc[pt][ot][r]);
        }
    }
}

// ---------------- out-projection GEMM (mode 2), 3 blocks/CU ----------------------
__global__ __launch_bounds__(256, 3) void mfma_pw_out(
        const bf16* __restrict__ wt, const bf16* __restrict__ yt,
        const void* __restrict__ bias, void* __restrict__ out0,
        const void* __restrict__ xprobe) {
    __shared__ __align__(16) bf16 As[2][4096];
    __shared__ __align__(16) bf16 Bs[2][4096];
    const int P = PQ, O = CIN;
    int tid = threadIdx.x;
    int wave = tid >> 6, lane = tid & 63;
    int l15 = lane & 15, quad = lane >> 4;
    int wm = wave & 1, wn = wave >> 1;
    int b = blockIdx.z;
    int p0 = blockIdx.x * 128;
    int o0 = blockIdx.y * 128;

    const bf16* asrc = yt + ((size_t)b * P + p0) * CIN;
    const bf16* bsrc = wt + (size_t)o0 * CIN;

    int srow = (lane >> 2);
    int sc   = lane & 3;
    auto stage = [&](int step, int buf) {
#pragma unroll
        for (int it = 0; it < 2; it++) {
            int row = wave * 32 + it * 16 + srow;
            int g = sc ^ (row & 3);
            size_t goff = (size_t)row * CIN + step * 32 + g * 8;
            dma16(asrc + goff, &As[buf][(wave * 2 + it) * 512]);
            dma16(bsrc + goff, &Bs[buf][(wave * 2 + it) * 512]);
        }
    };

    floatx4 acc[4][4];
#pragma unroll
    for (int pt = 0; pt < 4; pt++)
#pragma unroll
        for (int ot = 0; ot < 4; ot++) acc[pt][ot] = (floatx4){0.f, 0.f, 0.f, 0.f};

    stage(0, 0);
    __syncthreads();
    for (int s = 0; s < CIN / 32; s++) {
        int buf = s & 1;
        if (s < CIN / 32 - 1) stage(s + 1, buf ^ 1);
        bf16x8 af[4], bw[4];
        int slot = (quad ^ (l15 & 3)) * 8;
#pragma unroll
        for (int pt = 0; pt < 4; pt++)
            af[pt] = *(const bf16x8*)&As[buf][(wm * 64 + pt * 16 + l15) * 32 + slot];
#pragma unroll
        for (int ot = 0; ot < 4; ot++)
            bw[ot] = *(const bf16x8*)&Bs[buf][(wn * 64 + ot * 16 + l15) * 32 + slot];
#pragma unroll
        for (int pt = 0; pt < 4; pt++)
#pragma unroll
            for (int ot = 0; ot < 4; ot++)
                acc[pt][ot] = __builtin_amdgcn_mfma_f32_16x16x32_bf16(af[pt], bw[ot], acc[pt][ot], 0, 0, 0);
        __syncthreads();
    }

    int pw0 = p0 + wm * 64, ow0 = o0 + wn * 64;
    int isbf = probe_isbf(xprobe);
#pragma unroll
    for (int ot = 0; ot < 4; ot++) {
        int o = ow0 + ot * 16 + l15;
        float bv = ldf(bias, o, isbf);
#pragma unroll
        for (int pt = 0; pt < 4; pt++) {
            int p = pw0 + pt * 16 + quad * 4;
            size_t idx = ((size_t)b * O + o) * P + p;
            if (!isbf) {
                float4 v4 = {acc[pt][ot][0] + bv, acc[pt][ot][1] + bv,
                             acc[pt][ot][2] + bv, acc[pt][ot][3] + bv};
                *(float4*)((float*)out0 + idx) = v4;
            } else {
                ushort4 u4 = {f2bu(acc[pt][ot][0] + bv), f2bu(acc[pt][ot][1] + bv),
                              f2bu(acc[pt][ot][2] + bv), f2bu(acc[pt][ot][3] + bv)};
                *(ushort4*)((bf16*)out0 + idx) = u4;
            }
        }
    }
}

// ---------------- fused MFMA attention v6: 2-tile software pipeline --------------
// Same proven v5 building blocks (QKT swapped, cvt_pk+halfswap+xor16 reshape, Ot
// store) restructured as a 2-deep pipeline with named register sets sA/sB:
// softmax(cur) and QKT(next) share one basic block so the scheduler fills the
// softmax dependency stalls with MFMA/ds_read issue. Q loads issued 1 tile ahead.
// ILP-tree max/sum reductions (4 parallel chains) cut the serial chain 4x.
#define QKT(S, Q0, Q1)                                                              \
    do {                                                                            \
        floatx4 z_ = (floatx4){0.f, 0.f, 0.f, 0.f};                                 \
        _Pragma("unroll")                                                           \
        for (int jt_ = 0; jt_ < 16; jt_++) {                                        \
            int j_ = jt_ * 16 + l15;                                                \
            bf16x8 k0_ = *(const bf16x8*)&Kl[j_ * 64 + (quad ^ (j_ & 7)) * 8];      \
            bf16x8 k1_ = *(const bf16x8*)&Kl[j_ * 64 + ((4 + quad) ^ (j_ & 7)) * 8];\
            floatx4 t_ = __builtin_amdgcn_mfma_f32_16x16x32_bf16(k0_, Q0, z_, 0, 0, 0); \
            S[jt_] = __builtin_amdgcn_mfma_f32_16x16x32_bf16(k1_, Q1, t_, 0, 0, 0); \
        }                                                                           \
    } while (0)

#define SOFTMAX(S, PINV)                                                            \
    do {                                                                            \
        float m0_ = S[0][0], m1_ = S[0][1], m2_ = S[0][2], m3_ = S[0][3];           \
        _Pragma("unroll")                                                           \
        for (int jt_ = 1; jt_ < 16; jt_++) {                                        \
            m0_ = fmaxf(m0_, S[jt_][0]); m1_ = fmaxf(m1_, S[jt_][1]);               \
            m2_ = fmaxf(m2_, S[jt_][2]); m3_ = fmaxf(m3_, S[jt_][3]);               \
        }                                                                           \
        float mx_ = fmaxf(fmaxf(m0_, m1_), fmaxf(m2_, m3_));                        \
        mx_ = fmaxf(mx_, __shfl_xor(mx_, 16, 64));                                  \
        mx_ = fmaxf(mx_, __shfl_xor(mx_, 32, 64));                                  \
        float mc_ = mx_ * C;                                                        \
        float a0_ = 0.f, a1_ = 0.f, a2_ = 0.f, a3_ = 0.f;                           \
        _Pragma("unroll")                                                           \
        for (int jt_ = 0; jt_ < 16; jt_++) {                                        \
            float e0_ = exp2f(S[jt_][0] * C - mc_);                                 \
            float e1_ = exp2f(S[jt_][1] * C - mc_);                                 \
            float e2_ = exp2f(S[jt_][2] * C - mc_);                                 \
            float e3_ = exp2f(S[jt_][3] * C - mc_);                                 \
            S[jt_][0] = e0_; S[jt_][1] = e1_; S[jt_][2] = e2_; S[jt_][3] = e3_;     \
            a0_ += e0_; a1_ += e1_; a2_ += e2_; a3_ += e3_;                         \
        }                                                                           \
        float sm_ = (a0_ + a1_) + (a2_ + a3_);                                      \
        sm_ += __shfl_xor(sm_, 16, 64);                                             \
        sm_ += __shfl_xor(sm_, 32, 64);                                             \
        PINV = 1.f / sm_;                                                           \
    } while (0)

#define PV_STORE(S, PINV, T)                                                        \
    do {                                                                            \
        floatx4 oacc_[4];                                                           \
        _Pragma("unroll")                                                           \
        for (int nt_ = 0; nt_ < 4; nt_++) oacc_[nt_] = (floatx4){0.f, 0.f, 0.f, 0.f}; \
        _Pragma("unroll")                                                           \
        for (int kk_ = 0; kk_ < 8; kk_++) {                                         \
            floatx4 se_ = S[2 * kk_], so_ = S[2 * kk_ + 1];                         \
            unsigned E0_ = cvtpk(se_[0] * PINV, se_[1] * PINV);                     \
            unsigned E1_ = cvtpk(se_[2] * PINV, se_[3] * PINV);                     \
            unsigned D0_ = cvtpk(so_[0] * PINV, so_[1] * PINV);                     \
            unsigned D1_ = cvtpk(so_[2] * PINV, so_[3] * PINV);                     \
            unsigned lo0_, hi0_, lo1_, hi1_;                                        \
            halfswap(E0_, D0_, lo0_, hi0_);                                         \
            halfswap(E1_, D1_, lo1_, hi1_);                                         \
            unsigned sel0_ = (quad & 1) ? hi0_ : lo0_;                              \
            unsigned sel1_ = (quad & 1) ? hi1_ : lo1_;                              \
            unsigned x0_ = (unsigned)__shfl_xor((int)sel0_, 16, 64);                \
            unsigned x1_ = (unsigned)__shfl_xor((int)sel1_, 16, 64);                \
            union { unsigned u[4]; bf16x8 v; } pf_;                                 \
            pf_.u[0] = (quad & 1) ? x0_ : sel0_;                                    \
            pf_.u[1] = (quad & 1) ? x1_ : sel1_;                                    \
            pf_.u[2] = (quad & 1) ? sel0_ : x0_;                                    \
            pf_.u[3] = (quad & 1) ? sel1_ : x1_;                                    \
            _Pragma("unroll")                                                       \
            for (int nt_ = 0; nt_ < 4; nt_++) {                                     \
                int d_ = nt_ * 16 + l15;                                            \
                bf16x8 bv_ = *(const bf16x8*)&Vl[d_ * 256 + ((kk_ * 4 + quad) ^ (d_ & 15)) * 8]; \
                oacc_[nt_] = __builtin_amdgcn_mfma_f32_16x16x32_bf16(pf_.v, bv_, oacc_[nt_], 0, 0, 0); \
            }                                                                       \
        }                                                                           \
        _Pragma("unroll")                                                           \
        for (int nt_ = 0; nt_ < 4; nt_++)                                           \
            _Pragma("unroll")                                                       \
            for (int r_ = 0; r_ < 4; r_++)                                          \
                Ot[wave][quad * 4 + r_][nt_ * 16 + l15] = f2bu(oacc_[nt_][r_]);     \
        int row_ = lane >> 2, d0_ = (lane & 3) * 16;                                \
        uint4 ld0_ = *(const uint4*)&Ot[wave][row_][d0_];                           \
        uint4 ld1_ = *(const uint4*)&Ot[wave][row_][d0_ + 8];                       \
        bf16* dst_ = ao + ((size_t)b * PQ + p0 + (T) * 64 + row_) * INNER + h * DH + d0_; \
        *(uint4*)dst_ = ld0_;                                                       \
        *(uint4*)(dst_ + 8) = ld1_;                                                 \
    } while (0)

__global__ __launch_bounds__(256, 2) void attn_kernel(
        const bf16* __restrict__ qalt, const bf16* __restrict__ kalt,
        const bf16* __restrict__ valt, bf16* __restrict__ ao) {
    __shared__ __align__(16) bf16 Kl[16384];        // 32 KB, persistent
    __shared__ __align__(16) bf16 Vl[16384];        // 32 KB, persistent
    __shared__ __align__(16) ushort Ot[4][16][80];  // 10 KB, per-wave scratch
    int tid = threadIdx.x;
    int wave = tid >> 6, lane = tid & 63;
    int l15 = lane & 15, quad = lane >> 4;
    int blk = blockIdx.x;
    int swz = (blk & 7) * 96 + (blk >> 3);   // 768 = 8*96, bijective
    int seg = swz & 3;                        // 4 segments of 256 Q rows
    int bh  = swz >> 2;                       // 4 consecutive segs share (b,h) & XCD
    int b = bh / HEADS, h = bh % HEADS;

    const bf16* qbase = qalt + (size_t)(b * HEADS + h) * PQ * DH;
    const bf16* kbase = kalt + (size_t)(b * HEADS + h) * PKV * DH;
    const bf16* vbase = valt + ((size_t)b * INNER + h * DH) * PKV;

    // stage K: rows 128B, granule slot = cs ^ (row&7)
    {
        int j = lane >> 3, cs = lane & 7;
#pragma unroll
        for (int it = 0; it < 8; it++) {
            int jr = (wave * 8 + it) * 8 + j;
            int g = cs ^ (jr & 7);
            dma16(kbase + (size_t)jr * 64 + g * 8, &Kl[(wave * 8 + it) * 512]);
        }
        // stage V: rows 512B, granule slot = cs2 ^ (row&15)
        int d = lane >> 5, cs2 = lane & 31;
#pragma unroll
        for (int it = 0; it < 8; it++) {
            int dr = (wave * 8 + it) * 2 + d;
            int g = cs2 ^ (dr & 15);
            dma16(vbase + (size_t)dr * 256 + g * 8, &Vl[(wave * 8 + it) * 512]);
        }
    }

    int p0 = seg * 256 + wave * 16;  // tile t adds t*64
    const bf16* qrow = qbase + (size_t)(p0 + l15) * DH + quad * 8;
    // Q for tiles 0 and 1 issued under the K/V DMA
    bf16x8 qA0 = *(const bf16x8*)qrow;
    bf16x8 qA1 = *(const bf16x8*)(qrow + 32);
    bf16x8 qB0 = *(const bf16x8*)(qrow + 64 * DH);
    bf16x8 qB1 = *(const bf16x8*)(qrow + 64 * DH + 32);
    __syncthreads();  // drains DMA (vmcnt) + cross-wave staging visibility

    const float C = ATTN_SCALE * 1.44269504f;   // fold scale into exp2
    floatx4 sA[16], sB[16];
    float pinv;

    QKT(sA, qA0, qA1);                          // tile 0
    qA0 = *(const bf16x8*)(qrow + 128 * DH);    // Q(t2), hides under t0 compute
    qA1 = *(const bf16x8*)(qrow + 128 * DH + 32);

    // T=0: softmax(sA) + QKT(sB) share the block; PV(sA)
    SOFTMAX(sA, pinv);
    QKT(sB, qB0, qB1);                          // tile 1
    PV_STORE(sA, pinv, 0);
    qB0 = *(const bf16x8*)(qrow + 192 * DH);    // Q(t3), hides under t1 compute
    qB1 = *(const bf16x8*)(qrow + 192 * DH + 32);

    // T=1
    SOFTMAX(sB, pinv);
    QKT(sA, qA0, qA1);                          // tile 2
    PV_STORE(sB, pinv, 1);

    // T=2
    SOFTMAX(sA, pinv);
    QKT(sB, qB0, qB1);                          // tile 3
    PV_STORE(sA, pinv, 2);

    // T=3
    SOFTMAX(sB, pinv);
    PV_STORE(sB, pinv, 3);
}

extern "C" void kernel_launch(void* const* d_in, const int* in_sizes, int n_in,
                              void* d_out, int out_size, void* d_ws, size_t ws_size,
                              hipStream_t stream) {
    const void* x        = d_in[0];
    const void* q_dw     = d_in[1];
    const void* q_gamma  = d_in[2];
    const void* q_beta   = d_in[3];
    const void* q_mean   = d_in[4];
    const void* q_var    = d_in[5];
    const void* q_pw     = d_in[6];
    const void* kv_dw    = d_in[7];
    const void* kv_gamma = d_in[8];
    const void* kv_beta  = d_in[9];
    const void* kv_mean  = d_in[10];
    const void* kv_var   = d_in[11];
    const void* kv_pw    = d_in[12];
    const void* out_w    = d_in[13];
    const void* out_b    = d_in[14];

    bf16* pool = (bf16*)((char*)d_ws + 256);
    bf16* yqt  = pool;                              // [32,1024,384] Y^T Q-path; reused as aob
    bf16* ykvt = yqt  + (size_t)32 * 1024 * 384;    // [32,256,384]  Y^T KV-path
    bf16* qalt = ykvt + (size_t)32 * 256 * 384;     // [32,6,1024,64]
    bf16* kalt = qalt + (size_t)32 * 6 * 1024 * 64; // [32,6,256,64]
    bf16* valt = kalt + (size_t)32 * 6 * 256 * 64;  // [32,384,256]
    bf16* wbf  = valt + (size_t)32 * 384 * 256;     // q_pw | kv_pw | out_w bf16
    bf16* qpw_bf = wbf;
    bf16* kvpw_bf = wbf + (size_t)INNER * CIN;
    bf16* outw_bf = kvpw_bf + (size_t)2 * INNER * CIN;
    bf16* aob  = yqt;  // alias: yqt dead after Q pointwise; attn writes [b][p][c]

    dw_bn_kernel<1, 32, 32><<<dim3(4, 13, 32), 256, 0, stream>>>(
        x, q_dw, q_gamma, q_beta, q_mean, q_var, yqt, q_pw, kv_pw, out_w, wbf);
    dw_bn_kernel<2, 16, 16><<<dim3(2, 12, 32), 256, 0, stream>>>(
        x, kv_dw, kv_gamma, kv_beta, kv_mean, kv_var, ykvt, nullptr, nullptr, nullptr, nullptr);
    mfma_pw_qkv<<<1152, 256, 0, stream>>>(qpw_bf, yqt, qalt, kvpw_bf, ykvt, kalt, valt);
    attn_kernel<<<768, 256, 0, stream>>>(qalt, kalt, valt, aob);
    mfma_pw_out<<<dim3(8, 3, 32), 256, 0, stream>>>(outw_bf, aob, out_b, d_out, x);
}

// Round 9
// 228.384 us; speedup vs baseline: 1.1536x; 1.0371x over previous
//
#include <hip/hip_runtime.h>
#include <hip/hip_bf16.h>

#define CIN 384
#define PQ 1024
#define PKV 256
#define HEADS 6
#define DH 64
#define INNER 384
#define ATTN_SCALE 0.125f

typedef __hip_bfloat16 bf16;
typedef unsigned short ushort;
typedef __bf16 bf16x8 __attribute__((ext_vector_type(8)));
typedef float floatx4 __attribute__((ext_vector_type(4)));

__device__ __forceinline__ float b2f(bf16 v) { return __bfloat162float(v); }
__device__ __forceinline__ bf16 f2b(float v) { return __float2bfloat16(v); }
__device__ __forceinline__ ushort f2bu(float v) { bf16 h = __float2bfloat16(v); return *(ushort*)&h; }
__device__ __forceinline__ float ldf(const void* p, size_t i, int isbf) {
    return isbf ? __bfloat162float(((const bf16*)p)[i]) : ((const float*)p)[i];
}
// async global->LDS DMA, 16B per lane; LDS dest = uniform base + lane*16
__device__ __forceinline__ void dma16(const bf16* g, bf16* l) {
    __builtin_amdgcn_global_load_lds(
        (const __attribute__((address_space(1))) unsigned int*)g,
        (__attribute__((address_space(3))) unsigned int*)l, 16, 0, 0);
}
// uniform scalar dtype probe
__device__ __forceinline__ int probe_isbf(const void* x) {
    const unsigned* u = (const unsigned*)x;
    int cnt = 0;
    for (int i = 0; i < 64; i++) {
        unsigned e = (u[i] >> 7) & 0xFFu;
        cnt += (e >= 100u && e <= 140u) ? 1 : 0;
    }
    return cnt >= 48 ? 1 : 0;
}
__device__ __forceinline__ unsigned cvtpk(float lo, float hi) {
    unsigned r;
    asm("v_cvt_pk_bf16_f32 %0, %1, %2" : "=v"(r) : "v"(lo), "v"(hi));
    return r;
}
// half-wave swap: lo = [a(lanes0-31) | b(lanes0-31)], hi = [a(32-63) | b(32-63)]
__device__ __forceinline__ void halfswap(unsigned a, unsigned b, unsigned& lo, unsigned& hi) {
#if __has_builtin(__builtin_amdgcn_permlane32_swap)
    auto r = __builtin_amdgcn_permlane32_swap(a, b, false, false);
    lo = r[0]; hi = r[1];
#else
    unsigned ax = (unsigned)__shfl_xor((int)a, 32, 64);
    unsigned bx = (unsigned)__shfl_xor((int)b, 32, 64);
    bool lower = (threadIdx.x & 32) == 0;
    lo = lower ? a : bx;
    hi = lower ? ax : b;
#endif
}

// ---------------- depthwise 3x3 + BN -> Y^T [b][p][c]; wconv fused (y==12) ------
// v2: pad-free XOR-swizzled LDS rows (32 floats = 8 chunks, slot = c ^ (cc&7)),
// register-blocked conv (batched ds_read_b128 instead of 96 serial b32), edges
// as compile-time zeros. STRIDE=2 uses 4 rows/block (36.9KB LDS, 3-4 blocks/CU)
// with 8 thread-groups = 4 row-groups x 2 half-passes.
template <int STRIDE, int G, int HO, int WO>
__global__ __launch_bounds__(256) void dw_bn_kernel(
        const void* __restrict__ x, const void* __restrict__ wdw,
        const void* __restrict__ gamma, const void* __restrict__ beta,
        const void* __restrict__ mean, const void* __restrict__ var,
        bf16* __restrict__ yt,
        const void* __restrict__ w0, const void* __restrict__ w1,
        const void* __restrict__ w2, bf16* __restrict__ wdst) {
    constexpr int IN_ROWS = (G - 1) * STRIDE + 3;       // 10 (s1) or 9 (s2)
    constexpr int PT = G * WO;                          // pixels per block
    constexpr unsigned XSZ = 32u * IN_ROWS * 32 * 4;    // 40KB / 36.9KB
    constexpr unsigned OSZ = (unsigned)PT * 40 * 2;
    __shared__ __align__(16) char smem[XSZ > OSZ ? XSZ : OSZ];
    float* xs = (float*)smem;                           // row (i,cc) at ((i*32+cc)*32)
    ushort (*outt)[40] = (ushort (*)[40])smem;          // [pixel][cc]

    int isbf = probe_isbf(x);
    int rg = blockIdx.x;
    int c0 = blockIdx.y * 32;
    int b  = blockIdx.z;
    int tid = threadIdx.x;

    if (c0 >= CIN) {  // fused weight-convert blocks (blockIdx.y == 12, stride-1 only)
        const int n0 = INNER * CIN, n1 = 2 * INNER * CIN, n2 = INNER * CIN;
        const int total = n0 + n1 + n2;
        for (int i = (b * 4 + rg) * 256 + tid; i < total; i += 32768) {
            float v;
            if (i < n0) v = ldf(w0, i, isbf);
            else if (i < n0 + n1) v = ldf(w1, i - n0, isbf);
            else v = ldf(w2, i - n0 - n1, isbf);
            wdst[i] = f2b(v);
        }
        return;
    }

    int ri0 = rg * G * STRIDE - 1;

    // stage: lanes (wc fastest -> 64B global coalescing; cc next -> XOR bank spread)
    const int NCHUNK = 32 * IN_ROWS * 4;
    for (int ch = tid; ch < NCHUNK; ch += 256) {
        int wc = ch & 3;              // 8-float (32B) chunk along w
        int cc = (ch >> 2) & 31;
        int i  = ch >> 7;
        int row = ri0 + i;
        float f[8];
        if (row >= 0 && row < 32) {
            size_t goff = ((size_t)(b * CIN + c0 + cc) * 32 + row) * 32 + wc * 8;
            if (isbf) {
                uint4 v = *(const uint4*)((const bf16*)x + goff);
                const ushort* u = (const ushort*)&v;
#pragma unroll
                for (int j = 0; j < 8; j++) f[j] = __uint_as_float((unsigned)u[j] << 16);
            } else {
                float4 v0 = *(const float4*)((const float*)x + goff);
                float4 v1 = *(const float4*)((const float*)x + goff + 4);
                f[0] = v0.x; f[1] = v0.y; f[2] = v0.z; f[3] = v0.w;
                f[4] = v1.x; f[5] = v1.y; f[6] = v1.z; f[7] = v1.w;
            }
        } else {
#pragma unroll
            for (int j = 0; j < 8; j++) f[j] = 0.f;
        }
        float* rb = xs + ((size_t)(i * 32 + cc)) * 32;
        int key = cc & 7;
        float4 fa = {f[0], f[1], f[2], f[3]};
        float4 fb = {f[4], f[5], f[6], f[7]};
        *(float4*)(rb + ((2 * wc) ^ key) * 4)     = fa;
        *(float4*)(rb + ((2 * wc + 1) ^ key) * 4) = fb;
    }

    int cc = tid & 31;
    int g  = tid >> 5;
    int c  = c0 + cc;
    int key = cc & 7;
    float w9[9];
#pragma unroll
    for (int k = 0; k < 9; k++) w9[k] = ldf(wdw, c * 9 + k, isbf);
    float inv  = ldf(gamma, c, isbf) * rsqrtf(ldf(var, c, isbf) + 1e-5f);
    float bias = ldf(beta, c, isbf) - ldf(mean, c, isbf) * inv;
    __syncthreads();

    float o[STRIDE == 1 ? 32 : 8];
    if (STRIDE == 1) {
        // thread = (cc, row-group g); two 16-wide passes, rf[ky][j] = x[w=16p+j-1]
#pragma unroll
        for (int p = 0; p < 2; p++) {
            float rf[3][18];
#pragma unroll
            for (int ky = 0; ky < 3; ky++) {
                const float* rb = xs + ((size_t)((g + ky) * 32 + cc)) * 32;
#pragma unroll
                for (int cch = 0; cch < 4; cch++) {
                    float4 v = *(const float4*)(rb + ((4 * p + cch) ^ key) * 4);
                    rf[ky][1 + 4 * cch] = v.x; rf[ky][2 + 4 * cch] = v.y;
                    rf[ky][3 + 4 * cch] = v.z; rf[ky][4 + 4 * cch] = v.w;
                }
                rf[ky][0]  = p ? rb[((3 ^ key) * 4) + 3] : 0.f;  // w=16p-1
                rf[ky][17] = p ? 0.f : rb[((4 ^ key) * 4) + 0];  // w=16p+16
            }
#pragma unroll
            for (int j = 0; j < 16; j++) {
                float acc = w9[0] * rf[0][j] + w9[1] * rf[0][j + 1] + w9[2] * rf[0][j + 2]
                          + w9[3] * rf[1][j] + w9[4] * rf[1][j + 1] + w9[5] * rf[1][j + 2]
                          + w9[6] * rf[2][j] + w9[7] * rf[2][j + 1] + w9[8] * rf[2][j + 2];
                o[p * 16 + j] = acc * inv + bias;
            }
        }
    } else {
        // thread = (cc, rgrp = g&3, half = g>>2); 8 outputs; rf[j] = x[w=16h+j-1]
        int rgrp = g & 3, hf = g >> 2;
        float rf[3][17];
#pragma unroll
        for (int ky = 0; ky < 3; ky++) {
            const float* rb = xs + ((size_t)((2 * rgrp + ky) * 32 + cc)) * 32;
#pragma unroll
            for (int cch = 0; cch < 4; cch++) {
                float4 v = *(const float4*)(rb + ((4 * hf + cch) ^ key) * 4);
                rf[ky][1 + 4 * cch] = v.x; rf[ky][2 + 4 * cch] = v.y;
                rf[ky][3 + 4 * cch] = v.z; rf[ky][4 + 4 * cch] = v.w;
            }
            rf[ky][0] = hf ? rb[((3 ^ key) * 4) + 3] : 0.f;      // w=16h-1
        }
#pragma unroll
        for (int j = 0; j < 8; j++) {
            float acc = w9[0] * rf[0][2 * j] + w9[1] * rf[0][2 * j + 1] + w9[2] * rf[0][2 * j + 2]
                      + w9[3] * rf[1][2 * j] + w9[4] * rf[1][2 * j + 1] + w9[5] * rf[1][2 * j + 2]
                      + w9[6] * rf[2][2 * j] + w9[7] * rf[2][2 * j + 1] + w9[8] * rf[2][2 * j + 2];
            o[j] = acc * inv + bias;
        }
    }
    __syncthreads();  // all xs reads done -> safe to overwrite union with outputs

    if (STRIDE == 1) {
#pragma unroll
        for (int wo = 0; wo < 32; wo++) outt[g * WO + wo][cc] = f2bu(o[wo]);
    } else {
        int rgrp = g & 3, hf = g >> 2;
#pragma unroll
        for (int j = 0; j < 8; j++) outt[rgrp * 16 + hf * 8 + j][cc] = f2bu(o[j]);
    }
    __syncthreads();

    const size_t pbase = (size_t)b * (HO * WO) + (size_t)rg * G * WO;
    for (int chk = tid; chk < PT * 4; chk += 256) {
        int k = chk & 3, p = chk >> 2;
        uint4 v = *(const uint4*)&outt[p][k * 8];
        *(uint4*)(yt + (pbase + p) * CIN + c0 + k * 8) = v;
    }
}

// ---------------- merged QKV pointwise GEMM (modes 0+1), 3 blocks/CU -------------
__global__ __launch_bounds__(256, 3) void mfma_pw_qkv(
        const bf16* __restrict__ qpw, const bf16* __restrict__ yqt,
        bf16* __restrict__ qalt,
        const bf16* __restrict__ kvpw, const bf16* __restrict__ ykvt,
        bf16* __restrict__ kalt, bf16* __restrict__ valt) {
    __shared__ __align__(16) bf16 As[2][4096];  // 128 rows x 32 k
    __shared__ __align__(16) bf16 Bs[2][4096];
    int tid = threadIdx.x;
    int wave = tid >> 6, lane = tid & 63;
    int l15 = lane & 15, quad = lane >> 4;
    int wm = wave & 1, wn = wave >> 1;

    int bid = blockIdx.x;
    int P, b, p0, o0;
    const bf16 *asrc0, *bsrc0;
    bf16* outq;
    if (bid < 768) {                 // mode 0: Q path, grid (8,3,32) flattened
        int m = bid;
        int p0t = m & 7; m >>= 3;
        int o0t = m % 3; b = m / 3;
        P = 1024; p0 = p0t * 128; o0 = o0t * 128;
        asrc0 = yqt; bsrc0 = qpw; outq = qalt;
    } else {                          // mode 1: KV path, grid (2,6,32) flattened
        int m = bid - 768;
        int p0t = m & 1; m >>= 1;
        int o0t = m % 6; b = m / 6;
        P = 256; p0 = p0t * 128; o0 = o0t * 128;
        asrc0 = ykvt; bsrc0 = kvpw; outq = kalt;
    }

    const bf16* asrc = asrc0 + ((size_t)b * P + p0) * CIN;
    const bf16* bsrc = bsrc0 + (size_t)o0 * CIN;

    int srow = (lane >> 2);
    int sc   = lane & 3;
    auto stage = [&](int step, int buf) {
#pragma unroll
        for (int it = 0; it < 2; it++) {
            int row = wave * 32 + it * 16 + srow;
            int g = sc ^ (row & 3);
            size_t goff = (size_t)row * CIN + step * 32 + g * 8;
            dma16(asrc + goff, &As[buf][(wave * 2 + it) * 512]);
            dma16(bsrc + goff, &Bs[buf][(wave * 2 + it) * 512]);
        }
    };

    floatx4 acc[4][4];
#pragma unroll
    for (int pt = 0; pt < 4; pt++)
#pragma unroll
        for (int ot = 0; ot < 4; ot++) acc[pt][ot] = (floatx4){0.f, 0.f, 0.f, 0.f};

    stage(0, 0);
    __syncthreads();
    for (int s = 0; s < CIN / 32; s++) {
        int buf = s & 1;
        if (s < CIN / 32 - 1) stage(s + 1, buf ^ 1);
        bf16x8 af[4], bw[4];
        int slot = (quad ^ (l15 & 3)) * 8;
#pragma unroll
        for (int pt = 0; pt < 4; pt++)
            af[pt] = *(const bf16x8*)&As[buf][(wm * 64 + pt * 16 + l15) * 32 + slot];
#pragma unroll
        for (int ot = 0; ot < 4; ot++)
            bw[ot] = *(const bf16x8*)&Bs[buf][(wn * 64 + ot * 16 + l15) * 32 + slot];
#pragma unroll
        for (int pt = 0; pt < 4; pt++)
#pragma unroll
            for (int ot = 0; ot < 4; ot++)
                acc[pt][ot] = __builtin_amdgcn_mfma_f32_16x16x32_bf16(af[pt], bw[ot], acc[pt][ot], 0, 0, 0);
        __syncthreads();
    }

    int pw0 = p0 + wm * 64, ow0 = o0 + wn * 64;
#pragma unroll
    for (int ot = 0; ot < 4; ot++) {
        int o = ow0 + ot * 16 + l15;
        if (o < INNER) {
            int h = o >> 6, d = o & 63;
            bf16* base = outq + ((size_t)(b * HEADS + h) * P) * 64 + d;
#pragma unroll
            for (int pt = 0; pt < 4; pt++)
#pragma unroll
                for (int r = 0; r < 4; r++)
                    base[(size_t)(pw0 + pt * 16 + quad * 4 + r) * 64] = f2b(acc[pt][ot][r]);
        } else {
            int ch = o - INNER;
            bf16* base = valt + ((size_t)b * INNER + ch) * PKV;
#pragma unroll
            for (int pt = 0; pt < 4; pt++)
#pragma unroll
                for (int r = 0; r < 4; r++)
                    base[pw0 + pt * 16 + quad * 4 + r] = f2b(acc[pt][ot][r]);
        }
    }
}

// ---------------- out-projection GEMM (mode 2), 3 blocks/CU ----------------------
__global__ __launch_bounds__(256, 3) void mfma_pw_out(
        const bf16* __restrict__ wt, const bf16* __restrict__ yt,
        const void* __restrict__ bias, void* __restrict__ out0,
        const void* __restrict__ xprobe) {
    __shared__ __align__(16) bf16 As[2][4096];
    __shared__ __align__(16) bf16 Bs[2][4096];
    const int P = PQ, O = CIN;
    int tid = threadIdx.x;
    int wave = tid >> 6, lane = tid & 63;
    int l15 = lane & 15, quad = lane >> 4;
    int wm = wave & 1, wn = wave >> 1;
    int b = blockIdx.z;
    int p0 = blockIdx.x * 128;
    int o0 = blockIdx.y * 128;

    const bf16* asrc = yt + ((size_t)b * P + p0) * CIN;
    const bf16* bsrc = wt + (size_t)o0 * CIN;

    int srow = (lane >> 2);
    int sc   = lane & 3;
    auto stage = [&](int step, int buf) {
#pragma unroll
        for (int it = 0; it < 2; it++) {
            int row = wave * 32 + it * 16 + srow;
            int g = sc ^ (row & 3);
            size_t goff = (size_t)row * CIN + step * 32 + g * 8;
            dma16(asrc + goff, &As[buf][(wave * 2 + it) * 512]);
            dma16(bsrc + goff, &Bs[buf][(wave * 2 + it) * 512]);
        }
    };

    floatx4 acc[4][4];
#pragma unroll
    for (int pt = 0; pt < 4; pt++)
#pragma unroll
        for (int ot = 0; ot < 4; ot++) acc[pt][ot] = (floatx4){0.f, 0.f, 0.f, 0.f};

    stage(0, 0);
    __syncthreads();
    for (int s = 0; s < CIN / 32; s++) {
        int buf = s & 1;
        if (s < CIN / 32 - 1) stage(s + 1, buf ^ 1);
        bf16x8 af[4], bw[4];
        int slot = (quad ^ (l15 & 3)) * 8;
#pragma unroll
        for (int pt = 0; pt < 4; pt++)
            af[pt] = *(const bf16x8*)&As[buf][(wm * 64 + pt * 16 + l15) * 32 + slot];
#pragma unroll
        for (int ot = 0; ot < 4; ot++)
            bw[ot] = *(const bf16x8*)&Bs[buf][(wn * 64 + ot * 16 + l15) * 32 + slot];
#pragma unroll
        for (int pt = 0; pt < 4; pt++)
#pragma unroll
            for (int ot = 0; ot < 4; ot++)
                acc[pt][ot] = __builtin_amdgcn_mfma_f32_16x16x32_bf16(af[pt], bw[ot], acc[pt][ot], 0, 0, 0);
        __syncthreads();
    }

    int pw0 = p0 + wm * 64, ow0 = o0 + wn * 64;
    int isbf = probe_isbf(xprobe);
#pragma unroll
    for (int ot = 0; ot < 4; ot++) {
        int o = ow0 + ot * 16 + l15;
        float bv = ldf(bias, o, isbf);
#pragma unroll
        for (int pt = 0; pt < 4; pt++) {
            int p = pw0 + pt * 16 + quad * 4;
            size_t idx = ((size_t)b * O + o) * P + p;
            if (!isbf) {
                float4 v4 = {acc[pt][ot][0] + bv, acc[pt][ot][1] + bv,
                             acc[pt][ot][2] + bv, acc[pt][ot][3] + bv};
                *(float4*)((float*)out0 + idx) = v4;
            } else {
                ushort4 u4 = {f2bu(acc[pt][ot][0] + bv), f2bu(acc[pt][ot][1] + bv),
                              f2bu(acc[pt][ot][2] + bv), f2bu(acc[pt][ot][3] + bv)};
                *(ushort4*)((bf16*)out0 + idx) = u4;
            }
        }
    }
}

// ---------------- fused MFMA attention v6: 2-tile software pipeline --------------
#define QKT(S, Q0, Q1)                                                              \
    do {                                                                            \
        floatx4 z_ = (floatx4){0.f, 0.f, 0.f, 0.f};                                 \
        _Pragma("unroll")                                                           \
        for (int jt_ = 0; jt_ < 16; jt_++) {                                        \
            int j_ = jt_ * 16 + l15;                                                \
            bf16x8 k0_ = *(const bf16x8*)&Kl[j_ * 64 + (quad ^ (j_ & 7)) * 8];      \
            bf16x8 k1_ = *(const bf16x8*)&Kl[j_ * 64 + ((4 + quad) ^ (j_ & 7)) * 8];\
            floatx4 t_ = __builtin_amdgcn_mfma_f32_16x16x32_bf16(k0_, Q0, z_, 0, 0, 0); \
            S[jt_] = __builtin_amdgcn_mfma_f32_16x16x32_bf16(k1_, Q1, t_, 0, 0, 0); \
        }                                                                           \
    } while (0)

#define SOFTMAX(S, PINV)                                                            \
    do {                                                                            \
        float m0_ = S[0][0], m1_ = S[0][1], m2_ = S[0][2], m3_ = S[0][3];           \
        _Pragma("unroll")                                                           \
        for (int jt_ = 1; jt_ < 16; jt_++) {                                        \
            m0_ = fmaxf(m0_, S[jt_][0]); m1_ = fmaxf(m1_, S[jt_][1]);               \
            m2_ = fmaxf(m2_, S[jt_][2]); m3_ = fmaxf(m3_, S[jt_][3]);               \
        }                                                                           \
        float mx_ = fmaxf(fmaxf(m0_, m1_), fmaxf(m2_, m3_));                        \
        mx_ = fmaxf(mx_, __shfl_xor(mx_, 16, 64));                                  \
        mx_ = fmaxf(mx_, __shfl_xor(mx_, 32, 64));                                  \
        float mc_ = mx_ * C;                                                        \
        float a0_ = 0.f, a1_ = 0.f, a2_ = 0.f, a3_ = 0.f;                           \
        _Pragma("unroll")                                                           \
        for (int jt_ = 0; jt_ < 16; jt_++) {                                        \
            float e0_ = exp2f(S[jt_][0] * C - mc_);                                 \
            float e1_ = exp2f(S[jt_][1] * C - mc_);                                 \
            float e2_ = exp2f(S[jt_][2] * C - mc_);                                 \
            float e3_ = exp2f(S[jt_][3] * C - mc_);                                 \
            S[jt_][0] = e0_; S[jt_][1] = e1_; S[jt_][2] = e2_; S[jt_][3] = e3_;     \
            a0_ += e0_; a1_ += e1_; a2_ += e2_; a3_ += e3_;                         \
        }                                                                           \
        float sm_ = (a0_ + a1_) + (a2_ + a3_);                                      \
        sm_ += __shfl_xor(sm_, 16, 64);                                             \
        sm_ += __shfl_xor(sm_, 32, 64);                                             \
        PINV = 1.f / sm_;                                                           \
    } while (0)

#define PV_STORE(S, PINV, T)                                                        \
    do {                                                                            \
        floatx4 oacc_[4];                                                           \
        _Pragma("unroll")                                                           \
        for (int nt_ = 0; nt_ < 4; nt_++) oacc_[nt_] = (floatx4){0.f, 0.f, 0.f, 0.f}; \
        _Pragma("unroll")                                                           \
        for (int kk_ = 0; kk_ < 8; kk_++) {                                         \
            floatx4 se_ = S[2 * kk_], so_ = S[2 * kk_ + 1];                         \
            unsigned E0_ = cvtpk(se_[0] * PINV, se_[1] * PINV);                     \
            unsigned E1_ = cvtpk(se_[2] * PINV, se_[3] * PINV);                     \
            unsigned D0_ = cvtpk(so_[0] * PINV, so_[1] * PINV);                     \
            unsigned D1_ = cvtpk(so_[2] * PINV, so_[3] * PINV);                     \
            unsigned lo0_, hi0_, lo1_, hi1_;                                        \
            halfswap(E0_, D0_, lo0_, hi0_);                                         \
            halfswap(E1_, D1_, lo1_, hi1_);                                         \
            unsigned sel0_ = (quad & 1) ? hi0_ : lo0_;                              \
            unsigned sel1_ = (quad & 1) ? hi1_ : lo1_;                              \
            unsigned x0_ = (unsigned)__shfl_xor((int)sel0_, 16, 64);                \
            unsigned x1_ = (unsigned)__shfl_xor((int)sel1_, 16, 64);                \
            union { unsigned u[4]; bf16x8 v; } pf_;                                 \
            pf_.u[0] = (quad & 1) ? x0_ : sel0_;                                    \
            pf_.u[1] = (quad & 1) ? x1_ : sel1_;                                    \
            pf_.u[2] = (quad & 1) ? sel0_ : x0_;                                    \
            pf_.u[3] = (quad & 1) ? sel1_ : x1_;                                    \
            _Pragma("unroll")                                                       \
            for (int nt_ = 0; nt_ < 4; nt_++) {                                     \
                int d_ = nt_ * 16 + l15;                                            \
                bf16x8 bv_ = *(const bf16x8*)&Vl[d_ * 256 + ((kk_ * 4 + quad) ^ (d_ & 15)) * 8]; \
                oacc_[nt_] = __builtin_amdgcn_mfma_f32_16x16x32_bf16(pf_.v, bv_, oacc_[nt_], 0, 0, 0); \
            }                                                                       \
        }                                                                           \
        _Pragma("unroll")                                                           \
        for (int nt_ = 0; nt_ < 4; nt_++)                                           \
            _Pragma("unroll")                                                       \
            for (int r_ = 0; r_ < 4; r_++)                                          \
                Ot[wave][quad * 4 + r_][nt_ * 16 + l15] = f2bu(oacc_[nt_][r_]);     \
        int row_ = lane >> 2, d0_ = (lane & 3) * 16;                                \
        uint4 ld0_ = *(const uint4*)&Ot[wave][row_][d0_];                           \
        uint4 ld1_ = *(const uint4*)&Ot[wave][row_][d0_ + 8];                       \
        bf16* dst_ = ao + ((size_t)b * PQ + p0 + (T) * 64 + row_) * INNER + h * DH + d0_; \
        *(uint4*)dst_ = ld0_;                                                       \
        *(uint4*)(dst_ + 8) = ld1_;                                                 \
    } while (0)

__global__ __launch_bounds__(256, 2) void attn_kernel(
        const bf16* __restrict__ qalt, const bf16* __restrict__ kalt,
        const bf16* __restrict__ valt, bf16* __restrict__ ao) {
    __shared__ __align__(16) bf16 Kl[16384];        // 32 KB, persistent
    __shared__ __align__(16) bf16 Vl[16384];        // 32 KB, persistent
    __shared__ __align__(16) ushort Ot[4][16][80];  // 10 KB, per-wave scratch
    int tid = threadIdx.x;
    int wave = tid >> 6, lane = tid & 63;
    int l15 = lane & 15, quad = lane >> 4;
    int blk = blockIdx.x;
    int swz = (blk & 7) * 96 + (blk >> 3);   // 768 = 8*96, bijective
    int seg = swz & 3;                        // 4 segments of 256 Q rows
    int bh  = swz >> 2;                       // 4 consecutive segs share (b,h) & XCD
    int b = bh / HEADS, h = bh % HEADS;

    const bf16* qbase = qalt + (size_t)(b * HEADS + h) * PQ * DH;
    const bf16* kbase = kalt + (size_t)(b * HEADS + h) * PKV * DH;
    const bf16* vbase = valt + ((size_t)b * INNER + h * DH) * PKV;

    // stage K: rows 128B, granule slot = cs ^ (row&7)
    {
        int j = lane >> 3, cs = lane & 7;
#pragma unroll
        for (int it = 0; it < 8; it++) {
            int jr = (wave * 8 + it) * 8 + j;
            int g = cs ^ (jr & 7);
            dma16(kbase + (size_t)jr * 64 + g * 8, &Kl[(wave * 8 + it) * 512]);
        }
        // stage V: rows 512B, granule slot = cs2 ^ (row&15)
        int d = lane >> 5, cs2 = lane & 31;
#pragma unroll
        for (int it = 0; it < 8; it++) {
            int dr = (wave * 8 + it) * 2 + d;
            int g = cs2 ^ (dr & 15);
            dma16(vbase + (size_t)dr * 256 + g * 8, &Vl[(wave * 8 + it) * 512]);
        }
    }

    int p0 = seg * 256 + wave * 16;  // tile t adds t*64
    const bf16* qrow = qbase + (size_t)(p0 + l15) * DH + quad * 8;
    bf16x8 qA0 = *(const bf16x8*)qrow;
    bf16x8 qA1 = *(const bf16x8*)(qrow + 32);
    bf16x8 qB0 = *(const bf16x8*)(qrow + 64 * DH);
    bf16x8 qB1 = *(const bf16x8*)(qrow + 64 * DH + 32);
    __syncthreads();  // drains DMA (vmcnt) + cross-wave staging visibility

    const float C = ATTN_SCALE * 1.44269504f;   // fold scale into exp2
    floatx4 sA[16], sB[16];
    float pinv;

    QKT(sA, qA0, qA1);                          // tile 0
    qA0 = *(const bf16x8*)(qrow + 128 * DH);    // Q(t2), hides under t0 compute
    qA1 = *(const bf16x8*)(qrow + 128 * DH + 32);

    SOFTMAX(sA, pinv);
    QKT(sB, qB0, qB1);                          // tile 1
    PV_STORE(sA, pinv, 0);
    qB0 = *(const bf16x8*)(qrow + 192 * DH);    // Q(t3), hides under t1 compute
    qB1 = *(const bf16x8*)(qrow + 192 * DH + 32);

    SOFTMAX(sB, pinv);
    QKT(sA, qA0, qA1);                          // tile 2
    PV_STORE(sB, pinv, 1);

    SOFTMAX(sA, pinv);
    QKT(sB, qB0, qB1);                          // tile 3
    PV_STORE(sA, pinv, 2);

    SOFTMAX(sB, pinv);
    PV_STORE(sB, pinv, 3);
}

extern "C" void kernel_launch(void* const* d_in, const int* in_sizes, int n_in,
                              void* d_out, int out_size, void* d_ws, size_t ws_size,
                              hipStream_t stream) {
    const void* x        = d_in[0];
    const void* q_dw     = d_in[1];
    const void* q_gamma  = d_in[2];
    const void* q_beta   = d_in[3];
    const void* q_mean   = d_in[4];
    const void* q_var    = d_in[5];
    const void* q_pw     = d_in[6];
    const void* kv_dw    = d_in[7];
    const void* kv_gamma = d_in[8];
    const void* kv_beta  = d_in[9];
    const void* kv_mean  = d_in[10];
    const void* kv_var   = d_in[11];
    const void* kv_pw    = d_in[12];
    const void* out_w    = d_in[13];
    const void* out_b    = d_in[14];

    bf16* pool = (bf16*)((char*)d_ws + 256);
    bf16* yqt  = pool;                              // [32,1024,384] Y^T Q-path; reused as aob
    bf16* ykvt = yqt  + (size_t)32 * 1024 * 384;    // [32,256,384]  Y^T KV-path
    bf16* qalt = ykvt + (size_t)32 * 256 * 384;     // [32,6,1024,64]
    bf16* kalt = qalt + (size_t)32 * 6 * 1024 * 64; // [32,6,256,64]
    bf16* valt = kalt + (size_t)32 * 6 * 256 * 64;  // [32,384,256]
    bf16* wbf  = valt + (size_t)32 * 384 * 256;     // q_pw | kv_pw | out_w bf16
    bf16* qpw_bf = wbf;
    bf16* kvpw_bf = wbf + (size_t)INNER * CIN;
    bf16* outw_bf = kvpw_bf + (size_t)2 * INNER * CIN;
    bf16* aob  = yqt;  // alias: yqt dead after Q pointwise; attn writes [b][p][c]

    dw_bn_kernel<1, 8, 32, 32><<<dim3(4, 13, 32), 256, 0, stream>>>(
        x, q_dw, q_gamma, q_beta, q_mean, q_var, yqt, q_pw, kv_pw, out_w, wbf);
    dw_bn_kernel<2, 4, 16, 16><<<dim3(4, 12, 32), 256, 0, stream>>>(
        x, kv_dw, kv_gamma, kv_beta, kv_mean, kv_var, ykvt, nullptr, nullptr, nullptr, nullptr);
    mfma_pw_qkv<<<1152, 256, 0, stream>>>(qpw_bf, yqt, qalt, kvpw_bf, ykvt, kalt, valt);
    attn_kernel<<<768, 256, 0, stream>>>(qalt, kalt, valt, aob);
    mfma_pw_out<<<dim3(8, 3, 32), 256, 0, stream>>>(outw_bf, aob, out_b, d_out, x);
}

// Round 10
// 225.745 us; speedup vs baseline: 1.1671x; 1.0117x over previous
//
#include <hip/hip_runtime.h>
#include <hip/hip_bf16.h>

#define CIN 384
#define PQ 1024
#define PKV 256
#define HEADS 6
#define DH 64
#define INNER 384
#define ATTN_SCALE 0.125f

typedef __hip_bfloat16 bf16;
typedef unsigned short ushort;
typedef __bf16 bf16x8 __attribute__((ext_vector_type(8)));
typedef float floatx4 __attribute__((ext_vector_type(4)));

__device__ __forceinline__ float b2f(bf16 v) { return __bfloat162float(v); }
__device__ __forceinline__ bf16 f2b(float v) { return __float2bfloat16(v); }
__device__ __forceinline__ ushort f2bu(float v) { bf16 h = __float2bfloat16(v); return *(ushort*)&h; }
__device__ __forceinline__ float ldf(const void* p, size_t i, int isbf) {
    return isbf ? __bfloat162float(((const bf16*)p)[i]) : ((const float*)p)[i];
}
// async global->LDS DMA, 16B per lane; LDS dest = uniform base + lane*16
__device__ __forceinline__ void dma16(const bf16* g, bf16* l) {
    __builtin_amdgcn_global_load_lds(
        (const __attribute__((address_space(1))) unsigned int*)g,
        (__attribute__((address_space(3))) unsigned int*)l, 16, 0, 0);
}
// uniform scalar dtype probe
__device__ __forceinline__ int probe_isbf(const void* x) {
    const unsigned* u = (const unsigned*)x;
    int cnt = 0;
    for (int i = 0; i < 64; i++) {
        unsigned e = (u[i] >> 7) & 0xFFu;
        cnt += (e >= 100u && e <= 140u) ? 1 : 0;
    }
    return cnt >= 48 ? 1 : 0;
}
__device__ __forceinline__ unsigned cvtpk(float lo, float hi) {
    unsigned r;
    asm("v_cvt_pk_bf16_f32 %0, %1, %2" : "=v"(r) : "v"(lo), "v"(hi));
    return r;
}
// half-wave swap: lo = [a(lanes0-31) | b(lanes0-31)], hi = [a(32-63) | b(32-63)]
__device__ __forceinline__ void halfswap(unsigned a, unsigned b, unsigned& lo, unsigned& hi) {
#if __has_builtin(__builtin_amdgcn_permlane32_swap)
    auto r = __builtin_amdgcn_permlane32_swap(a, b, false, false);
    lo = r[0]; hi = r[1];
#else
    unsigned ax = (unsigned)__shfl_xor((int)a, 32, 64);
    unsigned bx = (unsigned)__shfl_xor((int)b, 32, 64);
    bool lower = (threadIdx.x & 32) == 0;
    lo = lower ? a : bx;
    hi = lower ? ax : b;
#endif
}

// ---------------- depthwise 3x3 + BN body (proven round-9 code, relocated) ------
// Pad-free XOR-swizzled LDS rows (32 floats = 8 chunks, slot = c ^ (cc&7)),
// register-blocked conv, edges as compile-time zeros.
template <int STRIDE, int G, int HO, int WO>
__device__ __forceinline__ void dw_bn_body(
        const void* __restrict__ x, const void* __restrict__ wdw,
        const void* __restrict__ gamma, const void* __restrict__ beta,
        const void* __restrict__ mean, const void* __restrict__ var,
        bf16* __restrict__ yt, int isbf, int rg, int c0, int b, int tid,
        char* smem) {
    constexpr int IN_ROWS = (G - 1) * STRIDE + 3;       // 10 (s1) or 9 (s2)
    constexpr int PT = G * WO;                          // pixels per block
    float* xs = (float*)smem;                           // row (i,cc) at ((i*32+cc)*32)
    ushort (*outt)[40] = (ushort (*)[40])smem;          // [pixel][cc]

    int ri0 = rg * G * STRIDE - 1;

    // stage: lanes (wc fastest -> 64B global coalescing; cc next -> XOR bank spread)
    const int NCHUNK = 32 * IN_ROWS * 4;
    for (int ch = tid; ch < NCHUNK; ch += 256) {
        int wc = ch & 3;              // 8-float (32B) chunk along w
        int cc = (ch >> 2) & 31;
        int i  = ch >> 7;
        int row = ri0 + i;
        float f[8];
        if (row >= 0 && row < 32) {
            size_t goff = ((size_t)(b * CIN + c0 + cc) * 32 + row) * 32 + wc * 8;
            if (isbf) {
                uint4 v = *(const uint4*)((const bf16*)x + goff);
                const ushort* u = (const ushort*)&v;
#pragma unroll
                for (int j = 0; j < 8; j++) f[j] = __uint_as_float((unsigned)u[j] << 16);
            } else {
                float4 v0 = *(const float4*)((const float*)x + goff);
                float4 v1 = *(const float4*)((const float*)x + goff + 4);
                f[0] = v0.x; f[1] = v0.y; f[2] = v0.z; f[3] = v0.w;
                f[4] = v1.x; f[5] = v1.y; f[6] = v1.z; f[7] = v1.w;
            }
        } else {
#pragma unroll
            for (int j = 0; j < 8; j++) f[j] = 0.f;
        }
        float* rb = xs + ((size_t)(i * 32 + cc)) * 32;
        int key = cc & 7;
        float4 fa = {f[0], f[1], f[2], f[3]};
        float4 fb = {f[4], f[5], f[6], f[7]};
        *(float4*)(rb + ((2 * wc) ^ key) * 4)     = fa;
        *(float4*)(rb + ((2 * wc + 1) ^ key) * 4) = fb;
    }

    int cc = tid & 31;
    int g  = tid >> 5;
    int c  = c0 + cc;
    int key = cc & 7;
    float w9[9];
#pragma unroll
    for (int k = 0; k < 9; k++) w9[k] = ldf(wdw, c * 9 + k, isbf);
    float inv  = ldf(gamma, c, isbf) * rsqrtf(ldf(var, c, isbf) + 1e-5f);
    float bias = ldf(beta, c, isbf) - ldf(mean, c, isbf) * inv;
    __syncthreads();

    float o[STRIDE == 1 ? 32 : 8];
    if (STRIDE == 1) {
        // thread = (cc, row-group g); two 16-wide passes, rf[ky][j] = x[w=16p+j-1]
#pragma unroll
        for (int p = 0; p < 2; p++) {
            float rf[3][18];
#pragma unroll
            for (int ky = 0; ky < 3; ky++) {
                const float* rb = xs + ((size_t)((g + ky) * 32 + cc)) * 32;
#pragma unroll
                for (int cch = 0; cch < 4; cch++) {
                    float4 v = *(const float4*)(rb + ((4 * p + cch) ^ key) * 4);
                    rf[ky][1 + 4 * cch] = v.x; rf[ky][2 + 4 * cch] = v.y;
                    rf[ky][3 + 4 * cch] = v.z; rf[ky][4 + 4 * cch] = v.w;
                }
                rf[ky][0]  = p ? rb[((3 ^ key) * 4) + 3] : 0.f;  // w=16p-1
                rf[ky][17] = p ? 0.f : rb[((4 ^ key) * 4) + 0];  // w=16p+16
            }
#pragma unroll
            for (int j = 0; j < 16; j++) {
                float acc = w9[0] * rf[0][j] + w9[1] * rf[0][j + 1] + w9[2] * rf[0][j + 2]
                          + w9[3] * rf[1][j] + w9[4] * rf[1][j + 1] + w9[5] * rf[1][j + 2]
                          + w9[6] * rf[2][j] + w9[7] * rf[2][j + 1] + w9[8] * rf[2][j + 2];
                o[p * 16 + j] = acc * inv + bias;
            }
        }
    } else {
        // thread = (cc, rgrp = g&3, half = g>>2); 8 outputs; rf[j] = x[w=16h+j-1]
        int rgrp = g & 3, hf = g >> 2;
        float rf[3][17];
#pragma unroll
        for (int ky = 0; ky < 3; ky++) {
            const float* rb = xs + ((size_t)((2 * rgrp + ky) * 32 + cc)) * 32;
#pragma unroll
            for (int cch = 0; cch < 4; cch++) {
                float4 v = *(const float4*)(rb + ((4 * hf + cch) ^ key) * 4);
                rf[ky][1 + 4 * cch] = v.x; rf[ky][2 + 4 * cch] = v.y;
                rf[ky][3 + 4 * cch] = v.z; rf[ky][4 + 4 * cch] = v.w;
            }
            rf[ky][0] = hf ? rb[((3 ^ key) * 4) + 3] : 0.f;      // w=16h-1
        }
#pragma unroll
        for (int j = 0; j < 8; j++) {
            float acc = w9[0] * rf[0][2 * j] + w9[1] * rf[0][2 * j + 1] + w9[2] * rf[0][2 * j + 2]
                      + w9[3] * rf[1][2 * j] + w9[4] * rf[1][2 * j + 1] + w9[5] * rf[1][2 * j + 2]
                      + w9[6] * rf[2][2 * j] + w9[7] * rf[2][2 * j + 1] + w9[8] * rf[2][2 * j + 2];
            o[j] = acc * inv + bias;
        }
    }
    __syncthreads();  // all xs reads done -> safe to overwrite union with outputs

    if (STRIDE == 1) {
#pragma unroll
        for (int wo = 0; wo < 32; wo++) outt[g * WO + wo][cc] = f2bu(o[wo]);
    } else {
        int rgrp = g & 3, hf = g >> 2;
#pragma unroll
        for (int j = 0; j < 8; j++) outt[rgrp * 16 + hf * 8 + j][cc] = f2bu(o[j]);
    }
    __syncthreads();

    const size_t pbase = (size_t)b * (HO * WO) + (size_t)rg * G * WO;
    for (int chk = tid; chk < PT * 4; chk += 256) {
        int k = chk & 3, p = chk >> 2;
        uint4 v = *(const uint4*)&outt[p][k * 8];
        *(uint4*)(yt + (pbase + p) * CIN + c0 + k * 8) = v;
    }
}

// ---------------- merged dw_bn dispatch: s1 conv | wconv | s2 conv ---------------
// grid (4, 25, 32): y<12 -> stride-1 conv (c0=y*32); y==12 -> weight convert;
// y>12 -> stride-2 conv (c0=(y-13)*32). One launch replaces three.
__global__ __launch_bounds__(256) void dw_bn_all(
        const void* __restrict__ x,
        const void* __restrict__ q_dw, const void* __restrict__ q_gamma,
        const void* __restrict__ q_beta, const void* __restrict__ q_mean,
        const void* __restrict__ q_var, bf16* __restrict__ yqt,
        const void* __restrict__ kv_dw, const void* __restrict__ kv_gamma,
        const void* __restrict__ kv_beta, const void* __restrict__ kv_mean,
        const void* __restrict__ kv_var, bf16* __restrict__ ykvt,
        const void* __restrict__ w0, const void* __restrict__ w1,
        const void* __restrict__ w2, bf16* __restrict__ wdst) {
    __shared__ __align__(16) char smem[40960];
    int isbf = probe_isbf(x);
    int rg = blockIdx.x;
    int y  = blockIdx.y;
    int b  = blockIdx.z;
    int tid = threadIdx.x;

    if (y < 12) {
        dw_bn_body<1, 8, 32, 32>(x, q_dw, q_gamma, q_beta, q_mean, q_var,
                                 yqt, isbf, rg, y * 32, b, tid, smem);
    } else if (y == 12) {
        const int n0 = INNER * CIN, n1 = 2 * INNER * CIN, n2 = INNER * CIN;
        const int total = n0 + n1 + n2;
        for (int i = (b * 4 + rg) * 256 + tid; i < total; i += 32768) {
            float v;
            if (i < n0) v = ldf(w0, i, isbf);
            else if (i < n0 + n1) v = ldf(w1, i - n0, isbf);
            else v = ldf(w2, i - n0 - n1, isbf);
            wdst[i] = f2b(v);
        }
    } else {
        dw_bn_body<2, 4, 16, 16>(x, kv_dw, kv_gamma, kv_beta, kv_mean, kv_var,
                                 ykvt, isbf, rg, (y - 13) * 32, b, tid, smem);
    }
}

// ---------------- merged QKV pointwise GEMM (modes 0+1), 3 blocks/CU -------------
__global__ __launch_bounds__(256, 3) void mfma_pw_qkv(
        const bf16* __restrict__ qpw, const bf16* __restrict__ yqt,
        bf16* __restrict__ qalt,
        const bf16* __restrict__ kvpw, const bf16* __restrict__ ykvt,
        bf16* __restrict__ kalt, bf16* __restrict__ valt) {
    __shared__ __align__(16) bf16 As[2][4096];  // 128 rows x 32 k
    __shared__ __align__(16) bf16 Bs[2][4096];
    int tid = threadIdx.x;
    int wave = tid >> 6, lane = tid & 63;
    int l15 = lane & 15, quad = lane >> 4;
    int wm = wave & 1, wn = wave >> 1;

    int bid = blockIdx.x;
    int P, b, p0, o0;
    const bf16 *asrc0, *bsrc0;
    bf16* outq;
    if (bid < 768) {                 // mode 0: Q path, grid (8,3,32) flattened
        int m = bid;
        int p0t = m & 7; m >>= 3;
        int o0t = m % 3; b = m / 3;
        P = 1024; p0 = p0t * 128; o0 = o0t * 128;
        asrc0 = yqt; bsrc0 = qpw; outq = qalt;
    } else {                          // mode 1: KV path, grid (2,6,32) flattened
        int m = bid - 768;
        int p0t = m & 1; m >>= 1;
        int o0t = m % 6; b = m / 6;
        P = 256; p0 = p0t * 128; o0 = o0t * 128;
        asrc0 = ykvt; bsrc0 = kvpw; outq = kalt;
    }

    const bf16* asrc = asrc0 + ((size_t)b * P + p0) * CIN;
    const bf16* bsrc = bsrc0 + (size_t)o0 * CIN;

    int srow = (lane >> 2);
    int sc   = lane & 3;
    auto stage = [&](int step, int buf) {
#pragma unroll
        for (int it = 0; it < 2; it++) {
            int row = wave * 32 + it * 16 + srow;
            int g = sc ^ (row & 3);
            size_t goff = (size_t)row * CIN + step * 32 + g * 8;
            dma16(asrc + goff, &As[buf][(wave * 2 + it) * 512]);
            dma16(bsrc + goff, &Bs[buf][(wave * 2 + it) * 512]);
        }
    };

    floatx4 acc[4][4];
#pragma unroll
    for (int pt = 0; pt < 4; pt++)
#pragma unroll
        for (int ot = 0; ot < 4; ot++) acc[pt][ot] = (floatx4){0.f, 0.f, 0.f, 0.f};

    stage(0, 0);
    __syncthreads();
    for (int s = 0; s < CIN / 32; s++) {
        int buf = s & 1;
        if (s < CIN / 32 - 1) stage(s + 1, buf ^ 1);
        bf16x8 af[4], bw[4];
        int slot = (quad ^ (l15 & 3)) * 8;
#pragma unroll
        for (int pt = 0; pt < 4; pt++)
            af[pt] = *(const bf16x8*)&As[buf][(wm * 64 + pt * 16 + l15) * 32 + slot];
#pragma unroll
        for (int ot = 0; ot < 4; ot++)
            bw[ot] = *(const bf16x8*)&Bs[buf][(wn * 64 + ot * 16 + l15) * 32 + slot];
#pragma unroll
        for (int pt = 0; pt < 4; pt++)
#pragma unroll
            for (int ot = 0; ot < 4; ot++)
                acc[pt][ot] = __builtin_amdgcn_mfma_f32_16x16x32_bf16(af[pt], bw[ot], acc[pt][ot], 0, 0, 0);
        __syncthreads();
    }

    int pw0 = p0 + wm * 64, ow0 = o0 + wn * 64;
#pragma unroll
    for (int ot = 0; ot < 4; ot++) {
        int o = ow0 + ot * 16 + l15;
        if (o < INNER) {
            int h = o >> 6, d = o & 63;
            bf16* base = outq + ((size_t)(b * HEADS + h) * P) * 64 + d;
#pragma unroll
            for (int pt = 0; pt < 4; pt++)
#pragma unroll
                for (int r = 0; r < 4; r++)
                    base[(size_t)(pw0 + pt * 16 + quad * 4 + r) * 64] = f2b(acc[pt][ot][r]);
        } else {
            int ch = o - INNER;
            bf16* base = valt + ((size_t)b * INNER + ch) * PKV;
#pragma unroll
            for (int pt = 0; pt < 4; pt++)
#pragma unroll
                for (int r = 0; r < 4; r++)
                    base[pw0 + pt * 16 + quad * 4 + r] = f2b(acc[pt][ot][r]);
        }
    }
}

// ---------------- out-projection GEMM (mode 2), 3 blocks/CU ----------------------
__global__ __launch_bounds__(256, 3) void mfma_pw_out(
        const bf16* __restrict__ wt, const bf16* __restrict__ yt,
        const void* __restrict__ bias, void* __restrict__ out0,
        const void* __restrict__ xprobe) {
    __shared__ __align__(16) bf16 As[2][4096];
    __shared__ __align__(16) bf16 Bs[2][4096];
    const int P = PQ, O = CIN;
    int tid = threadIdx.x;
    int wave = tid >> 6, lane = tid & 63;
    int l15 = lane & 15, quad = lane >> 4;
    int wm = wave & 1, wn = wave >> 1;
    int b = blockIdx.z;
    int p0 = blockIdx.x * 128;
    int o0 = blockIdx.y * 128;

    const bf16* asrc = yt + ((size_t)b * P + p0) * CIN;
    const bf16* bsrc = wt + (size_t)o0 * CIN;

    int srow = (lane >> 2);
    int sc   = lane & 3;
    auto stage = [&](int step, int buf) {
#pragma unroll
        for (int it = 0; it < 2; it++) {
            int row = wave * 32 + it * 16 + srow;
            int g = sc ^ (row & 3);
            size_t goff = (size_t)row * CIN + step * 32 + g * 8;
            dma16(asrc + goff, &As[buf][(wave * 2 + it) * 512]);
            dma16(bsrc + goff, &Bs[buf][(wave * 2 + it) * 512]);
        }
    };

    floatx4 acc[4][4];
#pragma unroll
    for (int pt = 0; pt < 4; pt++)
#pragma unroll
        for (int ot = 0; ot < 4; ot++) acc[pt][ot] = (floatx4){0.f, 0.f, 0.f, 0.f};

    stage(0, 0);
    __syncthreads();
    for (int s = 0; s < CIN / 32; s++) {
        int buf = s & 1;
        if (s < CIN / 32 - 1) stage(s + 1, buf ^ 1);
        bf16x8 af[4], bw[4];
        int slot = (quad ^ (l15 & 3)) * 8;
#pragma unroll
        for (int pt = 0; pt < 4; pt++)
            af[pt] = *(const bf16x8*)&As[buf][(wm * 64 + pt * 16 + l15) * 32 + slot];
#pragma unroll
        for (int ot = 0; ot < 4; ot++)
            bw[ot] = *(const bf16x8*)&Bs[buf][(wn * 64 + ot * 16 + l15) * 32 + slot];
#pragma unroll
        for (int pt = 0; pt < 4; pt++)
#pragma unroll
            for (int ot = 0; ot < 4; ot++)
                acc[pt][ot] = __builtin_amdgcn_mfma_f32_16x16x32_bf16(af[pt], bw[ot], acc[pt][ot], 0, 0, 0);
        __syncthreads();
    }

    int pw0 = p0 + wm * 64, ow0 = o0 + wn * 64;
    int isbf = probe_isbf(xprobe);
#pragma unroll
    for (int ot = 0; ot < 4; ot++) {
        int o = ow0 + ot * 16 + l15;
        float bv = ldf(bias, o, isbf);
#pragma unroll
        for (int pt = 0; pt < 4; pt++) {
            int p = pw0 + pt * 16 + quad * 4;
            size_t idx = ((size_t)b * O + o) * P + p;
            if (!isbf) {
                float4 v4 = {acc[pt][ot][0] + bv, acc[pt][ot][1] + bv,
                             acc[pt][ot][2] + bv, acc[pt][ot][3] + bv};
                *(float4*)((float*)out0 + idx) = v4;
            } else {
                ushort4 u4 = {f2bu(acc[pt][ot][0] + bv), f2bu(acc[pt][ot][1] + bv),
                              f2bu(acc[pt][ot][2] + bv), f2bu(acc[pt][ot][3] + bv)};
                *(ushort4*)((bf16*)out0 + idx) = u4;
            }
        }
    }
}

// ---------------- fused MFMA attention v6: 2-tile software pipeline --------------
#define QKT(S, Q0, Q1)                                                              \
    do {                                                                            \
        floatx4 z_ = (floatx4){0.f, 0.f, 0.f, 0.f};                                 \
        _Pragma("unroll")                                                           \
        for (int jt_ = 0; jt_ < 16; jt_++) {                                        \
            int j_ = jt_ * 16 + l15;                                                \
            bf16x8 k0_ = *(const bf16x8*)&Kl[j_ * 64 + (quad ^ (j_ & 7)) * 8];      \
            bf16x8 k1_ = *(const bf16x8*)&Kl[j_ * 64 + ((4 + quad) ^ (j_ & 7)) * 8];\
            floatx4 t_ = __builtin_amdgcn_mfma_f32_16x16x32_bf16(k0_, Q0, z_, 0, 0, 0); \
            S[jt_] = __builtin_amdgcn_mfma_f32_16x16x32_bf16(k1_, Q1, t_, 0, 0, 0); \
        }                                                                           \
    } while (0)

#define SOFTMAX(S, PINV)                                                            \
    do {                                                                            \
        float m0_ = S[0][0], m1_ = S[0][1], m2_ = S[0][2], m3_ = S[0][3];           \
        _Pragma("unroll")                                                           \
        for (int jt_ = 1; jt_ < 16; jt_++) {                                        \
            m0_ = fmaxf(m0_, S[jt_][0]); m1_ = fmaxf(m1_, S[jt_][1]);               \
            m2_ = fmaxf(m2_, S[jt_][2]); m3_ = fmaxf(m3_, S[jt_][3]);               \
        }                                                                           \
        float mx_ = fmaxf(fmaxf(m0_, m1_), fmaxf(m2_, m3_));                        \
        mx_ = fmaxf(mx_, __shfl_xor(mx_, 16, 64));                                  \
        mx_ = fmaxf(mx_, __shfl_xor(mx_, 32, 64));                                  \
        float mc_ = mx_ * C;                                                        \
        float a0_ = 0.f, a1_ = 0.f, a2_ = 0.f, a3_ = 0.f;                           \
        _Pragma("unroll")                                                           \
        for (int jt_ = 0; jt_ < 16; jt_++) {                                        \
            float e0_ = exp2f(S[jt_][0] * C - mc_);                                 \
            float e1_ = exp2f(S[jt_][1] * C - mc_);                                 \
            float e2_ = exp2f(S[jt_][2] * C - mc_);                                 \
            float e3_ = exp2f(S[jt_][3] * C - mc_);                                 \
            S[jt_][0] = e0_; S[jt_][1] = e1_; S[jt_][2] = e2_; S[jt_][3] = e3_;     \
            a0_ += e0_; a1_ += e1_; a2_ += e2_; a3_ += e3_;                         \
        }                                                                           \
        float sm_ = (a0_ + a1_) + (a2_ + a3_);                                      \
        sm_ += __shfl_xor(sm_, 16, 64);                                             \
        sm_ += __shfl_xor(sm_, 32, 64);                                             \
        PINV = 1.f / sm_;                                                           \
    } while (0)

#define PV_STORE(S, PINV, T)                                                        \
    do {                                                                            \
        floatx4 oacc_[4];                                                           \
        _Pragma("unroll")                                                           \
        for (int nt_ = 0; nt_ < 4; nt_++) oacc_[nt_] = (floatx4){0.f, 0.f, 0.f, 0.f}; \
        _Pragma("unroll")                                                           \
        for (int kk_ = 0; kk_ < 8; kk_++) {                                         \
            floatx4 se_ = S[2 * kk_], so_ = S[2 * kk_ + 1];                         \
            unsigned E0_ = cvtpk(se_[0] * PINV, se_[1] * PINV);                     \
            unsigned E1_ = cvtpk(se_[2] * PINV, se_[3] * PINV);                     \
            unsigned D0_ = cvtpk(so_[0] * PINV, so_[1] * PINV);                     \
            unsigned D1_ = cvtpk(so_[2] * PINV, so_[3] * PINV);                     \
            unsigned lo0_, hi0_, lo1_, hi1_;                                        \
            halfswap(E0_, D0_, lo0_, hi0_);                                         \
            halfswap(E1_, D1_, lo1_, hi1_);                                         \
            unsigned sel0_ = (quad & 1) ? hi0_ : lo0_;                              \
            unsigned sel1_ = (quad & 1) ? hi1_ : lo1_;                              \
            unsigned x0_ = (unsigned)__shfl_xor((int)sel0_, 16, 64);                \
            unsigned x1_ = (unsigned)__shfl_xor((int)sel1_, 16, 64);                \
            union { unsigned u[4]; bf16x8 v; } pf_;                                 \
            pf_.u[0] = (quad & 1) ? x0_ : sel0_;                                    \
            pf_.u[1] = (quad & 1) ? x1_ : sel1_;                                    \
            pf_.u[2] = (quad & 1) ? sel0_ : x0_;                                    \
            pf_.u[3] = (quad & 1) ? sel1_ : x1_;                                    \
            _Pragma("unroll")                                                       \
            for (int nt_ = 0; nt_ < 4; nt_++) {                                     \
                int d_ = nt_ * 16 + l15;                                            \
                bf16x8 bv_ = *(const bf16x8*)&Vl[d_ * 256 + ((kk_ * 4 + quad) ^ (d_ & 15)) * 8]; \
                oacc_[nt_] = __builtin_amdgcn_mfma_f32_16x16x32_bf16(pf_.v, bv_, oacc_[nt_], 0, 0, 0); \
            }                                                                       \
        }                                                                           \
        _Pragma("unroll")                                                           \
        for (int nt_ = 0; nt_ < 4; nt_++)                                           \
            _Pragma("unroll")                                                       \
            for (int r_ = 0; r_ < 4; r_++)                                          \
                Ot[wave][quad * 4 + r_][nt_ * 16 + l15] = f2bu(oacc_[nt_][r_]);     \
        int row_ = lane >> 2, d0_ = (lane & 3) * 16;                                \
        uint4 ld0_ = *(const uint4*)&Ot[wave][row_][d0_];                           \
        uint4 ld1_ = *(const uint4*)&Ot[wave][row_][d0_ + 8];                       \
        bf16* dst_ = ao + ((size_t)b * PQ + p0 + (T) * 64 + row_) * INNER + h * DH + d0_; \
        *(uint4*)dst_ = ld0_;                                                       \
        *(uint4*)(dst_ + 8) = ld1_;                                                 \
    } while (0)

__global__ __launch_bounds__(256, 2) void attn_kernel(
        const bf16* __restrict__ qalt, const bf16* __restrict__ kalt,
        const bf16* __restrict__ valt, bf16* __restrict__ ao) {
    __shared__ __align__(16) bf16 Kl[16384];        // 32 KB, persistent
    __shared__ __align__(16) bf16 Vl[16384];        // 32 KB, persistent
    __shared__ __align__(16) ushort Ot[4][16][80];  // 10 KB, per-wave scratch
    int tid = threadIdx.x;
    int wave = tid >> 6, lane = tid & 63;
    int l15 = lane & 15, quad = lane >> 4;
    int blk = blockIdx.x;
    int swz = (blk & 7) * 96 + (blk >> 3);   // 768 = 8*96, bijective
    int seg = swz & 3;                        // 4 segments of 256 Q rows
    int bh  = swz >> 2;                       // 4 consecutive segs share (b,h) & XCD
    int b = bh / HEADS, h = bh % HEADS;

    const bf16* qbase = qalt + (size_t)(b * HEADS + h) * PQ * DH;
    const bf16* kbase = kalt + (size_t)(b * HEADS + h) * PKV * DH;
    const bf16* vbase = valt + ((size_t)b * INNER + h * DH) * PKV;

    // stage K: rows 128B, granule slot = cs ^ (row&7)
    {
        int j = lane >> 3, cs = lane & 7;
#pragma unroll
        for (int it = 0; it < 8; it++) {
            int jr = (wave * 8 + it) * 8 + j;
            int g = cs ^ (jr & 7);
            dma16(kbase + (size_t)jr * 64 + g * 8, &Kl[(wave * 8 + it) * 512]);
        }
        // stage V: rows 512B, granule slot = cs2 ^ (row&15)
        int d = lane >> 5, cs2 = lane & 31;
#pragma unroll
        for (int it = 0; it < 8; it++) {
            int dr = (wave * 8 + it) * 2 + d;
            int g = cs2 ^ (dr & 15);
            dma16(vbase + (size_t)dr * 256 + g * 8, &Vl[(wave * 8 + it) * 512]);
        }
    }

    int p0 = seg * 256 + wave * 16;  // tile t adds t*64
    const bf16* qrow = qbase + (size_t)(p0 + l15) * DH + quad * 8;
    bf16x8 qA0 = *(const bf16x8*)qrow;
    bf16x8 qA1 = *(const bf16x8*)(qrow + 32);
    bf16x8 qB0 = *(const bf16x8*)(qrow + 64 * DH);
    bf16x8 qB1 = *(const bf16x8*)(qrow + 64 * DH + 32);
    __syncthreads();  // drains DMA (vmcnt) + cross-wave staging visibility

    const float C = ATTN_SCALE * 1.44269504f;   // fold scale into exp2
    floatx4 sA[16], sB[16];
    float pinv;

    QKT(sA, qA0, qA1);                          // tile 0
    qA0 = *(const bf16x8*)(qrow + 128 * DH);    // Q(t2), hides under t0 compute
    qA1 = *(const bf16x8*)(qrow + 128 * DH + 32);

    SOFTMAX(sA, pinv);
    QKT(sB, qB0, qB1);                          // tile 1
    PV_STORE(sA, pinv, 0);
    qB0 = *(const bf16x8*)(qrow + 192 * DH);    // Q(t3), hides under t1 compute
    qB1 = *(const bf16x8*)(qrow + 192 * DH + 32);

    SOFTMAX(sB, pinv);
    QKT(sA, qA0, qA1);                          // tile 2
    PV_STORE(sB, pinv, 1);

    SOFTMAX(sA, pinv);
    QKT(sB, qB0, qB1);                          // tile 3
    PV_STORE(sA, pinv, 2);

    SOFTMAX(sB, pinv);
    PV_STORE(sB, pinv, 3);
}

extern "C" void kernel_launch(void* const* d_in, const int* in_sizes, int n_in,
                              void* d_out, int out_size, void* d_ws, size_t ws_size,
                              hipStream_t stream) {
    const void* x        = d_in[0];
    const void* q_dw     = d_in[1];
    const void* q_gamma  = d_in[2];
    const void* q_beta   = d_in[3];
    const void* q_mean   = d_in[4];
    const void* q_var    = d_in[5];
    const void* q_pw     = d_in[6];
    const void* kv_dw    = d_in[7];
    const void* kv_gamma = d_in[8];
    const void* kv_beta  = d_in[9];
    const void* kv_mean  = d_in[10];
    const void* kv_var   = d_in[11];
    const void* kv_pw    = d_in[12];
    const void* out_w    = d_in[13];
    const void* out_b    = d_in[14];

    bf16* pool = (bf16*)((char*)d_ws + 256);
    bf16* yqt  = pool;                              // [32,1024,384] Y^T Q-path; reused as aob
    bf16* ykvt = yqt  + (size_t)32 * 1024 * 384;    // [32,256,384]  Y^T KV-path
    bf16* qalt = ykvt + (size_t)32 * 256 * 384;     // [32,6,1024,64]
    bf16* kalt = qalt + (size_t)32 * 6 * 1024 * 64; // [32,6,256,64]
    bf16* valt = kalt + (size_t)32 * 6 * 256 * 64;  // [32,384,256]
    bf16* wbf  = valt + (size_t)32 * 384 * 256;     // q_pw | kv_pw | out_w bf16
    bf16* qpw_bf = wbf;
    bf16* kvpw_bf = wbf + (size_t)INNER * CIN;
    bf16* outw_bf = kvpw_bf + (size_t)2 * INNER * CIN;
    bf16* aob  = yqt;  // alias: yqt dead after Q pointwise; attn writes [b][p][c]

    dw_bn_all<<<dim3(4, 25, 32), 256, 0, stream>>>(
        x, q_dw, q_gamma, q_beta, q_mean, q_var, yqt,
        kv_dw, kv_gamma, kv_beta, kv_mean, kv_var, ykvt,
        q_pw, kv_pw, out_w, wbf);
    mfma_pw_qkv<<<1152, 256, 0, stream>>>(qpw_bf, yqt, qalt, kvpw_bf, ykvt, kalt, valt);
    attn_kernel<<<768, 256, 0, stream>>>(qalt, kalt, valt, aob);
    mfma_pw_out<<<dim3(8, 3, 32), 256, 0, stream>>>(outw_bf, aob, out_b, d_out, x);
}

// Round 11
// 224.151 us; speedup vs baseline: 1.1754x; 1.0071x over previous
//
#include <hip/hip_runtime.h>
#include <hip/hip_bf16.h>

#define CIN 384
#define PQ 1024
#define PKV 256
#define HEADS 6
#define DH 64
#define INNER 384
#define ATTN_SCALE 0.125f

typedef __hip_bfloat16 bf16;
typedef unsigned short ushort;
typedef __bf16 bf16x8 __attribute__((ext_vector_type(8)));
typedef float floatx4 __attribute__((ext_vector_type(4)));

__device__ __forceinline__ float b2f(bf16 v) { return __bfloat162float(v); }
__device__ __forceinline__ bf16 f2b(float v) { return __float2bfloat16(v); }
__device__ __forceinline__ ushort f2bu(float v) { bf16 h = __float2bfloat16(v); return *(ushort*)&h; }
__device__ __forceinline__ float ldf(const void* p, size_t i, int isbf) {
    return isbf ? __bfloat162float(((const bf16*)p)[i]) : ((const float*)p)[i];
}
// async global->LDS DMA, 16B per lane; LDS dest = uniform base + lane*16
__device__ __forceinline__ void dma16(const bf16* g, bf16* l) {
    __builtin_amdgcn_global_load_lds(
        (const __attribute__((address_space(1))) unsigned int*)g,
        (__attribute__((address_space(3))) unsigned int*)l, 16, 0, 0);
}
// uniform dtype probe, vectorized: 16 independent uint4 loads (same 64 words/criterion)
__device__ __forceinline__ int probe_isbf(const void* x) {
    const uint4* p = (const uint4*)x;
    int cnt = 0;
#pragma unroll
    for (int i = 0; i < 16; i++) {
        uint4 v = p[i];
        const unsigned* u = (const unsigned*)&v;
#pragma unroll
        for (int j = 0; j < 4; j++) {
            unsigned e = (u[j] >> 7) & 0xFFu;
            cnt += (e >= 100u && e <= 140u) ? 1 : 0;
        }
    }
    return cnt >= 48 ? 1 : 0;
}
__device__ __forceinline__ unsigned cvtpk(float lo, float hi) {
    unsigned r;
    asm("v_cvt_pk_bf16_f32 %0, %1, %2" : "=v"(r) : "v"(lo), "v"(hi));
    return r;
}
__device__ __forceinline__ float bflo(unsigned u) { return __uint_as_float(u << 16); }
__device__ __forceinline__ float bfhi(unsigned u) { return __uint_as_float(u & 0xFFFF0000u); }
// half-wave swap: lo = [a(lanes0-31) | b(lanes0-31)], hi = [a(32-63) | b(32-63)]
__device__ __forceinline__ void halfswap(unsigned a, unsigned b, unsigned& lo, unsigned& hi) {
#if __has_builtin(__builtin_amdgcn_permlane32_swap)
    auto r = __builtin_amdgcn_permlane32_swap(a, b, false, false);
    lo = r[0]; hi = r[1];
#else
    unsigned ax = (unsigned)__shfl_xor((int)a, 32, 64);
    unsigned bx = (unsigned)__shfl_xor((int)b, 32, 64);
    bool lower = (threadIdx.x & 32) == 0;
    lo = lower ? a : bx;
    hi = lower ? ax : b;
#endif
}

// ---------------- depthwise 3x3 + BN body, bf16-LDS v3 --------------------------
// LDS row (i,cc) = 32 bf16 (64B) as 4 chunks of 8 at slot (wc ^ (cc&3)).
// s1: 20KB, s2: 18KB -> 8 blocks/CU (2x round-9). Staging = pure 16B copy for
// bf16 input (bit-identical math to round-9); conv converts bf16->f32 at read.
template <int STRIDE, int G, int HO, int WO>
__device__ __forceinline__ void dw_bn_body(
        const void* __restrict__ x, const void* __restrict__ wdw,
        const void* __restrict__ gamma, const void* __restrict__ beta,
        const void* __restrict__ mean, const void* __restrict__ var,
        bf16* __restrict__ yt, int isbf, int rg, int c0, int b, int tid,
        char* smem) {
    constexpr int IN_ROWS = (G - 1) * STRIDE + 3;       // 10 (s1) or 9 (s2)
    constexpr int PT = G * WO;                          // pixels per block
    ushort* xs = (ushort*)smem;                         // row (i,cc) at ((i*32+cc)*32)
    ushort (*outt)[40] = (ushort (*)[40])smem;          // [pixel][cc]

    int ri0 = rg * G * STRIDE - 1;

    // stage: 1 uint4 per chunk (8 bf16); wc fastest -> 64B global coalescing
    const int NCHUNK = 32 * IN_ROWS * 4;
    for (int ch = tid; ch < NCHUNK; ch += 256) {
        int wc = ch & 3;
        int cc = (ch >> 2) & 31;
        int i  = ch >> 7;
        int row = ri0 + i;
        uint4 v = {0u, 0u, 0u, 0u};
        if (row >= 0 && row < 32) {
            size_t goff = ((size_t)(b * CIN + c0 + cc) * 32 + row) * 32 + wc * 8;
            if (isbf) {
                v = *(const uint4*)((const bf16*)x + goff);
            } else {
                float4 v0 = *(const float4*)((const float*)x + goff);
                float4 v1 = *(const float4*)((const float*)x + goff + 4);
                v.x = cvtpk(v0.x, v0.y); v.y = cvtpk(v0.z, v0.w);
                v.z = cvtpk(v1.x, v1.y); v.w = cvtpk(v1.z, v1.w);
            }
        }
        *(uint4*)(xs + ((size_t)(i * 32 + cc)) * 32 + ((wc ^ (cc & 3)) * 8)) = v;
    }

    int cc = tid & 31;
    int g  = tid >> 5;
    int c  = c0 + cc;
    int key = cc & 3;
    float w9[9];
#pragma unroll
    for (int k = 0; k < 9; k++) w9[k] = ldf(wdw, c * 9 + k, isbf);
    float inv  = ldf(gamma, c, isbf) * rsqrtf(ldf(var, c, isbf) + 1e-5f);
    float bias = ldf(beta, c, isbf) - ldf(mean, c, isbf) * inv;
    __syncthreads();

    float o[STRIDE == 1 ? 32 : 8];
    if (STRIDE == 1) {
        // thread = (cc, row-group g); two 16-wide passes, rf[ky][1+t] = x[w=16p+t]
#pragma unroll
        for (int p = 0; p < 2; p++) {
            float rf[3][18];
#pragma unroll
            for (int ky = 0; ky < 3; ky++) {
                const ushort* rb = xs + ((size_t)((g + ky) * 32 + cc)) * 32;
                uint4 va = *(const uint4*)(rb + (((2 * p)     ^ key) * 8));
                uint4 vb = *(const uint4*)(rb + (((2 * p + 1) ^ key) * 8));
                const unsigned* ua = (const unsigned*)&va;
                const unsigned* ub = (const unsigned*)&vb;
#pragma unroll
                for (int q = 0; q < 4; q++) {
                    rf[ky][1 + 2 * q]  = bflo(ua[q]);
                    rf[ky][2 + 2 * q]  = bfhi(ua[q]);
                    rf[ky][9 + 2 * q]  = bflo(ub[q]);
                    rf[ky][10 + 2 * q] = bfhi(ub[q]);
                }
                rf[ky][0]  = p ? bflo((unsigned)rb[((1 ^ key) * 8) + 7]) : 0.f;  // w=15
                rf[ky][17] = p ? 0.f : bflo((unsigned)rb[((2 ^ key) * 8) + 0]);  // w=16
            }
#pragma unroll
            for (int j = 0; j < 16; j++) {
                float acc = w9[0] * rf[0][j] + w9[1] * rf[0][j + 1] + w9[2] * rf[0][j + 2]
                          + w9[3] * rf[1][j] + w9[4] * rf[1][j + 1] + w9[5] * rf[1][j + 2]
                          + w9[6] * rf[2][j] + w9[7] * rf[2][j + 1] + w9[8] * rf[2][j + 2];
                o[p * 16 + j] = acc * inv + bias;
            }
        }
    } else {
        // thread = (cc, rgrp = g&3, half = g>>2); 8 outputs; rf[1+t] = x[w=16h+t]
        int rgrp = g & 3, hf = g >> 2;
        float rf[3][17];
#pragma unroll
        for (int ky = 0; ky < 3; ky++) {
            const ushort* rb = xs + ((size_t)((2 * rgrp + ky) * 32 + cc)) * 32;
            uint4 va = *(const uint4*)(rb + (((2 * hf)     ^ key) * 8));
            uint4 vb = *(const uint4*)(rb + (((2 * hf + 1) ^ key) * 8));
            const unsigned* ua = (const unsigned*)&va;
            const unsigned* ub = (const unsigned*)&vb;
#pragma unroll
            for (int q = 0; q < 4; q++) {
                rf[ky][1 + 2 * q]  = bflo(ua[q]);
                rf[ky][2 + 2 * q]  = bfhi(ua[q]);
                rf[ky][9 + 2 * q]  = bflo(ub[q]);
                rf[ky][10 + 2 * q] = bfhi(ub[q]);
            }
            rf[ky][0] = hf ? bflo((unsigned)rb[((1 ^ key) * 8) + 7]) : 0.f;      // w=15
        }
#pragma unroll
        for (int j = 0; j < 8; j++) {
            float acc = w9[0] * rf[0][2 * j] + w9[1] * rf[0][2 * j + 1] + w9[2] * rf[0][2 * j + 2]
                      + w9[3] * rf[1][2 * j] + w9[4] * rf[1][2 * j + 1] + w9[5] * rf[1][2 * j + 2]
                      + w9[6] * rf[2][2 * j] + w9[7] * rf[2][2 * j + 1] + w9[8] * rf[2][2 * j + 2];
            o[j] = acc * inv + bias;
        }
    }
    __syncthreads();  // all xs reads done -> safe to overwrite union with outputs

    if (STRIDE == 1) {
#pragma unroll
        for (int wo = 0; wo < 32; wo++) outt[g * WO + wo][cc] = f2bu(o[wo]);
    } else {
        int rgrp = g & 3, hf = g >> 2;
#pragma unroll
        for (int j = 0; j < 8; j++) outt[rgrp * 16 + hf * 8 + j][cc] = f2bu(o[j]);
    }
    __syncthreads();

    const size_t pbase = (size_t)b * (HO * WO) + (size_t)rg * G * WO;
    for (int chk = tid; chk < PT * 4; chk += 256) {
        int k = chk & 3, p = chk >> 2;
        uint4 v = *(const uint4*)&outt[p][k * 8];
        *(uint4*)(yt + (pbase + p) * CIN + c0 + k * 8) = v;
    }
}

// ---------------- merged dw_bn dispatch: s1 conv | wconv | s2 conv ---------------
// grid (4, 25, 32): y<12 -> stride-1 conv (c0=y*32); y==12 -> weight convert;
// y>12 -> stride-2 conv (c0=(y-13)*32). 20KB LDS -> 8 blocks/CU.
__global__ __launch_bounds__(256) void dw_bn_all(
        const void* __restrict__ x,
        const void* __restrict__ q_dw, const void* __restrict__ q_gamma,
        const void* __restrict__ q_beta, const void* __restrict__ q_mean,
        const void* __restrict__ q_var, bf16* __restrict__ yqt,
        const void* __restrict__ kv_dw, const void* __restrict__ kv_gamma,
        const void* __restrict__ kv_beta, const void* __restrict__ kv_mean,
        const void* __restrict__ kv_var, bf16* __restrict__ ykvt,
        const void* __restrict__ w0, const void* __restrict__ w1,
        const void* __restrict__ w2, bf16* __restrict__ wdst) {
    __shared__ __align__(16) char smem[20480];
    int isbf = probe_isbf(x);
    int rg = blockIdx.x;
    int y  = blockIdx.y;
    int b  = blockIdx.z;
    int tid = threadIdx.x;

    if (y < 12) {
        dw_bn_body<1, 8, 32, 32>(x, q_dw, q_gamma, q_beta, q_mean, q_var,
                                 yqt, isbf, rg, y * 32, b, tid, smem);
    } else if (y == 12) {
        const int n0 = INNER * CIN, n1 = 2 * INNER * CIN, n2 = INNER * CIN;
        const int total = n0 + n1 + n2;
        for (int i = (b * 4 + rg) * 256 + tid; i < total; i += 32768) {
            float v;
            if (i < n0) v = ldf(w0, i, isbf);
            else if (i < n0 + n1) v = ldf(w1, i - n0, isbf);
            else v = ldf(w2, i - n0 - n1, isbf);
            wdst[i] = f2b(v);
        }
    } else {
        dw_bn_body<2, 4, 16, 16>(x, kv_dw, kv_gamma, kv_beta, kv_mean, kv_var,
                                 ykvt, isbf, rg, (y - 13) * 32, b, tid, smem);
    }
}

// ---------------- merged QKV pointwise GEMM (modes 0+1), 3 blocks/CU -------------
__global__ __launch_bounds__(256, 3) void mfma_pw_qkv(
        const bf16* __restrict__ qpw, const bf16* __restrict__ yqt,
        bf16* __restrict__ qalt,
        const bf16* __restrict__ kvpw, const bf16* __restrict__ ykvt,
        bf16* __restrict__ kalt, bf16* __restrict__ valt) {
    __shared__ __align__(16) bf16 As[2][4096];  // 128 rows x 32 k
    __shared__ __align__(16) bf16 Bs[2][4096];
    int tid = threadIdx.x;
    int wave = tid >> 6, lane = tid & 63;
    int l15 = lane & 15, quad = lane >> 4;
    int wm = wave & 1, wn = wave >> 1;

    int bid = blockIdx.x;
    int P, b, p0, o0;
    const bf16 *asrc0, *bsrc0;
    bf16* outq;
    if (bid < 768) {                 // mode 0: Q path, grid (8,3,32) flattened
        int m = bid;
        int p0t = m & 7; m >>= 3;
        int o0t = m % 3; b = m / 3;
        P = 1024; p0 = p0t * 128; o0 = o0t * 128;
        asrc0 = yqt; bsrc0 = qpw; outq = qalt;
    } else {                          // mode 1: KV path, grid (2,6,32) flattened
        int m = bid - 768;
        int p0t = m & 1; m >>= 1;
        int o0t = m % 6; b = m / 6;
        P = 256; p0 = p0t * 128; o0 = o0t * 128;
        asrc0 = ykvt; bsrc0 = kvpw; outq = kalt;
    }

    const bf16* asrc = asrc0 + ((size_t)b * P + p0) * CIN;
    const bf16* bsrc = bsrc0 + (size_t)o0 * CIN;

    int srow = (lane >> 2);
    int sc   = lane & 3;
    auto stage = [&](int step, int buf) {
#pragma unroll
        for (int it = 0; it < 2; it++) {
            int row = wave * 32 + it * 16 + srow;
            int g = sc ^ (row & 3);
            size_t goff = (size_t)row * CIN + step * 32 + g * 8;
            dma16(asrc + goff, &As[buf][(wave * 2 + it) * 512]);
            dma16(bsrc + goff, &Bs[buf][(wave * 2 + it) * 512]);
        }
    };

    floatx4 acc[4][4];
#pragma unroll
    for (int pt = 0; pt < 4; pt++)
#pragma unroll
        for (int ot = 0; ot < 4; ot++) acc[pt][ot] = (floatx4){0.f, 0.f, 0.f, 0.f};

    stage(0, 0);
    __syncthreads();
    for (int s = 0; s < CIN / 32; s++) {
        int buf = s & 1;
        if (s < CIN / 32 - 1) stage(s + 1, buf ^ 1);
        bf16x8 af[4], bw[4];
        int slot = (quad ^ (l15 & 3)) * 8;
#pragma unroll
        for (int pt = 0; pt < 4; pt++)
            af[pt] = *(const bf16x8*)&As[buf][(wm * 64 + pt * 16 + l15) * 32 + slot];
#pragma unroll
        for (int ot = 0; ot < 4; ot++)
            bw[ot] = *(const bf16x8*)&Bs[buf][(wn * 64 + ot * 16 + l15) * 32 + slot];
#pragma unroll
        for (int pt = 0; pt < 4; pt++)
#pragma unroll
            for (int ot = 0; ot < 4; ot++)
                acc[pt][ot] = __builtin_amdgcn_mfma_f32_16x16x32_bf16(af[pt], bw[ot], acc[pt][ot], 0, 0, 0);
        __syncthreads();
    }

    int pw0 = p0 + wm * 64, ow0 = o0 + wn * 64;
#pragma unroll
    for (int ot = 0; ot < 4; ot++) {
        int o = ow0 + ot * 16 + l15;
        if (o < INNER) {
            int h = o >> 6, d = o & 63;
            bf16* base = outq + ((size_t)(b * HEADS + h) * P) * 64 + d;
#pragma unroll
            for (int pt = 0; pt < 4; pt++)
#pragma unroll
                for (int r = 0; r < 4; r++)
                    base[(size_t)(pw0 + pt * 16 + quad * 4 + r) * 64] = f2b(acc[pt][ot][r]);
        } else {
            int ch = o - INNER;
            bf16* base = valt + ((size_t)b * INNER + ch) * PKV;
#pragma unroll
            for (int pt = 0; pt < 4; pt++)
#pragma unroll
                for (int r = 0; r < 4; r++)
                    base[pw0 + pt * 16 + quad * 4 + r] = f2b(acc[pt][ot][r]);
        }
    }
}

// ---------------- out-projection GEMM (mode 2), 3 blocks/CU ----------------------
__global__ __launch_bounds__(256, 3) void mfma_pw_out(
        const bf16* __restrict__ wt, const bf16* __restrict__ yt,
        const void* __restrict__ bias, void* __restrict__ out0,
        const void* __restrict__ xprobe) {
    __shared__ __align__(16) bf16 As[2][4096];
    __shared__ __align__(16) bf16 Bs[2][4096];
    const int P = PQ, O = CIN;
    int tid = threadIdx.x;
    int wave = tid >> 6, lane = tid & 63;
    int l15 = lane & 15, quad = lane >> 4;
    int wm = wave & 1, wn = wave >> 1;
    int b = blockIdx.z;
    int p0 = blockIdx.x * 128;
    int o0 = blockIdx.y * 128;

    const bf16* asrc = yt + ((size_t)b * P + p0) * CIN;
    const bf16* bsrc = wt + (size_t)o0 * CIN;

    int srow = (lane >> 2);
    int sc   = lane & 3;
    auto stage = [&](int step, int buf) {
#pragma unroll
        for (int it = 0; it < 2; it++) {
            int row = wave * 32 + it * 16 + srow;
            int g = sc ^ (row & 3);
            size_t goff = (size_t)row * CIN + step * 32 + g * 8;
            dma16(asrc + goff, &As[buf][(wave * 2 + it) * 512]);
            dma16(bsrc + goff, &Bs[buf][(wave * 2 + it) * 512]);
        }
    };

    floatx4 acc[4][4];
#pragma unroll
    for (int pt = 0; pt < 4; pt++)
#pragma unroll
        for (int ot = 0; ot < 4; ot++) acc[pt][ot] = (floatx4){0.f, 0.f, 0.f, 0.f};

    stage(0, 0);
    __syncthreads();
    for (int s = 0; s < CIN / 32; s++) {
        int buf = s & 1;
        if (s < CIN / 32 - 1) stage(s + 1, buf ^ 1);
        bf16x8 af[4], bw[4];
        int slot = (quad ^ (l15 & 3)) * 8;
#pragma unroll
        for (int pt = 0; pt < 4; pt++)
            af[pt] = *(const bf16x8*)&As[buf][(wm * 64 + pt * 16 + l15) * 32 + slot];
#pragma unroll
        for (int ot = 0; ot < 4; ot++)
            bw[ot] = *(const bf16x8*)&Bs[buf][(wn * 64 + ot * 16 + l15) * 32 + slot];
#pragma unroll
        for (int pt = 0; pt < 4; pt++)
#pragma unroll
            for (int ot = 0; ot < 4; ot++)
                acc[pt][ot] = __builtin_amdgcn_mfma_f32_16x16x32_bf16(af[pt], bw[ot], acc[pt][ot], 0, 0, 0);
        __syncthreads();
    }

    int pw0 = p0 + wm * 64, ow0 = o0 + wn * 64;
    int isbf = probe_isbf(xprobe);
#pragma unroll
    for (int ot = 0; ot < 4; ot++) {
        int o = ow0 + ot * 16 + l15;
        float bv = ldf(bias, o, isbf);
#pragma unroll
        for (int pt = 0; pt < 4; pt++) {
            int p = pw0 + pt * 16 + quad * 4;
            size_t idx = ((size_t)b * O + o) * P + p;
            if (!isbf) {
                float4 v4 = {acc[pt][ot][0] + bv, acc[pt][ot][1] + bv,
                             acc[pt][ot][2] + bv, acc[pt][ot][3] + bv};
                *(float4*)((float*)out0 + idx) = v4;
            } else {
                ushort4 u4 = {f2bu(acc[pt][ot][0] + bv), f2bu(acc[pt][ot][1] + bv),
                              f2bu(acc[pt][ot][2] + bv), f2bu(acc[pt][ot][3] + bv)};
                *(ushort4*)((bf16*)out0 + idx) = u4;
            }
        }
    }
}

// ---------------- fused MFMA attention v6: 2-tile software pipeline --------------
#define QKT(S, Q0, Q1)                                                              \
    do {                                                                            \
        floatx4 z_ = (floatx4){0.f, 0.f, 0.f, 0.f};                                 \
        _Pragma("unroll")                                                           \
        for (int jt_ = 0; jt_ < 16; jt_++) {                                        \
            int j_ = jt_ * 16 + l15;                                                \
            bf16x8 k0_ = *(const bf16x8*)&Kl[j_ * 64 + (quad ^ (j_ & 7)) * 8];      \
            bf16x8 k1_ = *(const bf16x8*)&Kl[j_ * 64 + ((4 + quad) ^ (j_ & 7)) * 8];\
            floatx4 t_ = __builtin_amdgcn_mfma_f32_16x16x32_bf16(k0_, Q0, z_, 0, 0, 0); \
            S[jt_] = __builtin_amdgcn_mfma_f32_16x16x32_bf16(k1_, Q1, t_, 0, 0, 0); \
        }                                                                           \
    } while (0)

#define SOFTMAX(S, PINV)                                                            \
    do {                                                                            \
        float m0_ = S[0][0], m1_ = S[0][1], m2_ = S[0][2], m3_ = S[0][3];           \
        _Pragma("unroll")                                                           \
        for (int jt_ = 1; jt_ < 16; jt_++) {                                        \
            m0_ = fmaxf(m0_, S[jt_][0]); m1_ = fmaxf(m1_, S[jt_][1]);               \
            m2_ = fmaxf(m2_, S[jt_][2]); m3_ = fmaxf(m3_, S[jt_][3]);               \
        }                                                                           \
        float mx_ = fmaxf(fmaxf(m0_, m1_), fmaxf(m2_, m3_));                        \
        mx_ = fmaxf(mx_, __shfl_xor(mx_, 16, 64));                                  \
        mx_ = fmaxf(mx_, __shfl_xor(mx_, 32, 64));                                  \
        float mc_ = mx_ * C;                                                        \
        float a0_ = 0.f, a1_ = 0.f, a2_ = 0.f, a3_ = 0.f;                           \
        _Pragma("unroll")                                                           \
        for (int jt_ = 0; jt_ < 16; jt_++) {                                        \
            float e0_ = exp2f(S[jt_][0] * C - mc_);                                 \
            float e1_ = exp2f(S[jt_][1] * C - mc_);                                 \
            float e2_ = exp2f(S[jt_][2] * C - mc_);                                 \
            float e3_ = exp2f(S[jt_][3] * C - mc_);                                 \
            S[jt_][0] = e0_; S[jt_][1] = e1_; S[jt_][2] = e2_; S[jt_][3] = e3_;     \
            a0_ += e0_; a1_ += e1_; a2_ += e2_; a3_ += e3_;                         \
        }                                                                           \
        float sm_ = (a0_ + a1_) + (a2_ + a3_);                                      \
        sm_ += __shfl_xor(sm_, 16, 64);                                             \
        sm_ += __shfl_xor(sm_, 32, 64);                                             \
        PINV = 1.f / sm_;                                                           \
    } while (0)

#define PV_STORE(S, PINV, T)                                                        \
    do {                                                                            \
        floatx4 oacc_[4];                                                           \
        _Pragma("unroll")                                                           \
        for (int nt_ = 0; nt_ < 4; nt_++) oacc_[nt_] = (floatx4){0.f, 0.f, 0.f, 0.f}; \
        _Pragma("unroll")                                                           \
        for (int kk_ = 0; kk_ < 8; kk_++) {                                         \
            floatx4 se_ = S[2 * kk_], so_ = S[2 * kk_ + 1];                         \
            unsigned E0_ = cvtpk(se_[0] * PINV, se_[1] * PINV);                     \
            unsigned E1_ = cvtpk(se_[2] * PINV, se_[3] * PINV);                     \
            unsigned D0_ = cvtpk(so_[0] * PINV, so_[1] * PINV);                     \
            unsigned D1_ = cvtpk(so_[2] * PINV, so_[3] * PINV);                     \
            unsigned lo0_, hi0_, lo1_, hi1_;                                        \
            halfswap(E0_, D0_, lo0_, hi0_);                                         \
            halfswap(E1_, D1_, lo1_, hi1_);                                         \
            unsigned sel0_ = (quad & 1) ? hi0_ : lo0_;                              \
            unsigned sel1_ = (quad & 1) ? hi1_ : lo1_;                              \
            unsigned x0_ = (unsigned)__shfl_xor((int)sel0_, 16, 64);                \
            unsigned x1_ = (unsigned)__shfl_xor((int)sel1_, 16, 64);                \
            union { unsigned u[4]; bf16x8 v; } pf_;                                 \
            pf_.u[0] = (quad & 1) ? x0_ : sel0_;                                    \
            pf_.u[1] = (quad & 1) ? x1_ : sel1_;                                    \
            pf_.u[2] = (quad & 1) ? sel0_ : x0_;                                    \
            pf_.u[3] = (quad & 1) ? sel1_ : x1_;                                    \
            _Pragma("unroll")                                                       \
            for (int nt_ = 0; nt_ < 4; nt_++) {                                     \
                int d_ = nt_ * 16 + l15;                                            \
                bf16x8 bv_ = *(const bf16x8*)&Vl[d_ * 256 + ((kk_ * 4 + quad) ^ (d_ & 15)) * 8]; \
                oacc_[nt_] = __builtin_amdgcn_mfma_f32_16x16x32_bf16(pf_.v, bv_, oacc_[nt_], 0, 0, 0); \
            }                                                                       \
        }                                                                           \
        _Pragma("unroll")                                                           \
        for (int nt_ = 0; nt_ < 4; nt_++)                                           \
            _Pragma("unroll")                                                       \
            for (int r_ = 0; r_ < 4; r_++)                                          \
                Ot[wave][quad * 4 + r_][nt_ * 16 + l15] = f2bu(oacc_[nt_][r_]);     \
        int row_ = lane >> 2, d0_ = (lane & 3) * 16;                                \
        uint4 ld0_ = *(const uint4*)&Ot[wave][row_][d0_];                           \
        uint4 ld1_ = *(const uint4*)&Ot[wave][row_][d0_ + 8];                       \
        bf16* dst_ = ao + ((size_t)b * PQ + p0 + (T) * 64 + row_) * INNER + h * DH + d0_; \
        *(uint4*)dst_ = ld0_;                                                       \
        *(uint4*)(dst_ + 8) = ld1_;                                                 \
    } while (0)

__global__ __launch_bounds__(256, 2) void attn_kernel(
        const bf16* __restrict__ qalt, const bf16* __restrict__ kalt,
        const bf16* __restrict__ valt, bf16* __restrict__ ao) {
    __shared__ __align__(16) bf16 Kl[16384];        // 32 KB, persistent
    __shared__ __align__(16) bf16 Vl[16384];        // 32 KB, persistent
    __shared__ __align__(16) ushort Ot[4][16][80];  // 10 KB, per-wave scratch
    int tid = threadIdx.x;
    int wave = tid >> 6, lane = tid & 63;
    int l15 = lane & 15, quad = lane >> 4;
    int blk = blockIdx.x;
    int swz = (blk & 7) * 96 + (blk >> 3);   // 768 = 8*96, bijective
    int seg = swz & 3;                        // 4 segments of 256 Q rows
    int bh  = swz >> 2;                       // 4 consecutive segs share (b,h) & XCD
    int b = bh / HEADS, h = bh % HEADS;

    const bf16* qbase = qalt + (size_t)(b * HEADS + h) * PQ * DH;
    const bf16* kbase = kalt + (size_t)(b * HEADS + h) * PKV * DH;
    const bf16* vbase = valt + ((size_t)b * INNER + h * DH) * PKV;

    // stage K: rows 128B, granule slot = cs ^ (row&7)
    {
        int j = lane >> 3, cs = lane & 7;
#pragma unroll
        for (int it = 0; it < 8; it++) {
            int jr = (wave * 8 + it) * 8 + j;
            int g = cs ^ (jr & 7);
            dma16(kbase + (size_t)jr * 64 + g * 8, &Kl[(wave * 8 + it) * 512]);
        }
        // stage V: rows 512B, granule slot = cs2 ^ (row&15)
        int d = lane >> 5, cs2 = lane & 31;
#pragma unroll
        for (int it = 0; it < 8; it++) {
            int dr = (wave * 8 + it) * 2 + d;
            int g = cs2 ^ (dr & 15);
            dma16(vbase + (size_t)dr * 256 + g * 8, &Vl[(wave * 8 + it) * 512]);
        }
    }

    int p0 = seg * 256 + wave * 16;  // tile t adds t*64
    const bf16* qrow = qbase + (size_t)(p0 + l15) * DH + quad * 8;
    bf16x8 qA0 = *(const bf16x8*)qrow;
    bf16x8 qA1 = *(const bf16x8*)(qrow + 32);
    bf16x8 qB0 = *(const bf16x8*)(qrow + 64 * DH);
    bf16x8 qB1 = *(const bf16x8*)(qrow + 64 * DH + 32);
    __syncthreads();  // drains DMA (vmcnt) + cross-wave staging visibility

    const float C = ATTN_SCALE * 1.44269504f;   // fold scale into exp2
    floatx4 sA[16], sB[16];
    float pinv;

    QKT(sA, qA0, qA1);                          // tile 0
    qA0 = *(const bf16x8*)(qrow + 128 * DH);    // Q(t2), hides under t0 compute
    qA1 = *(const bf16x8*)(qrow + 128 * DH + 32);

    SOFTMAX(sA, pinv);
    QKT(sB, qB0, qB1);                          // tile 1
    PV_STORE(sA, pinv, 0);
    qB0 = *(const bf16x8*)(qrow + 192 * DH);    // Q(t3), hides under t1 compute
    qB1 = *(const bf16x8*)(qrow + 192 * DH + 32);

    SOFTMAX(sB, pinv);
    QKT(sA, qA0, qA1);                          // tile 2
    PV_STORE(sB, pinv, 1);

    SOFTMAX(sA, pinv);
    QKT(sB, qB0, qB1);                          // tile 3
    PV_STORE(sA, pinv, 2);

    SOFTMAX(sB, pinv);
    PV_STORE(sB, pinv, 3);
}

extern "C" void kernel_launch(void* const* d_in, const int* in_sizes, int n_in,
                              void* d_out, int out_size, void* d_ws, size_t ws_size,
                              hipStream_t stream) {
    const void* x        = d_in[0];
    const void* q_dw     = d_in[1];
    const void* q_gamma  = d_in[2];
    const void* q_beta   = d_in[3];
    const void* q_mean   = d_in[4];
    const void* q_var    = d_in[5];
    const void* q_pw     = d_in[6];
    const void* kv_dw    = d_in[7];
    const void* kv_gamma = d_in[8];
    const void* kv_beta  = d_in[9];
    const void* kv_mean  = d_in[10];
    const void* kv_var   = d_in[11];
    const void* kv_pw    = d_in[12];
    const void* out_w    = d_in[13];
    const void* out_b    = d_in[14];

    bf16* pool = (bf16*)((char*)d_ws + 256);
    bf16* yqt  = pool;                              // [32,1024,384] Y^T Q-path; reused as aob
    bf16* ykvt = yqt  + (size_t)32 * 1024 * 384;    // [32,256,384]  Y^T KV-path
    bf16* qalt = ykvt + (size_t)32 * 256 * 384;     // [32,6,1024,64]
    bf16* kalt = qalt + (size_t)32 * 6 * 1024 * 64; // [32,6,256,64]
    bf16* valt = kalt + (size_t)32 * 6 * 256 * 64;  // [32,384,256]
    bf16* wbf  = valt + (size_t)32 * 384 * 256;     // q_pw | kv_pw | out_w bf16
    bf16* qpw_bf = wbf;
    bf16* kvpw_bf = wbf + (size_t)INNER * CIN;
    bf16* outw_bf = kvpw_bf + (size_t)2 * INNER * CIN;
    bf16* aob  = yqt;  // alias: yqt dead after Q pointwise; attn writes [b][p][c]

    dw_bn_all<<<dim3(4, 25, 32), 256, 0, stream>>>(
        x, q_dw, q_gamma, q_beta, q_mean, q_var, yqt,
        kv_dw, kv_gamma, kv_beta, kv_mean, kv_var, ykvt,
        q_pw, kv_pw, out_w, wbf);
    mfma_pw_qkv<<<1152, 256, 0, stream>>>(qpw_bf, yqt, qalt, kvpw_bf, ykvt, kalt, valt);
    attn_kernel<<<768, 256, 0, stream>>>(qalt, kalt, valt, aob);
    mfma_pw_out<<<dim3(8, 3, 32), 256, 0, stream>>>(outw_bf, aob, out_b, d_out, x);
}

// Round 12
// 222.266 us; speedup vs baseline: 1.1854x; 1.0085x over previous
//
#include <hip/hip_runtime.h>
#include <hip/hip_bf16.h>

#define CIN 384
#define PQ 1024
#define PKV 256
#define HEADS 6
#define DH 64
#define INNER 384
#define ATTN_SCALE 0.125f

typedef __hip_bfloat16 bf16;
typedef unsigned short ushort;
typedef __bf16 bf16x8 __attribute__((ext_vector_type(8)));
typedef float floatx4 __attribute__((ext_vector_type(4)));

__device__ __forceinline__ float b2f(bf16 v) { return __bfloat162float(v); }
__device__ __forceinline__ bf16 f2b(float v) { return __float2bfloat16(v); }
__device__ __forceinline__ ushort f2bu(float v) { bf16 h = __float2bfloat16(v); return *(ushort*)&h; }
__device__ __forceinline__ float ldf(const void* p, size_t i, int isbf) {
    return isbf ? __bfloat162float(((const bf16*)p)[i]) : ((const float*)p)[i];
}
// async global->LDS DMA, 16B per lane; LDS dest = uniform base + lane*16
__device__ __forceinline__ void dma16(const bf16* g, bf16* l) {
    __builtin_amdgcn_global_load_lds(
        (const __attribute__((address_space(1))) unsigned int*)g,
        (__attribute__((address_space(3))) unsigned int*)l, 16, 0, 0);
}
// uniform dtype probe, vectorized: 16 independent uint4 loads
__device__ __forceinline__ int probe_isbf(const void* x) {
    const uint4* p = (const uint4*)x;
    int cnt = 0;
#pragma unroll
    for (int i = 0; i < 16; i++) {
        uint4 v = p[i];
        const unsigned* u = (const unsigned*)&v;
#pragma unroll
        for (int j = 0; j < 4; j++) {
            unsigned e = (u[j] >> 7) & 0xFFu;
            cnt += (e >= 100u && e <= 140u) ? 1 : 0;
        }
    }
    return cnt >= 48 ? 1 : 0;
}
__device__ __forceinline__ unsigned cvtpk(float lo, float hi) {
    unsigned r;
    asm("v_cvt_pk_bf16_f32 %0, %1, %2" : "=v"(r) : "v"(lo), "v"(hi));
    return r;
}
__device__ __forceinline__ float bflo(unsigned u) { return __uint_as_float(u << 16); }
__device__ __forceinline__ float bfhi(unsigned u) { return __uint_as_float(u & 0xFFFF0000u); }
// half-wave swap: lo = [a(lanes0-31) | b(lanes0-31)], hi = [a(32-63) | b(32-63)]
__device__ __forceinline__ void halfswap(unsigned a, unsigned b, unsigned& lo, unsigned& hi) {
#if __has_builtin(__builtin_amdgcn_permlane32_swap)
    auto r = __builtin_amdgcn_permlane32_swap(a, b, false, false);
    lo = r[0]; hi = r[1];
#else
    unsigned ax = (unsigned)__shfl_xor((int)a, 32, 64);
    unsigned bx = (unsigned)__shfl_xor((int)b, 32, 64);
    bool lower = (threadIdx.x & 32) == 0;
    lo = lower ? a : bx;
    hi = lower ? ax : b;
#endif
}

// ---------------- depthwise 3x3 + BN body v4 ------------------------------------
// bf16 LDS rows with 80B pitch (40 ushorts): chunk starts spread across all
// multiples of 4 banks -> dense-minimum LDS access, zero excess conflicts, no
// XOR address math. Conv results store DIRECTLY to global from registers
// (no outt restage, one barrier per block instead of three).
template <int STRIDE, int G, int HO, int WO>
__device__ __forceinline__ void dw_bn_body(
        const void* __restrict__ x, const void* __restrict__ wdw,
        const void* __restrict__ gamma, const void* __restrict__ beta,
        const void* __restrict__ mean, const void* __restrict__ var,
        bf16* __restrict__ yt, int isbf, int rg, int c0, int b, int tid,
        char* smem) {
    constexpr int IN_ROWS = (G - 1) * STRIDE + 3;       // 10 (s1) or 9 (s2)
    constexpr int RP = 40;                              // row pitch in ushorts (80B)
    ushort* xs = (ushort*)smem;                         // row (i,cc) at ((i*32+cc)*RP)

    int ri0 = rg * G * STRIDE - 1;

    // stage: 1 uint4 per chunk (8 bf16); wc fastest -> 64B global coalescing
    const int NCHUNK = 32 * IN_ROWS * 4;
    for (int ch = tid; ch < NCHUNK; ch += 256) {
        int wc = ch & 3;
        int cc = (ch >> 2) & 31;
        int i  = ch >> 7;
        int row = ri0 + i;
        uint4 v = {0u, 0u, 0u, 0u};
        if (row >= 0 && row < 32) {
            size_t goff = ((size_t)(b * CIN + c0 + cc) * 32 + row) * 32 + wc * 8;
            if (isbf) {
                v = *(const uint4*)((const bf16*)x + goff);
            } else {
                float4 v0 = *(const float4*)((const float*)x + goff);
                float4 v1 = *(const float4*)((const float*)x + goff + 4);
                v.x = cvtpk(v0.x, v0.y); v.y = cvtpk(v0.z, v0.w);
                v.z = cvtpk(v1.x, v1.y); v.w = cvtpk(v1.z, v1.w);
            }
        }
        *(uint4*)(xs + (size_t)(i * 32 + cc) * RP + wc * 8) = v;
    }

    int cc = tid & 31;
    int g  = tid >> 5;
    int c  = c0 + cc;
    float w9[9];
#pragma unroll
    for (int k = 0; k < 9; k++) w9[k] = ldf(wdw, c * 9 + k, isbf);
    float inv  = ldf(gamma, c, isbf) * rsqrtf(ldf(var, c, isbf) + 1e-5f);
    float bias = ldf(beta, c, isbf) - ldf(mean, c, isbf) * inv;
    __syncthreads();  // the only barrier: staged tile visible to all waves

    const size_t pbase = (size_t)b * (HO * WO) + (size_t)rg * G * WO;
    if (STRIDE == 1) {
        // thread = (cc, row-group g); two 16-wide passes, rf[ky][1+t] = x[w=16p+t]
        float o[32];
#pragma unroll
        for (int p = 0; p < 2; p++) {
            float rf[3][18];
#pragma unroll
            for (int ky = 0; ky < 3; ky++) {
                const ushort* rb = xs + (size_t)((g + ky) * 32 + cc) * RP;
                uint4 va = *(const uint4*)(rb + (2 * p) * 8);
                uint4 vb = *(const uint4*)(rb + (2 * p + 1) * 8);
                const unsigned* ua = (const unsigned*)&va;
                const unsigned* ub = (const unsigned*)&vb;
#pragma unroll
                for (int q = 0; q < 4; q++) {
                    rf[ky][1 + 2 * q]  = bflo(ua[q]);
                    rf[ky][2 + 2 * q]  = bfhi(ua[q]);
                    rf[ky][9 + 2 * q]  = bflo(ub[q]);
                    rf[ky][10 + 2 * q] = bfhi(ub[q]);
                }
                rf[ky][0]  = p ? bflo((unsigned)rb[15]) : 0.f;   // w=15
                rf[ky][17] = p ? 0.f : bflo((unsigned)rb[16]);   // w=16
            }
#pragma unroll
            for (int j = 0; j < 16; j++) {
                float acc = w9[0] * rf[0][j] + w9[1] * rf[0][j + 1] + w9[2] * rf[0][j + 2]
                          + w9[3] * rf[1][j] + w9[4] * rf[1][j + 1] + w9[5] * rf[1][j + 2]
                          + w9[6] * rf[2][j] + w9[7] * rf[2][j + 1] + w9[8] * rf[2][j + 2];
                o[p * 16 + j] = acc * inv + bias;
            }
        }
        // direct store: per wo, wave covers 2 rows x 64B contiguous channel slices
        bf16* dst = yt + (pbase + (size_t)g * 32) * CIN + c0 + cc;
#pragma unroll
        for (int wo = 0; wo < 32; wo++) dst[(size_t)wo * CIN] = f2b(o[wo]);
    } else {
        // thread = (cc, rgrp = g&3, half = g>>2); 8 outputs; rf[1+t] = x[w=16h+t]
        int rgrp = g & 3, hf = g >> 2;
        float o[8];
        float rf[3][17];
#pragma unroll
        for (int ky = 0; ky < 3; ky++) {
            const ushort* rb = xs + (size_t)((2 * rgrp + ky) * 32 + cc) * RP;
            uint4 va = *(const uint4*)(rb + (2 * hf) * 8);
            uint4 vb = *(const uint4*)(rb + (2 * hf + 1) * 8);
            const unsigned* ua = (const unsigned*)&va;
            const unsigned* ub = (const unsigned*)&vb;
#pragma unroll
            for (int q = 0; q < 4; q++) {
                rf[ky][1 + 2 * q]  = bflo(ua[q]);
                rf[ky][2 + 2 * q]  = bfhi(ua[q]);
                rf[ky][9 + 2 * q]  = bflo(ub[q]);
                rf[ky][10 + 2 * q] = bfhi(ub[q]);
            }
            rf[ky][0] = hf ? bflo((unsigned)rb[15]) : 0.f;       // w=15
        }
#pragma unroll
        for (int j = 0; j < 8; j++) {
            float acc = w9[0] * rf[0][2 * j] + w9[1] * rf[0][2 * j + 1] + w9[2] * rf[0][2 * j + 2]
                      + w9[3] * rf[1][2 * j] + w9[4] * rf[1][2 * j + 1] + w9[5] * rf[1][2 * j + 2]
                      + w9[6] * rf[2][2 * j] + w9[7] * rf[2][2 * j + 1] + w9[8] * rf[2][2 * j + 2];
            o[j] = acc * inv + bias;
        }
        bf16* dst = yt + (pbase + (size_t)(rgrp * 16 + hf * 8)) * CIN + c0 + cc;
#pragma unroll
        for (int j = 0; j < 8; j++) dst[(size_t)j * CIN] = f2b(o[j]);
    }
}

// ---------------- merged dw_bn dispatch: s1 conv | wconv | s2 conv ---------------
// grid (4, 25, 32): y<12 -> stride-1 conv (c0=y*32); y==12 -> weight convert;
// y>12 -> stride-2 conv (c0=(y-13)*32). 25.6KB LDS -> 6 blocks/CU.
__global__ __launch_bounds__(256) void dw_bn_all(
        const void* __restrict__ x,
        const void* __restrict__ q_dw, const void* __restrict__ q_gamma,
        const void* __restrict__ q_beta, const void* __restrict__ q_mean,
        const void* __restrict__ q_var, bf16* __restrict__ yqt,
        const void* __restrict__ kv_dw, const void* __restrict__ kv_gamma,
        const void* __restrict__ kv_beta, const void* __restrict__ kv_mean,
        const void* __restrict__ kv_var, bf16* __restrict__ ykvt,
        const void* __restrict__ w0, const void* __restrict__ w1,
        const void* __restrict__ w2, bf16* __restrict__ wdst) {
    __shared__ __align__(16) char smem[25600];
    int isbf = probe_isbf(x);
    int rg = blockIdx.x;
    int y  = blockIdx.y;
    int b  = blockIdx.z;
    int tid = threadIdx.x;

    if (y < 12) {
        dw_bn_body<1, 8, 32, 32>(x, q_dw, q_gamma, q_beta, q_mean, q_var,
                                 yqt, isbf, rg, y * 32, b, tid, smem);
    } else if (y == 12) {
        const int n0 = INNER * CIN, n1 = 2 * INNER * CIN, n2 = INNER * CIN;
        const int total = n0 + n1 + n2;
        for (int i = (b * 4 + rg) * 256 + tid; i < total; i += 32768) {
            float v;
            if (i < n0) v = ldf(w0, i, isbf);
            else if (i < n0 + n1) v = ldf(w1, i - n0, isbf);
            else v = ldf(w2, i - n0 - n1, isbf);
            wdst[i] = f2b(v);
        }
    } else {
        dw_bn_body<2, 4, 16, 16>(x, kv_dw, kv_gamma, kv_beta, kv_mean, kv_var,
                                 ykvt, isbf, rg, (y - 13) * 32, b, tid, smem);
    }
}

// ---------------- merged QKV pointwise GEMM (modes 0+1), 3 blocks/CU -------------
__global__ __launch_bounds__(256, 3) void mfma_pw_qkv(
        const bf16* __restrict__ qpw, const bf16* __restrict__ yqt,
        bf16* __restrict__ qalt,
        const bf16* __restrict__ kvpw, const bf16* __restrict__ ykvt,
        bf16* __restrict__ kalt, bf16* __restrict__ valt) {
    __shared__ __align__(16) bf16 As[2][4096];  // 128 rows x 32 k
    __shared__ __align__(16) bf16 Bs[2][4096];
    int tid = threadIdx.x;
    int wave = tid >> 6, lane = tid & 63;
    int l15 = lane & 15, quad = lane >> 4;
    int wm = wave & 1, wn = wave >> 1;

    int bid = blockIdx.x;
    int P, b, p0, o0;
    const bf16 *asrc0, *bsrc0;
    bf16* outq;
    if (bid < 768) {                 // mode 0: Q path, grid (8,3,32) flattened
        int m = bid;
        int p0t = m & 7; m >>= 3;
        int o0t = m % 3; b = m / 3;
        P = 1024; p0 = p0t * 128; o0 = o0t * 128;
        asrc0 = yqt; bsrc0 = qpw; outq = qalt;
    } else {                          // mode 1: KV path, grid (2,6,32) flattened
        int m = bid - 768;
        int p0t = m & 1; m >>= 1;
        int o0t = m % 6; b = m / 6;
        P = 256; p0 = p0t * 128; o0 = o0t * 128;
        asrc0 = ykvt; bsrc0 = kvpw; outq = kalt;
    }

    const bf16* asrc = asrc0 + ((size_t)b * P + p0) * CIN;
    const bf16* bsrc = bsrc0 + (size_t)o0 * CIN;

    int srow = (lane >> 2);
    int sc   = lane & 3;
    auto stage = [&](int step, int buf) {
#pragma unroll
        for (int it = 0; it < 2; it++) {
            int row = wave * 32 + it * 16 + srow;
            int g = sc ^ (row & 3);
            size_t goff = (size_t)row * CIN + step * 32 + g * 8;
            dma16(asrc + goff, &As[buf][(wave * 2 + it) * 512]);
            dma16(bsrc + goff, &Bs[buf][(wave * 2 + it) * 512]);
        }
    };

    floatx4 acc[4][4];
#pragma unroll
    for (int pt = 0; pt < 4; pt++)
#pragma unroll
        for (int ot = 0; ot < 4; ot++) acc[pt][ot] = (floatx4){0.f, 0.f, 0.f, 0.f};

    stage(0, 0);
    __syncthreads();
    for (int s = 0; s < CIN / 32; s++) {
        int buf = s & 1;
        if (s < CIN / 32 - 1) stage(s + 1, buf ^ 1);
        bf16x8 af[4], bw[4];
        int slot = (quad ^ (l15 & 3)) * 8;
#pragma unroll
        for (int pt = 0; pt < 4; pt++)
            af[pt] = *(const bf16x8*)&As[buf][(wm * 64 + pt * 16 + l15) * 32 + slot];
#pragma unroll
        for (int ot = 0; ot < 4; ot++)
            bw[ot] = *(const bf16x8*)&Bs[buf][(wn * 64 + ot * 16 + l15) * 32 + slot];
#pragma unroll
        for (int pt = 0; pt < 4; pt++)
#pragma unroll
            for (int ot = 0; ot < 4; ot++)
                acc[pt][ot] = __builtin_amdgcn_mfma_f32_16x16x32_bf16(af[pt], bw[ot], acc[pt][ot], 0, 0, 0);
        __syncthreads();
    }

    int pw0 = p0 + wm * 64, ow0 = o0 + wn * 64;
#pragma unroll
    for (int ot = 0; ot < 4; ot++) {
        int o = ow0 + ot * 16 + l15;
        if (o < INNER) {
            int h = o >> 6, d = o & 63;
            bf16* base = outq + ((size_t)(b * HEADS + h) * P) * 64 + d;
#pragma unroll
            for (int pt = 0; pt < 4; pt++)
#pragma unroll
                for (int r = 0; r < 4; r++)
                    base[(size_t)(pw0 + pt * 16 + quad * 4 + r) * 64] = f2b(acc[pt][ot][r]);
        } else {
            int ch = o - INNER;
            bf16* base = valt + ((size_t)b * INNER + ch) * PKV;
#pragma unroll
            for (int pt = 0; pt < 4; pt++)
#pragma unroll
                for (int r = 0; r < 4; r++)
                    base[pw0 + pt * 16 + quad * 4 + r] = f2b(acc[pt][ot][r]);
        }
    }
}

// ---------------- out-projection GEMM (mode 2), 3 blocks/CU ----------------------
__global__ __launch_bounds__(256, 3) void mfma_pw_out(
        const bf16* __restrict__ wt, const bf16* __restrict__ yt,
        const void* __restrict__ bias, void* __restrict__ out0,
        const void* __restrict__ xprobe) {
    __shared__ __align__(16) bf16 As[2][4096];
    __shared__ __align__(16) bf16 Bs[2][4096];
    const int P = PQ, O = CIN;
    int tid = threadIdx.x;
    int wave = tid >> 6, lane = tid & 63;
    int l15 = lane & 15, quad = lane >> 4;
    int wm = wave & 1, wn = wave >> 1;
    int b = blockIdx.z;
    int p0 = blockIdx.x * 128;
    int o0 = blockIdx.y * 128;

    const bf16* asrc = yt + ((size_t)b * P + p0) * CIN;
    const bf16* bsrc = wt + (size_t)o0 * CIN;

    int srow = (lane >> 2);
    int sc   = lane & 3;
    auto stage = [&](int step, int buf) {
#pragma unroll
        for (int it = 0; it < 2; it++) {
            int row = wave * 32 + it * 16 + srow;
            int g = sc ^ (row & 3);
            size_t goff = (size_t)row * CIN + step * 32 + g * 8;
            dma16(asrc + goff, &As[buf][(wave * 2 + it) * 512]);
            dma16(bsrc + goff, &Bs[buf][(wave * 2 + it) * 512]);
        }
    };

    floatx4 acc[4][4];
#pragma unroll
    for (int pt = 0; pt < 4; pt++)
#pragma unroll
        for (int ot = 0; ot < 4; ot++) acc[pt][ot] = (floatx4){0.f, 0.f, 0.f, 0.f};

    stage(0, 0);
    __syncthreads();
    for (int s = 0; s < CIN / 32; s++) {
        int buf = s & 1;
        if (s < CIN / 32 - 1) stage(s + 1, buf ^ 1);
        bf16x8 af[4], bw[4];
        int slot = (quad ^ (l15 & 3)) * 8;
#pragma unroll
        for (int pt = 0; pt < 4; pt++)
            af[pt] = *(const bf16x8*)&As[buf][(wm * 64 + pt * 16 + l15) * 32 + slot];
#pragma unroll
        for (int ot = 0; ot < 4; ot++)
            bw[ot] = *(const bf16x8*)&Bs[buf][(wn * 64 + ot * 16 + l15) * 32 + slot];
#pragma unroll
        for (int pt = 0; pt < 4; pt++)
#pragma unroll
            for (int ot = 0; ot < 4; ot++)
                acc[pt][ot] = __builtin_amdgcn_mfma_f32_16x16x32_bf16(af[pt], bw[ot], acc[pt][ot], 0, 0, 0);
        __syncthreads();
    }

    int pw0 = p0 + wm * 64, ow0 = o0 + wn * 64;
    int isbf = probe_isbf(xprobe);
#pragma unroll
    for (int ot = 0; ot < 4; ot++) {
        int o = ow0 + ot * 16 + l15;
        float bv = ldf(bias, o, isbf);
#pragma unroll
        for (int pt = 0; pt < 4; pt++) {
            int p = pw0 + pt * 16 + quad * 4;
            size_t idx = ((size_t)b * O + o) * P + p;
            if (!isbf) {
                float4 v4 = {acc[pt][ot][0] + bv, acc[pt][ot][1] + bv,
                             acc[pt][ot][2] + bv, acc[pt][ot][3] + bv};
                *(float4*)((float*)out0 + idx) = v4;
            } else {
                ushort4 u4 = {f2bu(acc[pt][ot][0] + bv), f2bu(acc[pt][ot][1] + bv),
                              f2bu(acc[pt][ot][2] + bv), f2bu(acc[pt][ot][3] + bv)};
                *(ushort4*)((bf16*)out0 + idx) = u4;
            }
        }
    }
}

// ---------------- fused MFMA attention v6: 2-tile software pipeline --------------
#define QKT(S, Q0, Q1)                                                              \
    do {                                                                            \
        floatx4 z_ = (floatx4){0.f, 0.f, 0.f, 0.f};                                 \
        _Pragma("unroll")                                                           \
        for (int jt_ = 0; jt_ < 16; jt_++) {                                        \
            int j_ = jt_ * 16 + l15;                                                \
            bf16x8 k0_ = *(const bf16x8*)&Kl[j_ * 64 + (quad ^ (j_ & 7)) * 8];      \
            bf16x8 k1_ = *(const bf16x8*)&Kl[j_ * 64 + ((4 + quad) ^ (j_ & 7)) * 8];\
            floatx4 t_ = __builtin_amdgcn_mfma_f32_16x16x32_bf16(k0_, Q0, z_, 0, 0, 0); \
            S[jt_] = __builtin_amdgcn_mfma_f32_16x16x32_bf16(k1_, Q1, t_, 0, 0, 0); \
        }                                                                           \
    } while (0)

#define SOFTMAX(S, PINV)                                                            \
    do {                                                                            \
        float m0_ = S[0][0], m1_ = S[0][1], m2_ = S[0][2], m3_ = S[0][3];           \
        _Pragma("unroll")                                                           \
        for (int jt_ = 1; jt_ < 16; jt_++) {                                        \
            m0_ = fmaxf(m0_, S[jt_][0]); m1_ = fmaxf(m1_, S[jt_][1]);               \
            m2_ = fmaxf(m2_, S[jt_][2]); m3_ = fmaxf(m3_, S[jt_][3]);               \
        }                                                                           \
        float mx_ = fmaxf(fmaxf(m0_, m1_), fmaxf(m2_, m3_));                        \
        mx_ = fmaxf(mx_, __shfl_xor(mx_, 16, 64));                                  \
        mx_ = fmaxf(mx_, __shfl_xor(mx_, 32, 64));                                  \
        float mc_ = mx_ * C;                                                        \
        float a0_ = 0.f, a1_ = 0.f, a2_ = 0.f, a3_ = 0.f;                           \
        _Pragma("unroll")                                                           \
        for (int jt_ = 0; jt_ < 16; jt_++) {                                        \
            float e0_ = exp2f(S[jt_][0] * C - mc_);                                 \
            float e1_ = exp2f(S[jt_][1] * C - mc_);                                 \
            float e2_ = exp2f(S[jt_][2] * C - mc_);                                 \
            float e3_ = exp2f(S[jt_][3] * C - mc_);                                 \
            S[jt_][0] = e0_; S[jt_][1] = e1_; S[jt_][2] = e2_; S[jt_][3] = e3_;     \
            a0_ += e0_; a1_ += e1_; a2_ += e2_; a3_ += e3_;                         \
        }                                                                           \
        float sm_ = (a0_ + a1_) + (a2_ + a3_);                                      \
        sm_ += __shfl_xor(sm_, 16, 64);                                             \
        sm_ += __shfl_xor(sm_, 32, 64);                                             \
        PINV = 1.f / sm_;                                                           \
    } while (0)

#define PV_STORE(S, PINV, T)                                                        \
    do {                                                                            \
        floatx4 oacc_[4];                                                           \
        _Pragma("unroll")                                                           \
        for (int nt_ = 0; nt_ < 4; nt_++) oacc_[nt_] = (floatx4){0.f, 0.f, 0.f, 0.f}; \
        _Pragma("unroll")                                                           \
        for (int kk_ = 0; kk_ < 8; kk_++) {                                         \
            floatx4 se_ = S[2 * kk_], so_ = S[2 * kk_ + 1];                         \
            unsigned E0_ = cvtpk(se_[0] * PINV, se_[1] * PINV);                     \
            unsigned E1_ = cvtpk(se_[2] * PINV, se_[3] * PINV);                     \
            unsigned D0_ = cvtpk(so_[0] * PINV, so_[1] * PINV);                     \
            unsigned D1_ = cvtpk(so_[2] * PINV, so_[3] * PINV);                     \
            unsigned lo0_, hi0_, lo1_, hi1_;                                        \
            halfswap(E0_, D0_, lo0_, hi0_);                                         \
            halfswap(E1_, D1_, lo1_, hi1_);                                         \
            unsigned sel0_ = (quad & 1) ? hi0_ : lo0_;                              \
            unsigned sel1_ = (quad & 1) ? hi1_ : lo1_;                              \
            unsigned x0_ = (unsigned)__shfl_xor((int)sel0_, 16, 64);                \
            unsigned x1_ = (unsigned)__shfl_xor((int)sel1_, 16, 64);                \
            union { unsigned u[4]; bf16x8 v; } pf_;                                 \
            pf_.u[0] = (quad & 1) ? x0_ : sel0_;                                    \
            pf_.u[1] = (quad & 1) ? x1_ : sel1_;                                    \
            pf_.u[2] = (quad & 1) ? sel0_ : x0_;                                    \
            pf_.u[3] = (quad & 1) ? sel1_ : x1_;                                    \
            _Pragma("unroll")                                                       \
            for (int nt_ = 0; nt_ < 4; nt_++) {                                     \
                int d_ = nt_ * 16 + l15;                                            \
                bf16x8 bv_ = *(const bf16x8*)&Vl[d_ * 256 + ((kk_ * 4 + quad) ^ (d_ & 15)) * 8]; \
                oacc_[nt_] = __builtin_amdgcn_mfma_f32_16x16x32_bf16(pf_.v, bv_, oacc_[nt_], 0, 0, 0); \
            }                                                                       \
        }                                                                           \
        _Pragma("unroll")                                                           \
        for (int nt_ = 0; nt_ < 4; nt_++)                                           \
            _Pragma("unroll")                                                       \
            for (int r_ = 0; r_ < 4; r_++)                                          \
                Ot[wave][quad * 4 + r_][nt_ * 16 + l15] = f2bu(oacc_[nt_][r_]);     \
        int row_ = lane >> 2, d0_ = (lane & 3) * 16;                                \
        uint4 ld0_ = *(const uint4*)&Ot[wave][row_][d0_];                           \
        uint4 ld1_ = *(const uint4*)&Ot[wave][row_][d0_ + 8];                       \
        bf16* dst_ = ao + ((size_t)b * PQ + p0 + (T) * 64 + row_) * INNER + h * DH + d0_; \
        *(uint4*)dst_ = ld0_;                                                       \
        *(uint4*)(dst_ + 8) = ld1_;                                                 \
    } while (0)

__global__ __launch_bounds__(256, 2) void attn_kernel(
        const bf16* __restrict__ qalt, const bf16* __restrict__ kalt,
        const bf16* __restrict__ valt, bf16* __restrict__ ao) {
    __shared__ __align__(16) bf16 Kl[16384];        // 32 KB, persistent
    __shared__ __align__(16) bf16 Vl[16384];        // 32 KB, persistent
    __shared__ __align__(16) ushort Ot[4][16][80];  // 10 KB, per-wave scratch
    int tid = threadIdx.x;
    int wave = tid >> 6, lane = tid & 63;
    int l15 = lane & 15, quad = lane >> 4;
    int blk = blockIdx.x;
    int swz = (blk & 7) * 96 + (blk >> 3);   // 768 = 8*96, bijective
    int seg = swz & 3;                        // 4 segments of 256 Q rows
    int bh  = swz >> 2;                       // 4 consecutive segs share (b,h) & XCD
    int b = bh / HEADS, h = bh % HEADS;

    const bf16* qbase = qalt + (size_t)(b * HEADS + h) * PQ * DH;
    const bf16* kbase = kalt + (size_t)(b * HEADS + h) * PKV * DH;
    const bf16* vbase = valt + ((size_t)b * INNER + h * DH) * PKV;

    // stage K: rows 128B, granule slot = cs ^ (row&7)
    {
        int j = lane >> 3, cs = lane & 7;
#pragma unroll
        for (int it = 0; it < 8; it++) {
            int jr = (wave * 8 + it) * 8 + j;
            int g = cs ^ (jr & 7);
            dma16(kbase + (size_t)jr * 64 + g * 8, &Kl[(wave * 8 + it) * 512]);
        }
        // stage V: rows 512B, granule slot = cs2 ^ (row&15)
        int d = lane >> 5, cs2 = lane & 31;
#pragma unroll
        for (int it = 0; it < 8; it++) {
            int dr = (wave * 8 + it) * 2 + d;
            int g = cs2 ^ (dr & 15);
            dma16(vbase + (size_t)dr * 256 + g * 8, &Vl[(wave * 8 + it) * 512]);
        }
    }

    int p0 = seg * 256 + wave * 16;  // tile t adds t*64
    const bf16* qrow = qbase + (size_t)(p0 + l15) * DH + quad * 8;
    bf16x8 qA0 = *(const bf16x8*)qrow;
    bf16x8 qA1 = *(const bf16x8*)(qrow + 32);
    bf16x8 qB0 = *(const bf16x8*)(qrow + 64 * DH);
    bf16x8 qB1 = *(const bf16x8*)(qrow + 64 * DH + 32);
    __syncthreads();  // drains DMA (vmcnt) + cross-wave staging visibility

    const float C = ATTN_SCALE * 1.44269504f;   // fold scale into exp2
    floatx4 sA[16], sB[16];
    float pinv;

    QKT(sA, qA0, qA1);                          // tile 0
    qA0 = *(const bf16x8*)(qrow + 128 * DH);    // Q(t2), hides under t0 compute
    qA1 = *(const bf16x8*)(qrow + 128 * DH + 32);

    SOFTMAX(sA, pinv);
    QKT(sB, qB0, qB1);                          // tile 1
    PV_STORE(sA, pinv, 0);
    qB0 = *(const bf16x8*)(qrow + 192 * DH);    // Q(t3), hides under t1 compute
    qB1 = *(const bf16x8*)(qrow + 192 * DH + 32);

    SOFTMAX(sB, pinv);
    QKT(sA, qA0, qA1);                          // tile 2
    PV_STORE(sB, pinv, 1);

    SOFTMAX(sA, pinv);
    QKT(sB, qB0, qB1);                          // tile 3
    PV_STORE(sA, pinv, 2);

    SOFTMAX(sB, pinv);
    PV_STORE(sB, pinv, 3);
}

extern "C" void kernel_launch(void* const* d_in, const int* in_sizes, int n_in,
                              void* d_out, int out_size, void* d_ws, size_t ws_size,
                              hipStream_t stream) {
    const void* x        = d_in[0];
    const void* q_dw     = d_in[1];
    const void* q_gamma  = d_in[2];
    const void* q_beta   = d_in[3];
    const void* q_mean   = d_in[4];
    const void* q_var    = d_in[5];
    const void* q_pw     = d_in[6];
    const void* kv_dw    = d_in[7];
    const void* kv_gamma = d_in[8];
    const void* kv_beta  = d_in[9];
    const void* kv_mean  = d_in[10];
    const void* kv_var   = d_in[11];
    const void* kv_pw    = d_in[12];
    const void* out_w    = d_in[13];
    const void* out_b    = d_in[14];

    bf16* pool = (bf16*)((char*)d_ws + 256);
    bf16* yqt  = pool;                              // [32,1024,384] Y^T Q-path; reused as aob
    bf16* ykvt = yqt  + (size_t)32 * 1024 * 384;    // [32,256,384]  Y^T KV-path
    bf16* qalt = ykvt + (size_t)32 * 256 * 384;     // [32,6,1024,64]
    bf16* kalt = qalt + (size_t)32 * 6 * 1024 * 64; // [32,6,256,64]
    bf16* valt = kalt + (size_t)32 * 6 * 256 * 64;  // [32,384,256]
    bf16* wbf  = valt + (size_t)32 * 384 * 256;     // q_pw | kv_pw | out_w bf16
    bf16* qpw_bf = wbf;
    bf16* kvpw_bf = wbf + (size_t)INNER * CIN;
    bf16* outw_bf = kvpw_bf + (size_t)2 * INNER * CIN;
    bf16* aob  = yqt;  // alias: yqt dead after Q pointwise; attn writes [b][p][c]

    dw_bn_all<<<dim3(4, 25, 32), 256, 0, stream>>>(
        x, q_dw, q_gamma, q_beta, q_mean, q_var, yqt,
        kv_dw, kv_gamma, kv_beta, kv_mean, kv_var, ykvt,
        q_pw, kv_pw, out_w, wbf);
    mfma_pw_qkv<<<1152, 256, 0, stream>>>(qpw_bf, yqt, qalt, kvpw_bf, ykvt, kalt, valt);
    attn_kernel<<<768, 256, 0, stream>>>(qalt, kalt, valt, aob);
    mfma_pw_out<<<dim3(8, 3, 32), 256, 0, stream>>>(outw_bf, aob, out_b, d_out, x);
}